// Round 8
// baseline (647.039 us; speedup 1.0000x reference)
//
#include <hip/hip_runtime.h>
#include <hip/hip_bf16.h>
#include <math.h>

namespace {

constexpr int Bb   = 2;
constexpr int Ss   = 2048;
constexpr int Dd   = 1024;
constexpr int Hh   = 8;
constexpr int DKk  = 128;
constexpr int KTOP = 512;
constexpr int BH    = Bb * Hh;   // 16
constexpr int MROWS = Bb * Ss;   // 4096
constexpr float SCALE = 0.08838834764831845f;  // 1/sqrt(128)

typedef __attribute__((ext_vector_type(8))) short short8t;  // 8 bf16 = 16 B
typedef __attribute__((ext_vector_type(4))) short short4t;  // 4 bf16 = 8 B
typedef __attribute__((ext_vector_type(4))) float f32x4;

__device__ inline ushort f2bf(float x) {  // f32 -> bf16 RNE
  const unsigned u = __float_as_uint(x);
  return (ushort)((u + 0x7FFFu + ((u >> 16) & 1u)) >> 16);
}
__device__ inline float bf2f(ushort h) {
  return __uint_as_float(((unsigned)h) << 16);
}
struct HL { short h, l; };
__device__ inline HL split1(float x) {
  HL r;
  const ushort hu = f2bf(x);
  r.h = (short)hu;
  r.l = (short)f2bf(x - bf2f(hu));
  return r;
}

__device__ inline unsigned key_of(float v) {
  const unsigned u = __float_as_uint(v);
  return (u & 0x80000000u) ? ~u : (u | 0x80000000u);
}
__device__ inline float key_to_float(unsigned k) {
  const unsigned u = (k & 0x80000000u) ? (k & 0x7FFFFFFFu) : ~k;
  return __uint_as_float(u);
}

// ---------------------------------------------------------------------------
// Split-bf16 MFMA NT GEMM: C = A @ Bt^T via Ah·Bh + Ah·Bl + Al·Bh
// 128x128 tile, BK=32, 4 waves, 16x16x32 bf16 MFMA (~f32 precision).
// MODE 0: qproj — out f32 scatter to [B,H,S,DK]
// MODE 2: kproj — out split hi/lo bf16 scatter to [B,H,S,DK] (Oh/Ol)
// ---------------------------------------------------------------------------
template <int MODE>
__global__ __launch_bounds__(256) void mfma_split_nt(
    const float* __restrict__ Afp,
    const ushort* __restrict__ Bth, const ushort* __restrict__ Btl,
    const float* __restrict__ bias, float* __restrict__ Cout,
    ushort* __restrict__ Oh, ushort* __restrict__ Ol,
    int M, int N, int K)
{
  __shared__ ushort Ah[128 * 32];
  __shared__ ushort Al[128 * 32];
  __shared__ ushort Bh[128 * 32];
  __shared__ ushort Bl[128 * 32];
  const int t  = threadIdx.x;
  const int n0 = blockIdx.x * 128;
  const int m0 = blockIdx.y * 128;
  const int l  = t & 63, wv = t >> 6;
  const int wr = wv >> 1, wc = wv & 1;
  const int lrow = l & 15, lhi = l >> 4;

  f32x4 acc[4][4] = {};

  for (int kt = 0; kt < K; kt += 32) {
#pragma unroll
    for (int p = 0; p < 2; ++p) {
      const int li = p * 256 + t, row = li >> 2, g = li & 3;
      const int sw = row * 32 + ((g ^ (row & 3)) << 3);
      {
        const float* src = Afp + (size_t)(m0 + row) * K + kt + g * 8;
        const float4 v0 = *(const float4*)src;
        const float4 v1 = *(const float4*)(src + 4);
        short8t h, lo;
        HL r;
        r = split1(v0.x); h[0] = r.h; lo[0] = r.l;
        r = split1(v0.y); h[1] = r.h; lo[1] = r.l;
        r = split1(v0.z); h[2] = r.h; lo[2] = r.l;
        r = split1(v0.w); h[3] = r.h; lo[3] = r.l;
        r = split1(v1.x); h[4] = r.h; lo[4] = r.l;
        r = split1(v1.y); h[5] = r.h; lo[5] = r.l;
        r = split1(v1.z); h[6] = r.h; lo[6] = r.l;
        r = split1(v1.w); h[7] = r.h; lo[7] = r.l;
        *(short8t*)&Ah[sw] = h;
        *(short8t*)&Al[sw] = lo;
      }
      const size_t off = (size_t)(n0 + row) * K + kt + g * 8;
      *(short8t*)&Bh[sw] = *(const short8t*)(Bth + off);
      *(short8t*)&Bl[sw] = *(const short8t*)(Btl + off);
    }
    __syncthreads();

    short8t ah[4], al[4], bh[4], bl[4];
#pragma unroll
    for (int i = 0; i < 4; ++i) {
      const int row = wr * 64 + i * 16 + lrow;
      const int idx = row * 32 + ((lhi ^ (row & 3)) << 3);
      ah[i] = *(const short8t*)&Ah[idx];
      al[i] = *(const short8t*)&Al[idx];
    }
#pragma unroll
    for (int j = 0; j < 4; ++j) {
      const int row = wc * 64 + j * 16 + lrow;
      const int idx = row * 32 + ((lhi ^ (row & 3)) << 3);
      bh[j] = *(const short8t*)&Bh[idx];
      bl[j] = *(const short8t*)&Bl[idx];
    }
#pragma unroll
    for (int i = 0; i < 4; ++i)
#pragma unroll
      for (int j = 0; j < 4; ++j) {
        acc[i][j] = __builtin_amdgcn_mfma_f32_16x16x32_bf16(ah[i], bh[j], acc[i][j], 0, 0, 0);
        acc[i][j] = __builtin_amdgcn_mfma_f32_16x16x32_bf16(ah[i], bl[j], acc[i][j], 0, 0, 0);
        acc[i][j] = __builtin_amdgcn_mfma_f32_16x16x32_bf16(al[i], bh[j], acc[i][j], 0, 0, 0);
      }
    __syncthreads();
  }

#pragma unroll
  for (int i = 0; i < 4; ++i) {
#pragma unroll
    for (int j = 0; j < 4; ++j) {
      const int nn = n0 + wc * 64 + j * 16 + lrow;
#pragma unroll
      for (int r = 0; r < 4; ++r) {
        const int mm = m0 + wr * 64 + i * 16 + lhi * 4 + r;
        const float v = acc[i][j][r] + bias[nn];
        const int bb = mm >> 11, s = mm & (Ss - 1);
        const int hh = nn >> 7,  dk = nn & (DKk - 1);
        const size_t o = (((size_t)(bb * Hh + hh)) * Ss + s) * DKk + dk;
        if constexpr (MODE == 0) {
          Cout[o] = v;
        } else {
          const HL rr = split1(v);
          Oh[o] = (ushort)rr.h;
          Ol[o] = (ushort)rr.l;
        }
      }
    }
  }
}

// ---------------------------------------------------------------------------
// bf16 MFMA NT GEMM (plain)
// MODE 0: o_proj — A bf16, out f32 row-major, +bias
// MODE 1: v_proj — A bf16, out bf16 scatter Vt[bh][dk][s], +bias
// MODE 2: pv     — A f32 (weights, z=bh), out bf16 attn[B,S,D]
// ---------------------------------------------------------------------------
template <int MODE>
__global__ __launch_bounds__(256) void mfma_nt(
    const void* __restrict__ Ain, const ushort* __restrict__ BtAll,
    const float* __restrict__ bias, void* __restrict__ Cout,
    int M, int N, int K)
{
  __shared__ ushort As[128 * 64];
  __shared__ ushort Bs[128 * 64];
  const int t  = threadIdx.x;
  const int z  = blockIdx.z;
  const int n0 = blockIdx.x * 128;
  const int m0 = blockIdx.y * 128;
  const int l  = t & 63, wv = t >> 6;
  const int wr = wv >> 1, wc = wv & 1;
  const int lrow = l & 15, lhi = l >> 4;

  const float*  Af = (MODE == 2) ? ((const float*)Ain) + (size_t)z * Ss * Ss : nullptr;
  const ushort* Ab = (MODE == 2) ? nullptr : (const ushort*)Ain;
  const ushort* Bt = (MODE == 2) ? BtAll + (size_t)z * DKk * Ss : BtAll;

  f32x4 acc[4][4] = {};

  for (int kt = 0; kt < K; kt += 64) {
#pragma unroll
    for (int p = 0; p < 4; ++p) {
      const int li = p * 256 + t, row = li >> 3, g = li & 7;
      const int sw = row * 64 + ((g ^ (row & 7)) << 3);
      short8t sa;
      if constexpr (MODE == 2) {
        const float* src = Af + (size_t)(m0 + row) * K + kt + g * 8;
        const float4 v0 = *(const float4*)src;
        const float4 v1 = *(const float4*)(src + 4);
        sa[0] = (short)f2bf(v0.x); sa[1] = (short)f2bf(v0.y);
        sa[2] = (short)f2bf(v0.z); sa[3] = (short)f2bf(v0.w);
        sa[4] = (short)f2bf(v1.x); sa[5] = (short)f2bf(v1.y);
        sa[6] = (short)f2bf(v1.z); sa[7] = (short)f2bf(v1.w);
      } else {
        sa = *(const short8t*)(Ab + (size_t)(m0 + row) * K + kt + g * 8);
      }
      *(short8t*)&As[sw] = sa;
      const short8t sb = *(const short8t*)(Bt + (size_t)(n0 + row) * K + kt + g * 8);
      *(short8t*)&Bs[sw] = sb;
    }
    __syncthreads();

#pragma unroll
    for (int kk = 0; kk < 2; ++kk) {
      short8t a[4], b[4];
      const int g = kk * 4 + lhi;
#pragma unroll
      for (int i = 0; i < 4; ++i) {
        const int row = wr * 64 + i * 16 + lrow;
        a[i] = *(const short8t*)&As[row * 64 + ((g ^ (row & 7)) << 3)];
      }
#pragma unroll
      for (int j = 0; j < 4; ++j) {
        const int row = wc * 64 + j * 16 + lrow;
        b[j] = *(const short8t*)&Bs[row * 64 + ((g ^ (row & 7)) << 3)];
      }
#pragma unroll
      for (int i = 0; i < 4; ++i)
#pragma unroll
        for (int j = 0; j < 4; ++j)
          acc[i][j] = __builtin_amdgcn_mfma_f32_16x16x32_bf16(a[i], b[j], acc[i][j], 0, 0, 0);
    }
    __syncthreads();
  }

#pragma unroll
  for (int i = 0; i < 4; ++i) {
#pragma unroll
    for (int j = 0; j < 4; ++j) {
      const int nn = n0 + wc * 64 + j * 16 + lrow;
#pragma unroll
      for (int r = 0; r < 4; ++r) {
        const int mm = m0 + wr * 64 + i * 16 + lhi * 4 + r;
        const float v = acc[i][j][r];
        if constexpr (MODE == 0) {
          ((float*)Cout)[(size_t)mm * N + nn] = v + bias[nn];
        } else if constexpr (MODE == 1) {
          const int bb = mm >> 11, s = mm & (Ss - 1);
          const int hh = nn >> 7,  dk = nn & (DKk - 1);
          ((ushort*)Cout)[((size_t)((bb * Hh + hh) * DKk + dk)) * Ss + s] =
              f2bf(v + bias[nn]);
        } else {
          const int bb = z >> 3, hh = z & 7;
          ((ushort*)Cout)[((size_t)(bb * Ss + mm)) * Dd + hh * DKk + nn] = f2bf(v);
        }
      }
    }
  }
}

__global__ __launch_bounds__(256) void conv_bf16(
    const float* __restrict__ in, ushort* __restrict__ out, int n)
{
  const int i = (blockIdx.x * 256 + threadIdx.x) * 4;
  if (i < n) {
    const float4 v = *(const float4*)(in + i);
    short4t o;
    o[0] = (short)f2bf(v.x); o[1] = (short)f2bf(v.y);
    o[2] = (short)f2bf(v.z); o[3] = (short)f2bf(v.w);
    *(short4t*)(out + i) = o;
  }
}

__global__ __launch_bounds__(256) void transpose_bf16(
    const float* __restrict__ W, ushort* __restrict__ Wt)
{
  __shared__ float tile[32][33];
  const int t  = threadIdx.x;
  const int c0 = blockIdx.x * 32, r0 = blockIdx.y * 32;
  const int lr = t >> 3, lc4 = (t & 7) * 4;
  const float4 v = *(const float4*)(W + (size_t)(r0 + lr) * Dd + c0 + lc4);
  tile[lr][lc4 + 0] = v.x; tile[lr][lc4 + 1] = v.y;
  tile[lr][lc4 + 2] = v.z; tile[lr][lc4 + 3] = v.w;
  __syncthreads();
  const int oc = t >> 3, or4 = (t & 7) * 4;
  short4t o;
  o[0] = (short)f2bf(tile[or4 + 0][oc]);
  o[1] = (short)f2bf(tile[or4 + 1][oc]);
  o[2] = (short)f2bf(tile[or4 + 2][oc]);
  o[3] = (short)f2bf(tile[or4 + 3][oc]);
  *(short4t*)(Wt + (size_t)(c0 + oc) * Dd + r0 + or4) = o;
}

__global__ __launch_bounds__(256) void transpose_split(
    const float* __restrict__ W, ushort* __restrict__ Th, ushort* __restrict__ Tl)
{
  __shared__ float tile[32][33];
  const int t  = threadIdx.x;
  const int c0 = blockIdx.x * 32, r0 = blockIdx.y * 32;
  const int lr = t >> 3, lc4 = (t & 7) * 4;
  const float4 v = *(const float4*)(W + (size_t)(r0 + lr) * Dd + c0 + lc4);
  tile[lr][lc4 + 0] = v.x; tile[lr][lc4 + 1] = v.y;
  tile[lr][lc4 + 2] = v.z; tile[lr][lc4 + 3] = v.w;
  __syncthreads();
  const int oc = t >> 3, or4 = (t & 7) * 4;
  short4t oh, ol;
  HL r;
  r = split1(tile[or4 + 0][oc]); oh[0] = r.h; ol[0] = r.l;
  r = split1(tile[or4 + 1][oc]); oh[1] = r.h; ol[1] = r.l;
  r = split1(tile[or4 + 2][oc]); oh[2] = r.h; ol[2] = r.l;
  r = split1(tile[or4 + 3][oc]); oh[3] = r.h; ol[3] = r.l;
  *(short4t*)(Th + (size_t)(c0 + oc) * Dd + r0 + or4) = oh;
  *(short4t*)(Tl + (size_t)(c0 + oc) * Dd + r0 + or4) = ol;
}

// ---------------------------------------------------------------------------
// Fused scores + exact-top512 + softmax.
// One block = (bh, 16 q-rows), 512 threads (8 waves).
// Phase 1: scores^T tiles via mfma(K_frag, Q_frag) -> lane holds 4 consecutive
//          j for fixed q -> b128 writes into keys[16][2052] (padded). Pass-1
//          histogram (top byte) fused into the epilogue (16 per-row hists).
// Phase 2: 16 wave-synchronous 32-lane row-teams: radix passes 2-4, exp,
//          normalize, store. Zero __syncthreads in phase 2.
// ---------------------------------------------------------------------------
struct Sel { unsigned bin, need, tie; };

__device__ inline Sel team_select(const unsigned* h, int l32, int halfbase,
                                  unsigned needK)
{
  unsigned b[8], lsum = 0u;
#pragma unroll
  for (int i = 0; i < 8; ++i) { b[i] = h[l32 * 8 + i]; lsum += b[i]; }
  unsigned s = lsum;
#pragma unroll
  for (int off = 1; off < 32; off <<= 1) {
    const unsigned v = __shfl_down(s, off);
    if (l32 + off < 32) s += v;
  }
  unsigned run = s - lsum;  // count strictly above my bins
  unsigned fbin = 0u, fneed = 0u, ftie = 0u;
  bool found = false;
#pragma unroll
  for (int i = 7; i >= 0; --i) {
    const unsigned c = b[i];
    if (!found && c > 0u && run < needK && run + c >= needK) {
      found = true;
      fbin = (unsigned)(l32 * 8 + i);
      fneed = needK - run;
      ftie = c;
    }
    run += c;
  }
  const unsigned long long mask = __ballot(found);
  const unsigned mh = (unsigned)(mask >> halfbase);
  const int src = (__ffs(mh) - 1) + halfbase;
  Sel out;
  out.bin  = __shfl(fbin, src);
  out.need = __shfl(fneed, src);
  out.tie  = __shfl(ftie, src);
  return out;
}

__global__ __launch_bounds__(512) void fused_scores_topk(
    const float* __restrict__ Qw, const ushort* __restrict__ Kh,
    const ushort* __restrict__ Kl, float* __restrict__ wts)
{
  __shared__ unsigned keys[16][2052];   // 131.3 KB (pad 4 words: 2-way banks)
  __shared__ unsigned hist[16][256];    // 16 KB
  __shared__ ushort   cand[16][64];     // 2 KB
  __shared__ unsigned candCnt[16];

  const int t    = threadIdx.x;
  const int wgid = blockIdx.x;
  const int bh   = wgid & 15;           // XCD x serves bh x and x+8 (L2 reuse)
  const int q0   = (wgid >> 4) * 16;
  const int l    = t & 63, wv = t >> 6;
  const int lq   = l & 15, lk = l >> 4;

  for (int i = t; i < 16 * 256; i += 512) ((unsigned*)hist)[i] = 0u;
  if (t < 16) candCnt[t] = 0u;
  __syncthreads();

  // ---- Q fragments (B-operand): lane holds Q[q0+lq][ks*32 + lk*8 + e] ----
  const float* Qp = Qw + ((size_t)(bh * Ss + q0 + lq)) * DKk;
  short8t qh[4], ql[4];
#pragma unroll
  for (int ks = 0; ks < 4; ++ks) {
    const float* qsrc = Qp + ks * 32 + lk * 8;
    const float4 v0 = *(const float4*)qsrc;
    const float4 v1 = *(const float4*)(qsrc + 4);
    HL rr;
    rr = split1(v0.x); qh[ks][0] = rr.h; ql[ks][0] = rr.l;
    rr = split1(v0.y); qh[ks][1] = rr.h; ql[ks][1] = rr.l;
    rr = split1(v0.z); qh[ks][2] = rr.h; ql[ks][2] = rr.l;
    rr = split1(v0.w); qh[ks][3] = rr.h; ql[ks][3] = rr.l;
    rr = split1(v1.x); qh[ks][4] = rr.h; ql[ks][4] = rr.l;
    rr = split1(v1.y); qh[ks][5] = rr.h; ql[ks][5] = rr.l;
    rr = split1(v1.z); qh[ks][6] = rr.h; ql[ks][6] = rr.l;
    rr = split1(v1.w); qh[ks][7] = rr.h; ql[ks][7] = rr.l;
  }

  // ---- phase 1: wave's 256-col j-slab, 16 tiles of 16x16 ----
  const ushort* Khb = Kh + ((size_t)bh * Ss) * DKk;
  const ushort* Klb = Kl + ((size_t)bh * Ss) * DKk;
  for (int jt = 0; jt < 16; ++jt) {
    const int j0 = wv * 256 + jt * 16;
    const size_t ko = ((size_t)(j0 + lq)) * DKk + lk * 8;
    f32x4 acc = {};
#pragma unroll
    for (int ks = 0; ks < 4; ++ks) {
      const short8t ah = *(const short8t*)(Khb + ko + ks * 32);
      const short8t al = *(const short8t*)(Klb + ko + ks * 32);
      acc = __builtin_amdgcn_mfma_f32_16x16x32_bf16(ah, qh[ks], acc, 0, 0, 0);
      acc = __builtin_amdgcn_mfma_f32_16x16x32_bf16(ah, ql[ks], acc, 0, 0, 0);
      acc = __builtin_amdgcn_mfma_f32_16x16x32_bf16(al, qh[ks], acc, 0, 0, 0);
    }
    // C^T layout: q = l&15, j = j0 + (l>>4)*4 + r  (4 consecutive j per lane)
    uint4 kk;
    unsigned* kks = &kk.x;
#pragma unroll
    for (int r = 0; r < 4; ++r) {
      const unsigned kv = key_of(acc[r] * SCALE);
      kks[r] = kv;
      atomicAdd(&hist[lq][kv >> 24], 1u);
    }
    *(uint4*)&keys[lq][j0 + lk * 4] = kk;
  }
  __syncthreads();

  // ---- phase 2: 32-lane row-teams, wave-synchronous ----
  const int r        = t >> 5;       // team/row 0..15
  const int l32      = t & 31;
  const int halfbase = l & 32;       // 0 or 32
  unsigned* krow = keys[r];
  unsigned* h    = hist[r];

  unsigned needK = KTOP, tieC = 0u;

  // pass 1 (hist already built in epilogue)
  Sel s1 = team_select(h, l32, halfbase, needK);
  unsigned prefix = s1.bin << 24;
  needK = s1.need; tieC = s1.tie;

#pragma unroll
  for (int i = 0; i < 8; ++i) h[l32 * 8 + i] = 0u;

  // pass 2: full sweep, hist on byte2; also exact row max
  unsigned maxk = 0u;
  {
    const unsigned b1 = prefix >> 24;
    for (int it = 0; it < 16; ++it) {
      const uint4 kk = *(const uint4*)&krow[it * 128 + l32 * 4];
      maxk = max(max(maxk, max(kk.x, kk.y)), max(kk.z, kk.w));
      if ((kk.x >> 24) == b1) atomicAdd(&h[(kk.x >> 16) & 255u], 1u);
      if ((kk.y >> 24) == b1) atomicAdd(&h[(kk.y >> 16) & 255u], 1u);
      if ((kk.z >> 24) == b1) atomicAdd(&h[(kk.z >> 16) & 255u], 1u);
      if ((kk.w >> 24) == b1) atomicAdd(&h[(kk.w >> 16) & 255u], 1u);
    }
  }
#pragma unroll
  for (int off = 1; off < 32; off <<= 1) {
    const unsigned o = __shfl_xor(maxk, off);
    maxk = max(maxk, o);
  }
  const float m = key_to_float(maxk);

  Sel s2 = team_select(h, l32, halfbase, needK);
  prefix |= s2.bin << 16;
  needK = s2.need; tieC = s2.tie;

#pragma unroll
  for (int i = 0; i < 8; ++i) h[l32 * 8 + i] = 0u;

  // pass 3: full sweep on 16-bit prefix; collect candidates (typically 2-5)
  {
    const unsigned p16 = prefix >> 16;
    for (int it = 0; it < 16; ++it) {
      const int i0 = it * 128 + l32 * 4;
      const uint4 kk = *(const uint4*)&krow[i0];
      const unsigned a[4] = {kk.x, kk.y, kk.z, kk.w};
#pragma unroll
      for (int c = 0; c < 4; ++c) {
        if ((a[c] >> 16) == p16) {
          atomicAdd(&h[(a[c] >> 8) & 255u], 1u);
          const unsigned pos = atomicAdd(&candCnt[r], 1u);
          if (pos < 64u) cand[r][pos] = (ushort)(i0 + c);
        }
      }
    }
  }
  Sel s3 = team_select(h, l32, halfbase, needK);
  prefix |= s3.bin << 8;
  needK = s3.need; tieC = s3.tie;

#pragma unroll
  for (int i = 0; i < 8; ++i) h[l32 * 8 + i] = 0u;

  // pass 4: over candidates (fallback to full sweep if overflow)
  {
    const unsigned p24 = prefix >> 8;
    const unsigned cnt = candCnt[r];
    if (cnt <= 64u) {
      for (unsigned i = (unsigned)l32; i < cnt; i += 32u) {
        const unsigned k = krow[cand[r][i]];
        if ((k >> 8) == p24) atomicAdd(&h[k & 255u], 1u);
      }
    } else {
      for (int it = 0; it < 16; ++it) {
        const uint4 kk = *(const uint4*)&krow[it * 128 + l32 * 4];
        const unsigned a[4] = {kk.x, kk.y, kk.z, kk.w};
#pragma unroll
        for (int c = 0; c < 4; ++c)
          if ((a[c] >> 8) == p24) atomicAdd(&h[a[c] & 255u], 1u);
      }
    }
  }
  Sel s4 = team_select(h, l32, halfbase, needK);
  const unsigned T = prefix | s4.bin;
  needK = s4.need; tieC = s4.tie;

  // rare: duplicates of T straddle the boundary -> keep lowest indices
  if (tieC != needK) {
    if (l32 == 0) {
      unsigned taken = 0u;
      for (int j = 0; j < Ss; ++j)
        if (krow[j] == T) { if (taken < needK) ++taken; else krow[j] = 0u; }
    }
  }
  // invariant: count(krow == T) == needK; selected = (krow >= T)

  // exp sweep: w_pre = (k>=T ? exp(v-m) : 0), stored over keys
  float lz = 0.f;
  for (int it = 0; it < 16; ++it) {
    const int i0 = it * 128 + l32 * 4;
    const uint4 kk = *(const uint4*)&krow[i0];
    float4 w;
    w.x = (kk.x >= T) ? __expf(key_to_float(kk.x) - m) : 0.f;
    w.y = (kk.y >= T) ? __expf(key_to_float(kk.y) - m) : 0.f;
    w.z = (kk.z >= T) ? __expf(key_to_float(kk.z) - m) : 0.f;
    w.w = (kk.w >= T) ? __expf(key_to_float(kk.w) - m) : 0.f;
    lz += (w.x + w.y) + (w.z + w.w);
    *(float4*)&krow[i0] = w;
  }
#pragma unroll
  for (int off = 1; off < 32; off <<= 1) lz += __shfl_xor(lz, off);
  const float Zi = 1.0f / lz;

  // scale and store
  float* orow = wts + ((size_t)(bh * Ss + q0 + r)) * Ss;
  for (int it = 0; it < 16; ++it) {
    const int i0 = it * 128 + l32 * 4;
    const float4 w = *(const float4*)&krow[i0];
    float4 o;
    o.x = w.x * Zi; o.y = w.y * Zi; o.z = w.z * Zi; o.w = w.w * Zi;
    *(float4*)(orow + i0) = o;
  }
}

}  // namespace

extern "C" void kernel_launch(void* const* d_in, const int* in_sizes, int n_in,
                              void* d_out_v, int out_size, void* d_ws, size_t ws_size,
                              hipStream_t stream)
{
  const float* query = (const float*)d_in[0];
  const float* key   = (const float*)d_in[1];
  const float* value = (const float*)d_in[2];
  const float* Wq = (const float*)d_in[3];  const float* bq = (const float*)d_in[4];
  const float* Wk = (const float*)d_in[5];  const float* bk = (const float*)d_in[6];
  const float* Wv = (const float*)d_in[7];  const float* bv = (const float*)d_in[8];
  const float* Wo = (const float*)d_in[9];  const float* bo = (const float*)d_in[10];

  float* d_out = (float*)d_out_v;
  float* outp  = d_out;                              // [B,S,D] f32
  float* wts   = d_out + (size_t)Bb * Ss * Dd;       // [B,H,S,S] f32

  const size_t PROJ = (size_t)MROWS * Dd;            // 4M elements
  const size_t DD2  = (size_t)Dd * Dd;               // 1M elements

  float*  ws    = (float*)d_ws;
  float*  Q     = ws;                                // f32 [BH][S][DK]   16 MB
  ushort* Kth   = (ushort*)(Q + PROJ);               // bf16 K hi        8 MB
  ushort* Ktl   = Kth + PROJ;                        // bf16 K lo        8 MB
  ushort* r3    = Ktl + PROJ;                        // 8 MB region
  ushort* WqTh  = r3;
  ushort* WqTl  = r3 + DD2;
  ushort* WkTh  = r3 + 2 * DD2;
  ushort* WkTl  = r3 + 3 * DD2;
  ushort* vbf   = r3;                                // aliases after projections
  ushort* WvT   = r3 + 4 * DD2;                      // 2 MB
  ushort* WoT   = WvT + DD2;                         // 2 MB
  ushort* Vt    = WoT + DD2;                         // bf16 V^T [16][128][2048] 8 MB
  ushort* attnb = Vt + (size_t)BH * DKk * Ss;        // bf16 attn [4096][1024]   8 MB

  const dim3 blk(256);

  // weight prep
  transpose_split<<<dim3(32, 32), blk, 0, stream>>>(Wq, WqTh, WqTl);
  transpose_split<<<dim3(32, 32), blk, 0, stream>>>(Wk, WkTh, WkTl);
  transpose_bf16<<<dim3(32, 32), blk, 0, stream>>>(Wv, WvT);
  transpose_bf16<<<dim3(32, 32), blk, 0, stream>>>(Wo, WoT);

  // Q projection: split MFMA, f32 out [bh][s][dk]
  const dim3 gp(Dd / 128, MROWS / 128, 1);
  mfma_split_nt<0><<<gp, blk, 0, stream>>>(query, WqTh, WqTl, bq, Q,
                                           nullptr, nullptr, MROWS, Dd, Dd);
  // K projection: split MFMA, hi/lo bf16 out [bh][s][dk]
  mfma_split_nt<2><<<gp, blk, 0, stream>>>(key, WkTh, WkTl, bk, nullptr,
                                           Kth, Ktl, MROWS, Dd, Dd);

  // value -> bf16 (into the now-dead WqT/WkT region)
  conv_bf16<<<dim3((int)(PROJ / 1024)), blk, 0, stream>>>(value, vbf, (int)PROJ);

  // V projection -> V^T layout
  mfma_nt<1><<<dim3(Dd / 128, MROWS / 128, 1), blk, 0, stream>>>(
      vbf, WvT, bv, Vt, MROWS, Dd, Dd);

  // fused scores + top-512 + softmax -> weights
  fused_scores_topk<<<dim3(BH * (Ss / 16)), dim3(512), 0, stream>>>(
      Q, Kth, Ktl, wts);

  // PV
  mfma_nt<2><<<dim3(1, Ss / 128, BH), blk, 0, stream>>>(
      wts, Vt, nullptr, attnb, Ss, DKk, Ss);

  // output projection
  mfma_nt<0><<<dim3(Dd / 128, MROWS / 128, 1), blk, 0, stream>>>(
      attnb, WoT, bo, outp, MROWS, Dd, Dd);
}

// Round 9
// 588.035 us; speedup vs baseline: 1.1003x; 1.1003x over previous
//
#include <hip/hip_runtime.h>
#include <hip/hip_bf16.h>
#include <math.h>

namespace {

constexpr int Bb   = 2;
constexpr int Ss   = 2048;
constexpr int Dd   = 1024;
constexpr int Hh   = 8;
constexpr int DKk  = 128;
constexpr int KTOP = 512;
constexpr int BH    = Bb * Hh;   // 16
constexpr int MROWS = Bb * Ss;   // 4096
constexpr float SCALE = 0.08838834764831845f;  // 1/sqrt(128)

typedef __attribute__((ext_vector_type(8))) short short8t;  // 8 bf16 = 16 B
typedef __attribute__((ext_vector_type(4))) short short4t;  // 4 bf16 = 8 B
typedef __attribute__((ext_vector_type(4))) float f32x4;

__device__ inline ushort f2bf(float x) {  // f32 -> bf16 RNE
  const unsigned u = __float_as_uint(x);
  return (ushort)((u + 0x7FFFu + ((u >> 16) & 1u)) >> 16);
}
__device__ inline float bf2f(ushort h) {
  return __uint_as_float(((unsigned)h) << 16);
}
struct HL { short h, l; };
// split x into hi + lo bf16 (hi = RNE(x), lo = RNE(x - hi))
__device__ inline HL split1(float x) {
  HL r;
  const ushort hu = f2bf(x);
  r.h = (short)hu;
  r.l = (short)f2bf(x - bf2f(hu));
  return r;
}

// ---------------------------------------------------------------------------
// Split-bf16 MFMA NT GEMM: C = A @ Bt^T computed as Ah·Bh + Ah·Bl + Al·Bh
// 128x128 tile, BK=32, 4 waves, 16x16x32 bf16 MFMA (~f32 precision).
// MODE 0: proj   — A f32 [M x K] (raw input), Bt pre-split hi/lo bf16 [N x K],
//                  +bias, out f32 scatter to [B,H,S,DK] layout
// MODE 1: scores — A,Bt f32 [z][S][DK] (Q,K), out f32 [z][S][S] * SCALE
// ---------------------------------------------------------------------------
template <int MODE>
__global__ __launch_bounds__(256) void mfma_split_nt(
    const float* __restrict__ Afp, const float* __restrict__ Bfp,
    const ushort* __restrict__ Bth, const ushort* __restrict__ Btl,
    const float* __restrict__ bias, float* __restrict__ Cout,
    int M, int N, int K)
{
  __shared__ ushort Ah[128 * 32];  // 8 KB each
  __shared__ ushort Al[128 * 32];
  __shared__ ushort Bh[128 * 32];
  __shared__ ushort Bl[128 * 32];
  const int t  = threadIdx.x;
  const int z  = blockIdx.z;
  const int n0 = blockIdx.x * 128;
  const int m0 = blockIdx.y * 128;
  const int l  = t & 63, wv = t >> 6;
  const int wr = wv >> 1, wc = wv & 1;     // wave's 64x64 quadrant
  const int lrow = l & 15, lhi = l >> 4;

  const float* Af = (MODE == 1) ? Afp + (size_t)z * Ss * DKk : Afp;
  const float* Bf = (MODE == 1) ? Bfp + (size_t)z * Ss * DKk : nullptr;

  f32x4 acc[4][4] = {};

  for (int kt = 0; kt < K; kt += 32) {
#pragma unroll
    for (int p = 0; p < 2; ++p) {
      const int li = p * 256 + t, row = li >> 2, g = li & 3;
      const int sw = row * 32 + ((g ^ (row & 3)) << 3);
      {  // A: f32 -> hi/lo
        const float* src = Af + (size_t)(m0 + row) * K + kt + g * 8;
        const float4 v0 = *(const float4*)src;
        const float4 v1 = *(const float4*)(src + 4);
        short8t h, lo;
        HL r;
        r = split1(v0.x); h[0] = r.h; lo[0] = r.l;
        r = split1(v0.y); h[1] = r.h; lo[1] = r.l;
        r = split1(v0.z); h[2] = r.h; lo[2] = r.l;
        r = split1(v0.w); h[3] = r.h; lo[3] = r.l;
        r = split1(v1.x); h[4] = r.h; lo[4] = r.l;
        r = split1(v1.y); h[5] = r.h; lo[5] = r.l;
        r = split1(v1.z); h[6] = r.h; lo[6] = r.l;
        r = split1(v1.w); h[7] = r.h; lo[7] = r.l;
        *(short8t*)&Ah[sw] = h;
        *(short8t*)&Al[sw] = lo;
      }
      if constexpr (MODE == 1) {
        const float* src = Bf + (size_t)(n0 + row) * K + kt + g * 8;
        const float4 v0 = *(const float4*)src;
        const float4 v1 = *(const float4*)(src + 4);
        short8t h, lo;
        HL r;
        r = split1(v0.x); h[0] = r.h; lo[0] = r.l;
        r = split1(v0.y); h[1] = r.h; lo[1] = r.l;
        r = split1(v0.z); h[2] = r.h; lo[2] = r.l;
        r = split1(v0.w); h[3] = r.h; lo[3] = r.l;
        r = split1(v1.x); h[4] = r.h; lo[4] = r.l;
        r = split1(v1.y); h[5] = r.h; lo[5] = r.l;
        r = split1(v1.z); h[6] = r.h; lo[6] = r.l;
        r = split1(v1.w); h[7] = r.h; lo[7] = r.l;
        *(short8t*)&Bh[sw] = h;
        *(short8t*)&Bl[sw] = lo;
      } else {
        const size_t off = (size_t)(n0 + row) * K + kt + g * 8;
        *(short8t*)&Bh[sw] = *(const short8t*)(Bth + off);
        *(short8t*)&Bl[sw] = *(const short8t*)(Btl + off);
      }
    }
    __syncthreads();

    short8t ah[4], al[4], bh[4], bl[4];
#pragma unroll
    for (int i = 0; i < 4; ++i) {
      const int row = wr * 64 + i * 16 + lrow;
      const int idx = row * 32 + ((lhi ^ (row & 3)) << 3);
      ah[i] = *(const short8t*)&Ah[idx];
      al[i] = *(const short8t*)&Al[idx];
    }
#pragma unroll
    for (int j = 0; j < 4; ++j) {
      const int row = wc * 64 + j * 16 + lrow;
      const int idx = row * 32 + ((lhi ^ (row & 3)) << 3);
      bh[j] = *(const short8t*)&Bh[idx];
      bl[j] = *(const short8t*)&Bl[idx];
    }
#pragma unroll
    for (int i = 0; i < 4; ++i)
#pragma unroll
      for (int j = 0; j < 4; ++j) {
        acc[i][j] = __builtin_amdgcn_mfma_f32_16x16x32_bf16(ah[i], bh[j], acc[i][j], 0, 0, 0);
        acc[i][j] = __builtin_amdgcn_mfma_f32_16x16x32_bf16(ah[i], bl[j], acc[i][j], 0, 0, 0);
        acc[i][j] = __builtin_amdgcn_mfma_f32_16x16x32_bf16(al[i], bh[j], acc[i][j], 0, 0, 0);
      }
    __syncthreads();
  }

  // epilogue: C/D layout col=lane&15, row=(lane>>4)*4+reg
#pragma unroll
  for (int i = 0; i < 4; ++i) {
#pragma unroll
    for (int j = 0; j < 4; ++j) {
      const int nn = n0 + wc * 64 + j * 16 + lrow;
#pragma unroll
      for (int r = 0; r < 4; ++r) {
        const int mm = m0 + wr * 64 + i * 16 + lhi * 4 + r;
        if constexpr (MODE == 0) {
          const float v = acc[i][j][r] + bias[nn];
          const int bb = mm >> 11, s = mm & (Ss - 1);
          const int hh = nn >> 7,  dk = nn & (DKk - 1);
          Cout[(((size_t)(bb * Hh + hh)) * Ss + s) * DKk + dk] = v;
        } else {
          Cout[(size_t)z * Ss * Ss + (size_t)mm * Ss + nn] = acc[i][j][r] * SCALE;
        }
      }
    }
  }
}

// ---------------------------------------------------------------------------
// bf16 MFMA NT GEMM (plain): C[M x N] = A[M x K] @ Bt[N x K]^T  (+bias)
// MODE 0: o_proj — A bf16, out f32 row-major, +bias
// MODE 1: v_proj — A bf16, out bf16 scatter Vt[bh][dk][s], +bias
// MODE 2: pv     — A f32 (weights, batched z=bh), out bf16 attn[B,S,D]
// ---------------------------------------------------------------------------
template <int MODE>
__global__ __launch_bounds__(256) void mfma_nt(
    const void* __restrict__ Ain, const ushort* __restrict__ BtAll,
    const float* __restrict__ bias, void* __restrict__ Cout,
    int M, int N, int K)
{
  __shared__ ushort As[128 * 64];  // 16 KB
  __shared__ ushort Bs[128 * 64];  // 16 KB
  const int t  = threadIdx.x;
  const int z  = blockIdx.z;
  const int n0 = blockIdx.x * 128;
  const int m0 = blockIdx.y * 128;
  const int l  = t & 63, wv = t >> 6;
  const int wr = wv >> 1, wc = wv & 1;
  const int lrow = l & 15, lhi = l >> 4;

  const float*  Af = (MODE == 2) ? ((const float*)Ain) + (size_t)z * Ss * Ss : nullptr;
  const ushort* Ab = (MODE == 2) ? nullptr : (const ushort*)Ain;
  const ushort* Bt = (MODE == 2) ? BtAll + (size_t)z * DKk * Ss : BtAll;

  f32x4 acc[4][4] = {};

  for (int kt = 0; kt < K; kt += 64) {
#pragma unroll
    for (int p = 0; p < 4; ++p) {
      const int li = p * 256 + t, row = li >> 3, g = li & 7;
      const int sw = row * 64 + ((g ^ (row & 7)) << 3);
      short8t sa;
      if constexpr (MODE == 2) {
        const float* src = Af + (size_t)(m0 + row) * K + kt + g * 8;
        const float4 v0 = *(const float4*)src;
        const float4 v1 = *(const float4*)(src + 4);
        sa[0] = (short)f2bf(v0.x); sa[1] = (short)f2bf(v0.y);
        sa[2] = (short)f2bf(v0.z); sa[3] = (short)f2bf(v0.w);
        sa[4] = (short)f2bf(v1.x); sa[5] = (short)f2bf(v1.y);
        sa[6] = (short)f2bf(v1.z); sa[7] = (short)f2bf(v1.w);
      } else {
        sa = *(const short8t*)(Ab + (size_t)(m0 + row) * K + kt + g * 8);
      }
      *(short8t*)&As[sw] = sa;
      const short8t sb = *(const short8t*)(Bt + (size_t)(n0 + row) * K + kt + g * 8);
      *(short8t*)&Bs[sw] = sb;
    }
    __syncthreads();

#pragma unroll
    for (int kk = 0; kk < 2; ++kk) {
      short8t a[4], b[4];
      const int g = kk * 4 + lhi;
#pragma unroll
      for (int i = 0; i < 4; ++i) {
        const int row = wr * 64 + i * 16 + lrow;
        a[i] = *(const short8t*)&As[row * 64 + ((g ^ (row & 7)) << 3)];
      }
#pragma unroll
      for (int j = 0; j < 4; ++j) {
        const int row = wc * 64 + j * 16 + lrow;
        b[j] = *(const short8t*)&Bs[row * 64 + ((g ^ (row & 7)) << 3)];
      }
#pragma unroll
      for (int i = 0; i < 4; ++i)
#pragma unroll
        for (int j = 0; j < 4; ++j)
          acc[i][j] = __builtin_amdgcn_mfma_f32_16x16x32_bf16(a[i], b[j], acc[i][j], 0, 0, 0);
    }
    __syncthreads();
  }

#pragma unroll
  for (int i = 0; i < 4; ++i) {
#pragma unroll
    for (int j = 0; j < 4; ++j) {
      const int nn = n0 + wc * 64 + j * 16 + lrow;
#pragma unroll
      for (int r = 0; r < 4; ++r) {
        const int mm = m0 + wr * 64 + i * 16 + lhi * 4 + r;
        const float v = acc[i][j][r];
        if constexpr (MODE == 0) {
          ((float*)Cout)[(size_t)mm * N + nn] = v + bias[nn];
        } else if constexpr (MODE == 1) {
          const int bb = mm >> 11, s = mm & (Ss - 1);
          const int hh = nn >> 7,  dk = nn & (DKk - 1);
          ((ushort*)Cout)[((size_t)((bb * Hh + hh) * DKk + dk)) * Ss + s] =
              f2bf(v + bias[nn]);
        } else {
          const int bb = z >> 3, hh = z & 7;
          ((ushort*)Cout)[((size_t)(bb * Ss + mm)) * Dd + hh * DKk + nn] = f2bf(v);
        }
      }
    }
  }
}

// ---------------------------------------------------------------------------
// f32 -> bf16 elementwise conversion
// ---------------------------------------------------------------------------
__global__ __launch_bounds__(256) void conv_bf16(
    const float* __restrict__ in, ushort* __restrict__ out, int n)
{
  const int i = (blockIdx.x * 256 + threadIdx.x) * 4;
  if (i < n) {
    const float4 v = *(const float4*)(in + i);
    short4t o;
    o[0] = (short)f2bf(v.x); o[1] = (short)f2bf(v.y);
    o[2] = (short)f2bf(v.z); o[3] = (short)f2bf(v.w);
    *(short4t*)(out + i) = o;
  }
}

// ---------------------------------------------------------------------------
// W[1024][1024] f32 -> Wt bf16 (transposed), plain
// ---------------------------------------------------------------------------
__global__ __launch_bounds__(256) void transpose_bf16(
    const float* __restrict__ W, ushort* __restrict__ Wt)
{
  __shared__ float tile[32][33];
  const int t  = threadIdx.x;
  const int c0 = blockIdx.x * 32, r0 = blockIdx.y * 32;
  const int lr = t >> 3, lc4 = (t & 7) * 4;
  const float4 v = *(const float4*)(W + (size_t)(r0 + lr) * Dd + c0 + lc4);
  tile[lr][lc4 + 0] = v.x; tile[lr][lc4 + 1] = v.y;
  tile[lr][lc4 + 2] = v.z; tile[lr][lc4 + 3] = v.w;
  __syncthreads();
  const int oc = t >> 3, or4 = (t & 7) * 4;
  short4t o;
  o[0] = (short)f2bf(tile[or4 + 0][oc]);
  o[1] = (short)f2bf(tile[or4 + 1][oc]);
  o[2] = (short)f2bf(tile[or4 + 2][oc]);
  o[3] = (short)f2bf(tile[or4 + 3][oc]);
  *(short4t*)(Wt + (size_t)(c0 + oc) * Dd + r0 + or4) = o;
}

// ---------------------------------------------------------------------------
// W[1024][1024] f32 -> transposed hi/lo bf16 split
// ---------------------------------------------------------------------------
__global__ __launch_bounds__(256) void transpose_split(
    const float* __restrict__ W, ushort* __restrict__ Th, ushort* __restrict__ Tl)
{
  __shared__ float tile[32][33];
  const int t  = threadIdx.x;
  const int c0 = blockIdx.x * 32, r0 = blockIdx.y * 32;
  const int lr = t >> 3, lc4 = (t & 7) * 4;
  const float4 v = *(const float4*)(W + (size_t)(r0 + lr) * Dd + c0 + lc4);
  tile[lr][lc4 + 0] = v.x; tile[lr][lc4 + 1] = v.y;
  tile[lr][lc4 + 2] = v.z; tile[lr][lc4 + 3] = v.w;
  __syncthreads();
  const int oc = t >> 3, or4 = (t & 7) * 4;
  short4t oh, ol;
  HL r;
  r = split1(tile[or4 + 0][oc]); oh[0] = r.h; ol[0] = r.l;
  r = split1(tile[or4 + 1][oc]); oh[1] = r.h; ol[1] = r.l;
  r = split1(tile[or4 + 2][oc]); oh[2] = r.h; ol[2] = r.l;
  r = split1(tile[or4 + 3][oc]); oh[3] = r.h; ol[3] = r.l;
  *(short4t*)(Th + (size_t)(c0 + oc) * Dd + r0 + or4) = oh;
  *(short4t*)(Tl + (size_t)(c0 + oc) * Dd + r0 + or4) = ol;
}

__device__ inline unsigned key_of(float v) {
  const unsigned u = __float_as_uint(v);
  return (u & 0x80000000u) ? ~u : (u | 0x80000000u);
}
__device__ inline float key_to_float(unsigned k) {
  const unsigned u = (k & 0x80000000u) ? (k & 0x7FFFFFFFu) : ~k;
  return __uint_as_float(u);
}

// ---------------------------------------------------------------------------
// Per-row exact top-512 + softmax, in place.
// v4: single 11-bit histogram pass (2048 bins, naturally spread -> low atomic
// contention), ballot-compacted candidates of the threshold bin (C1 ~ 20-60),
// exact in-wave all-pairs ranking over the candidates (replaces radix passes
// 2-4 entirely), register-held exp/normalize (no LDS w_pre round trip).
// Exact radix fallback if C1 > 128 (statistically never; correctness always).
// ---------------------------------------------------------------------------
__global__ __launch_bounds__(256) void topk_softmax(float* __restrict__ wts)
{
  __shared__ unsigned keys[Ss];       // 8 KB
  __shared__ unsigned hist[2048];     // 8 KB (11-bit bins; low 256 reused in fallback)
  __shared__ unsigned candK[128];
  __shared__ unsigned wredA[4];
  __shared__ unsigned wredB[4];
  __shared__ float    fred[4];
  __shared__ unsigned sBin, sNeedK, sTie, sCnt, sT;

  const int t    = threadIdx.x;
  const int lane = t & 63;
  const int wv   = t >> 6;
  float* rowp = wts + (size_t)blockIdx.x * Ss;

  {
    const uint4 zz = {0u, 0u, 0u, 0u};
    *(uint4*)&hist[t * 8]     = zz;
    *(uint4*)&hist[t * 8 + 4] = zz;
  }
  if (t == 0) sCnt = 0u;
  __syncthreads();

  // ---- sweep 1: load, keys, 11-bit histogram, running max ----
  unsigned lmax = 0u;
#pragma unroll
  for (int base = 0; base < Ss; base += 1024) {
    const float4 v = *(const float4*)(rowp + base + 4 * t);
    uint4 k;
    k.x = key_of(v.x); k.y = key_of(v.y); k.z = key_of(v.z); k.w = key_of(v.w);
    lmax = max(max(lmax, max(k.x, k.y)), max(k.z, k.w));
    *(uint4*)&keys[base + 4 * t] = k;
    atomicAdd(&hist[k.x >> 21], 1u);
    atomicAdd(&hist[k.y >> 21], 1u);
    atomicAdd(&hist[k.z >> 21], 1u);
    atomicAdd(&hist[k.w >> 21], 1u);
  }
#pragma unroll
  for (int off = 32; off > 0; off >>= 1) lmax = max(lmax, __shfl_xor(lmax, off));
  if (lane == 0) wredA[wv] = lmax;
  __syncthreads();
  const float m = key_to_float(max(max(wredA[0], wredA[1]), max(wredA[2], wredA[3])));

  // ---- scan 2048 bins: suffix-sum from top, find threshold bin ----
  unsigned needK = KTOP, b1, tieC;
  {
    unsigned b[8], lsum = 0u;
#pragma unroll
    for (int i = 0; i < 8; ++i) { b[i] = hist[t * 8 + i]; lsum += b[i]; }
    unsigned s = lsum;
#pragma unroll
    for (int off = 1; off < 64; off <<= 1) {
      const unsigned v = __shfl_down(s, off);
      if (lane + off < 64) s += v;
    }
    if (lane == 0) wredB[wv] = s;
    __syncthreads();
    unsigned stot = s;
    for (int w2 = wv + 1; w2 < 4; ++w2) stot += wredB[w2];
    unsigned run = stot - lsum;  // count in bins strictly above mine
    unsigned fb = 0u, fn = 0u, ft = 0u;
    bool found = false;
#pragma unroll
    for (int i = 7; i >= 0; --i) {
      const unsigned c = b[i];
      if (!found && c > 0u && run < needK && run + c >= needK) {
        found = true; fb = (unsigned)(t * 8 + i); fn = needK - run; ft = c;
      }
      run += c;
    }
    if (found) { sBin = fb; sNeedK = fn; sTie = ft; }
    __syncthreads();
    b1 = sBin; needK = sNeedK; tieC = sTie;
  }

  // ---- compact candidates of bin b1 (ballot-aggregated, cap 128) ----
#pragma unroll
  for (int base = 0; base < Ss; base += 1024) {
    const uint4 k = *(const uint4*)&keys[base + 4 * t];
    const unsigned a[4] = {k.x, k.y, k.z, k.w};
#pragma unroll
    for (int c = 0; c < 4; ++c) {
      const bool f = ((a[c] >> 21) == b1);
      const unsigned long long msk = __ballot(f);
      if (msk) {
        const int ldr = (int)__ffsll(msk) - 1;
        unsigned bidx = 0u;
        if (lane == ldr) bidx = atomicAdd(&sCnt, (unsigned)__popcll(msk));
        bidx = __shfl(bidx, ldr);
        if (f) {
          const unsigned pos = bidx + (unsigned)__popcll(msk & ((1ull << lane) - 1ull));
          if (pos < 128u) candK[pos] = a[c];
        }
      }
    }
  }
  __syncthreads();
  const unsigned C1 = sCnt;
  unsigned T;

  if (C1 <= 128u) {
    // ---- exact rank among candidates, wave 0 only ----
    if (wv == 0) {
      const bool va = (unsigned)lane < C1;
      const bool vb = (unsigned)(lane + 64) < C1;
      const unsigned ka = va ? candK[lane] : 0u;
      const unsigned kb = vb ? candK[lane + 64] : 0u;
      unsigned ga = 0u, ea = 0u, gb = 0u, eb = 0u;
      for (unsigned j = 0; j < C1; ++j) {
        const unsigned kj = (j < 64u) ? __shfl(ka, (int)j) : __shfl(kb, (int)(j - 64u));
        ga += (kj > ka); ea += (kj == ka);
        gb += (kj > kb); eb += (kj == kb);
      }
      const bool fa = va && (ga < needK) && (ga + ea >= needK);
      const bool fb2 = vb && (gb < needK) && (gb + eb >= needK);
      const unsigned myT    = fa ? ka : kb;
      const unsigned myNeed = fa ? (needK - ga) : (needK - gb);
      const unsigned myTie  = fa ? ea : eb;
      const unsigned long long mm = __ballot(fa || fb2);
      const int src = (int)__ffsll(mm) - 1;
      if (lane == src) { sT = myT; sNeedK = myNeed; sTie = myTie; }
    }
    __syncthreads();
    T = sT; needK = sNeedK; tieC = sTie;
  } else {
    // ---- ultra-rare exact fallback: radix on bits [20:13],[12:5],[4:0] ----
    unsigned prefix = b1 << 21;
    unsigned maskHi = 0xFFE00000u;
    for (int p = 0; p < 3; ++p) {
      const int sh = (p == 0) ? 13 : (p == 1) ? 5 : 0;
      const unsigned bmask = (p < 2) ? 255u : 31u;
      if (t < 256) hist[t] = 0u;
      __syncthreads();
      for (int i = t; i < Ss; i += 256) {
        const unsigned k = keys[i];
        if ((k & maskHi) == prefix) atomicAdd(&hist[(k >> sh) & bmask], 1u);
      }
      __syncthreads();
      const unsigned h = ((unsigned)t <= bmask) ? hist[t] : 0u;
      unsigned s = h;
      for (int off = 1; off < 64; off <<= 1) {
        const unsigned v = __shfl_down(s, off);
        if (lane + off < 64) s += v;
      }
      if (lane == 0) wredB[wv] = s;
      __syncthreads();
      unsigned stot = s;
      for (int w2 = wv + 1; w2 < 4; ++w2) stot += wredB[w2];
      if (h > 0u && stot >= needK && stot - h < needK) {
        sBin = (unsigned)t; sNeedK = needK - (stot - h); sTie = h;
      }
      __syncthreads();
      prefix |= sBin << sh;
      needK = sNeedK; tieC = sTie;
      maskHi |= bmask << sh;
      __syncthreads();
    }
    T = prefix;
  }

  // ---- rare: duplicates of T straddle the boundary -> keep lowest indices ----
  if (tieC != needK) {
    if (t == 0) {
      unsigned taken = 0u;
      for (int i = 0; i < Ss; ++i)
        if (keys[i] == T) { if (taken < needK) ++taken; else keys[i] = 0u; }
    }
    __syncthreads();
  }
  // invariant: count(keys == T) == needK; selected = (keys >= T)

  // ---- exp sweep (register-held) + Z reduce + normalized store ----
  float w[8];
  float lz = 0.f;
#pragma unroll
  for (int half = 0; half < 2; ++half) {
    const int i0 = half * 1024 + 4 * t;
    const uint4 k = *(const uint4*)&keys[i0];
    w[half * 4 + 0] = (k.x >= T) ? __expf(key_to_float(k.x) - m) : 0.f;
    w[half * 4 + 1] = (k.y >= T) ? __expf(key_to_float(k.y) - m) : 0.f;
    w[half * 4 + 2] = (k.z >= T) ? __expf(key_to_float(k.z) - m) : 0.f;
    w[half * 4 + 3] = (k.w >= T) ? __expf(key_to_float(k.w) - m) : 0.f;
    lz += (w[half * 4 + 0] + w[half * 4 + 1]) + (w[half * 4 + 2] + w[half * 4 + 3]);
  }
#pragma unroll
  for (int off = 32; off > 0; off >>= 1) lz += __shfl_xor(lz, off);
  if (lane == 0) fred[wv] = lz;
  __syncthreads();
  const float Zi = 1.0f / (fred[0] + fred[1] + fred[2] + fred[3]);

#pragma unroll
  for (int half = 0; half < 2; ++half) {
    const int i0 = half * 1024 + 4 * t;
    float4 o;
    o.x = w[half * 4 + 0] * Zi;
    o.y = w[half * 4 + 1] * Zi;
    o.z = w[half * 4 + 2] * Zi;
    o.w = w[half * 4 + 3] * Zi;
    *(float4*)(rowp + i0) = o;
  }
}

}  // namespace

extern "C" void kernel_launch(void* const* d_in, const int* in_sizes, int n_in,
                              void* d_out_v, int out_size, void* d_ws, size_t ws_size,
                              hipStream_t stream)
{
  const float* query = (const float*)d_in[0];
  const float* key   = (const float*)d_in[1];
  const float* value = (const float*)d_in[2];
  const float* Wq = (const float*)d_in[3];  const float* bq = (const float*)d_in[4];
  const float* Wk = (const float*)d_in[5];  const float* bk = (const float*)d_in[6];
  const float* Wv = (const float*)d_in[7];  const float* bv = (const float*)d_in[8];
  const float* Wo = (const float*)d_in[9];  const float* bo = (const float*)d_in[10];

  float* d_out = (float*)d_out_v;
  float* outp  = d_out;                              // [B,S,D] f32
  float* wts   = d_out + (size_t)Bb * Ss * Dd;       // [B,H,S,S] f32

  const size_t PROJ = (size_t)MROWS * Dd;            // 4M elements
  const size_t DD2  = (size_t)Dd * Dd;               // 1M elements

  float*  ws    = (float*)d_ws;
  float*  Q     = ws;                                // f32 [BH][S][DK]  16 MB
  float*  Kw    = Q + PROJ;                          // f32 [BH][S][DK]  16 MB
  ushort* r3    = (ushort*)(Kw + PROJ);              // 8 MB region
  ushort* WqTh  = r3;                                //   Wq^T hi
  ushort* WqTl  = r3 + DD2;                          //   Wq^T lo
  ushort* WkTh  = r3 + 2 * DD2;                      //   Wk^T hi
  ushort* WkTl  = r3 + 3 * DD2;                      //   Wk^T lo
  ushort* vbf   = r3;                                //   (aliases after K proj)
  ushort* WvT   = r3 + 4 * DD2;                      // 2 MB
  ushort* WoT   = WvT + DD2;                         // 2 MB
  ushort* Vt    = WoT + DD2;                         // bf16 V^T [16][128][2048] 8 MB
  ushort* attnb = Vt + (size_t)BH * DKk * Ss;        // bf16 attn [4096][1024]  8 MB

  const dim3 blk(256);

  // weight prep
  transpose_split<<<dim3(32, 32), blk, 0, stream>>>(Wq, WqTh, WqTl);
  transpose_split<<<dim3(32, 32), blk, 0, stream>>>(Wk, WkTh, WkTl);
  transpose_bf16<<<dim3(32, 32), blk, 0, stream>>>(Wv, WvT);
  transpose_bf16<<<dim3(32, 32), blk, 0, stream>>>(Wo, WoT);

  // Q/K projections: split-bf16 MFMA (~f32 precision), out f32 [BH][S][DK]
  const dim3 gp(Dd / 128, MROWS / 128, 1);
  mfma_split_nt<0><<<gp, blk, 0, stream>>>(query, nullptr, WqTh, WqTl, bq, Q,
                                           MROWS, Dd, Dd);
  mfma_split_nt<0><<<gp, blk, 0, stream>>>(key, nullptr, WkTh, WkTl, bk, Kw,
                                           MROWS, Dd, Dd);

  // value -> bf16 (into the now-dead WqT/WkT region)
  conv_bf16<<<dim3((int)(PROJ / 1024)), blk, 0, stream>>>(value, vbf, (int)PROJ);

  // V projection (plain bf16 MFMA) -> V^T layout
  mfma_nt<1><<<dim3(Dd / 128, MROWS / 128, 1), blk, 0, stream>>>(
      vbf, WvT, bv, Vt, MROWS, Dd, Dd);

  // scores: split-bf16 MFMA, inline split of Q and K, out f32 * SCALE
  mfma_split_nt<1><<<dim3(Ss / 128, Ss / 128, BH), blk, 0, stream>>>(
      Q, Kw, nullptr, nullptr, nullptr, wts, Ss, Ss, DKk);

  // exact top-512 + softmax, in place
  topk_softmax<<<dim3(BH * Ss), blk, 0, stream>>>(wts);

  // PV (bf16 MFMA, stages f32 weights with inline conversion)
  mfma_nt<2><<<dim3(1, Ss / 128, BH), blk, 0, stream>>>(
      wts, Vt, nullptr, attnb, Ss, DKk, Ss);

  // output projection (bf16 MFMA, f32 out)
  mfma_nt<0><<<dim3(Dd / 128, MROWS / 128, 1), blk, 0, stream>>>(
      attnb, WoT, bo, outp, MROWS, Dd, Dd);
}

// Round 10
// 538.363 us; speedup vs baseline: 1.2019x; 1.0923x over previous
//
#include <hip/hip_runtime.h>
#include <hip/hip_bf16.h>
#include <math.h>

namespace {

constexpr int Bb   = 2;
constexpr int Ss   = 2048;
constexpr int Dd   = 1024;
constexpr int Hh   = 8;
constexpr int DKk  = 128;
constexpr int KTOP = 512;
constexpr int BH    = Bb * Hh;   // 16
constexpr int MROWS = Bb * Ss;   // 4096
constexpr float SCALE = 0.08838834764831845f;  // 1/sqrt(128)

typedef __attribute__((ext_vector_type(8))) short short8t;  // 8 bf16 = 16 B
typedef __attribute__((ext_vector_type(4))) short short4t;  // 4 bf16 = 8 B
typedef __attribute__((ext_vector_type(4))) float f32x4;

__device__ inline ushort f2bf(float x) {  // f32 -> bf16 RNE
  const unsigned u = __float_as_uint(x);
  return (ushort)((u + 0x7FFFu + ((u >> 16) & 1u)) >> 16);
}
__device__ inline float bf2f(ushort h) {
  return __uint_as_float(((unsigned)h) << 16);
}
struct HL { short h, l; };
__device__ inline HL split1(float x) {
  HL r;
  const ushort hu = f2bf(x);
  r.h = (short)hu;
  r.l = (short)f2bf(x - bf2f(hu));
  return r;
}

__device__ inline unsigned key_of(float v) {
  const unsigned u = __float_as_uint(v);
  return (u & 0x80000000u) ? ~u : (u | 0x80000000u);
}
__device__ inline float key_to_float(unsigned k) {
  const unsigned u = (k & 0x80000000u) ? (k & 0x7FFFFFFFu) : ~k;
  return __uint_as_float(u);
}

// ---------------------------------------------------------------------------
// Batched Q/K/V projection, split-bf16 MFMA NT (Ah·Bh + Ah·Bl + Al·Bh).
// grid z: 0=Q, 1=K (out: hi/lo bf16 [bh][s][dk]), 2=V (out: bf16 Vt[bh][dk][s])
// 128x128 tile, BK=32, 4 waves. 768 blocks -> 3 blocks/CU.
// ---------------------------------------------------------------------------
__global__ __launch_bounds__(256) void mfma_proj(
    const float* __restrict__ query, const float* __restrict__ keyi,
    const float* __restrict__ value,
    const ushort* __restrict__ WqTh, const ushort* __restrict__ WqTl,
    const ushort* __restrict__ WkTh, const ushort* __restrict__ WkTl,
    const ushort* __restrict__ WvTh, const ushort* __restrict__ WvTl,
    const float* __restrict__ bq, const float* __restrict__ bk,
    const float* __restrict__ bv,
    ushort* __restrict__ Qh, ushort* __restrict__ Ql,
    ushort* __restrict__ Kh, ushort* __restrict__ Kl,
    ushort* __restrict__ Vt)
{
  __shared__ ushort Ah[128 * 32];
  __shared__ ushort Al[128 * 32];
  __shared__ ushort Bh[128 * 32];
  __shared__ ushort Bl[128 * 32];
  const int t  = threadIdx.x;
  const int z  = blockIdx.z;
  const int n0 = blockIdx.x * 128;
  const int m0 = blockIdx.y * 128;
  const int l  = t & 63, wv = t >> 6;
  const int wr = wv >> 1, wc = wv & 1;
  const int lrow = l & 15, lhi = l >> 4;

  const float*  A    = (z == 0) ? query : (z == 1) ? keyi : value;
  const ushort* Bth  = (z == 0) ? WqTh  : (z == 1) ? WkTh : WvTh;
  const ushort* Btl  = (z == 0) ? WqTl  : (z == 1) ? WkTl : WvTl;
  const float*  bias = (z == 0) ? bq    : (z == 1) ? bk   : bv;

  f32x4 acc[4][4] = {};

  for (int kt = 0; kt < Dd; kt += 32) {
#pragma unroll
    for (int p = 0; p < 2; ++p) {
      const int li = p * 256 + t, row = li >> 2, g = li & 3;
      const int sw = row * 32 + ((g ^ (row & 3)) << 3);
      {
        const float* src = A + (size_t)(m0 + row) * Dd + kt + g * 8;
        const float4 v0 = *(const float4*)src;
        const float4 v1 = *(const float4*)(src + 4);
        short8t h, lo;
        HL r;
        r = split1(v0.x); h[0] = r.h; lo[0] = r.l;
        r = split1(v0.y); h[1] = r.h; lo[1] = r.l;
        r = split1(v0.z); h[2] = r.h; lo[2] = r.l;
        r = split1(v0.w); h[3] = r.h; lo[3] = r.l;
        r = split1(v1.x); h[4] = r.h; lo[4] = r.l;
        r = split1(v1.y); h[5] = r.h; lo[5] = r.l;
        r = split1(v1.z); h[6] = r.h; lo[6] = r.l;
        r = split1(v1.w); h[7] = r.h; lo[7] = r.l;
        *(short8t*)&Ah[sw] = h;
        *(short8t*)&Al[sw] = lo;
      }
      const size_t off = (size_t)(n0 + row) * Dd + kt + g * 8;
      *(short8t*)&Bh[sw] = *(const short8t*)(Bth + off);
      *(short8t*)&Bl[sw] = *(const short8t*)(Btl + off);
    }
    __syncthreads();

    short8t ah[4], al[4], bh[4], bl[4];
#pragma unroll
    for (int i = 0; i < 4; ++i) {
      const int row = wr * 64 + i * 16 + lrow;
      const int idx = row * 32 + ((lhi ^ (row & 3)) << 3);
      ah[i] = *(const short8t*)&Ah[idx];
      al[i] = *(const short8t*)&Al[idx];
    }
#pragma unroll
    for (int j = 0; j < 4; ++j) {
      const int row = wc * 64 + j * 16 + lrow;
      const int idx = row * 32 + ((lhi ^ (row & 3)) << 3);
      bh[j] = *(const short8t*)&Bh[idx];
      bl[j] = *(const short8t*)&Bl[idx];
    }
#pragma unroll
    for (int i = 0; i < 4; ++i)
#pragma unroll
      for (int j = 0; j < 4; ++j) {
        acc[i][j] = __builtin_amdgcn_mfma_f32_16x16x32_bf16(ah[i], bh[j], acc[i][j], 0, 0, 0);
        acc[i][j] = __builtin_amdgcn_mfma_f32_16x16x32_bf16(ah[i], bl[j], acc[i][j], 0, 0, 0);
        acc[i][j] = __builtin_amdgcn_mfma_f32_16x16x32_bf16(al[i], bh[j], acc[i][j], 0, 0, 0);
      }
    __syncthreads();
  }

#pragma unroll
  for (int i = 0; i < 4; ++i) {
#pragma unroll
    for (int j = 0; j < 4; ++j) {
      const int nn = n0 + wc * 64 + j * 16 + lrow;
#pragma unroll
      for (int r = 0; r < 4; ++r) {
        const int mm = m0 + wr * 64 + i * 16 + lhi * 4 + r;
        const float v = acc[i][j][r] + bias[nn];
        const int bb = mm >> 11, s = mm & (Ss - 1);
        const int hh = nn >> 7,  dk = nn & (DKk - 1);
        if (z < 2) {
          const size_t o = (((size_t)(bb * Hh + hh)) * Ss + s) * DKk + dk;
          const HL rr = split1(v);
          if (z == 0) { Qh[o] = (ushort)rr.h; Ql[o] = (ushort)rr.l; }
          else        { Kh[o] = (ushort)rr.h; Kl[o] = (ushort)rr.l; }
        } else {
          Vt[((size_t)((bb * Hh + hh) * DKk + dk)) * Ss + s] = f2bf(v);
        }
      }
    }
  }
}

// ---------------------------------------------------------------------------
// Scores from pre-split Q,K: 3 MFMAs per frag pair, no split VALU.
// Epilogue writes order-flipped u32 keys of (score * SCALE) into wts region.
// grid (S/128, S/128, BH).
// ---------------------------------------------------------------------------
__global__ __launch_bounds__(256) void mfma_scores(
    const ushort* __restrict__ Qh, const ushort* __restrict__ Ql,
    const ushort* __restrict__ Kh, const ushort* __restrict__ Kl,
    unsigned* __restrict__ wtsOut)
{
  __shared__ ushort Ah[128 * 32];
  __shared__ ushort Al[128 * 32];
  __shared__ ushort Bh[128 * 32];
  __shared__ ushort Bl[128 * 32];
  const int t  = threadIdx.x;
  const int z  = blockIdx.z;
  const int n0 = blockIdx.x * 128;   // j
  const int m0 = blockIdx.y * 128;   // q
  const int l  = t & 63, wv = t >> 6;
  const int wr = wv >> 1, wc = wv & 1;
  const int lrow = l & 15, lhi = l >> 4;
  const size_t boff = (size_t)z * Ss * DKk;

  f32x4 acc[4][4] = {};

  for (int kt = 0; kt < DKk; kt += 32) {
#pragma unroll
    for (int p = 0; p < 2; ++p) {
      const int li = p * 256 + t, row = li >> 2, g = li & 3;
      const int sw = row * 32 + ((g ^ (row & 3)) << 3);
      const size_t ao = boff + (size_t)(m0 + row) * DKk + kt + g * 8;
      *(short8t*)&Ah[sw] = *(const short8t*)(Qh + ao);
      *(short8t*)&Al[sw] = *(const short8t*)(Ql + ao);
      const size_t bo = boff + (size_t)(n0 + row) * DKk + kt + g * 8;
      *(short8t*)&Bh[sw] = *(const short8t*)(Kh + bo);
      *(short8t*)&Bl[sw] = *(const short8t*)(Kl + bo);
    }
    __syncthreads();

    short8t ah[4], al[4], bh[4], bl[4];
#pragma unroll
    for (int i = 0; i < 4; ++i) {
      const int row = wr * 64 + i * 16 + lrow;
      const int idx = row * 32 + ((lhi ^ (row & 3)) << 3);
      ah[i] = *(const short8t*)&Ah[idx];
      al[i] = *(const short8t*)&Al[idx];
    }
#pragma unroll
    for (int j = 0; j < 4; ++j) {
      const int row = wc * 64 + j * 16 + lrow;
      const int idx = row * 32 + ((lhi ^ (row & 3)) << 3);
      bh[j] = *(const short8t*)&Bh[idx];
      bl[j] = *(const short8t*)&Bl[idx];
    }
#pragma unroll
    for (int i = 0; i < 4; ++i)
#pragma unroll
      for (int j = 0; j < 4; ++j) {
        acc[i][j] = __builtin_amdgcn_mfma_f32_16x16x32_bf16(ah[i], bh[j], acc[i][j], 0, 0, 0);
        acc[i][j] = __builtin_amdgcn_mfma_f32_16x16x32_bf16(ah[i], bl[j], acc[i][j], 0, 0, 0);
        acc[i][j] = __builtin_amdgcn_mfma_f32_16x16x32_bf16(al[i], bh[j], acc[i][j], 0, 0, 0);
      }
    __syncthreads();
  }

#pragma unroll
  for (int i = 0; i < 4; ++i)
#pragma unroll
    for (int j = 0; j < 4; ++j) {
      const int nn = n0 + wc * 64 + j * 16 + lrow;
#pragma unroll
      for (int r = 0; r < 4; ++r) {
        const int mm = m0 + wr * 64 + i * 16 + lhi * 4 + r;
        wtsOut[(size_t)z * Ss * Ss + (size_t)mm * Ss + nn] =
            key_of(acc[i][j][r] * SCALE);
      }
    }
}

// ---------------------------------------------------------------------------
// bf16 MFMA NT (o_proj only): C = A @ Bt^T + bias, A bf16, out f32 row-major
// ---------------------------------------------------------------------------
__global__ __launch_bounds__(256) void mfma_oproj(
    const ushort* __restrict__ Ab, const ushort* __restrict__ Bt,
    const float* __restrict__ bias, float* __restrict__ Cout)
{
  __shared__ ushort As[128 * 64];
  __shared__ ushort Bs[128 * 64];
  const int t  = threadIdx.x;
  const int n0 = blockIdx.x * 128;
  const int m0 = blockIdx.y * 128;
  const int l  = t & 63, wv = t >> 6;
  const int wr = wv >> 1, wc = wv & 1;
  const int lrow = l & 15, lhi = l >> 4;

  f32x4 acc[4][4] = {};

  for (int kt = 0; kt < Dd; kt += 64) {
#pragma unroll
    for (int p = 0; p < 4; ++p) {
      const int li = p * 256 + t, row = li >> 3, g = li & 7;
      const int sw = row * 64 + ((g ^ (row & 7)) << 3);
      *(short8t*)&As[sw] = *(const short8t*)(Ab + (size_t)(m0 + row) * Dd + kt + g * 8);
      *(short8t*)&Bs[sw] = *(const short8t*)(Bt + (size_t)(n0 + row) * Dd + kt + g * 8);
    }
    __syncthreads();

#pragma unroll
    for (int kk = 0; kk < 2; ++kk) {
      short8t a[4], b[4];
      const int g = kk * 4 + lhi;
#pragma unroll
      for (int i = 0; i < 4; ++i) {
        const int row = wr * 64 + i * 16 + lrow;
        a[i] = *(const short8t*)&As[row * 64 + ((g ^ (row & 7)) << 3)];
      }
#pragma unroll
      for (int j = 0; j < 4; ++j) {
        const int row = wc * 64 + j * 16 + lrow;
        b[j] = *(const short8t*)&Bs[row * 64 + ((g ^ (row & 7)) << 3)];
      }
#pragma unroll
      for (int i = 0; i < 4; ++i)
#pragma unroll
        for (int j = 0; j < 4; ++j)
          acc[i][j] = __builtin_amdgcn_mfma_f32_16x16x32_bf16(a[i], b[j], acc[i][j], 0, 0, 0);
    }
    __syncthreads();
  }

#pragma unroll
  for (int i = 0; i < 4; ++i)
#pragma unroll
    for (int j = 0; j < 4; ++j) {
      const int nn = n0 + wc * 64 + j * 16 + lrow;
#pragma unroll
      for (int r = 0; r < 4; ++r) {
        const int mm = m0 + wr * 64 + i * 16 + lhi * 4 + r;
        Cout[(size_t)mm * Dd + nn] = acc[i][j][r] + bias[nn];
      }
    }
}

// ---------------------------------------------------------------------------
// PV with split-K=2: grid (2, S/128, BH); f32 partials -> pvp[ks][B,S,D]
// ---------------------------------------------------------------------------
__global__ __launch_bounds__(256) void pv_split(
    const float* __restrict__ Wts, const ushort* __restrict__ VtAll,
    float* __restrict__ pvp)
{
  __shared__ ushort As[128 * 64];
  __shared__ ushort Bs[128 * 64];
  const int t  = threadIdx.x;
  const int ks = blockIdx.x;
  const int m0 = blockIdx.y * 128;
  const int z  = blockIdx.z;
  const int l  = t & 63, wv = t >> 6;
  const int wr = wv >> 1, wc = wv & 1;
  const int lrow = l & 15, lhi = l >> 4;

  const float*  Af = Wts + (size_t)z * Ss * Ss;
  const ushort* Bt = VtAll + (size_t)z * DKk * Ss;

  f32x4 acc[4][4] = {};

  for (int kt = ks * 1024; kt < ks * 1024 + 1024; kt += 64) {
#pragma unroll
    for (int p = 0; p < 4; ++p) {
      const int li = p * 256 + t, row = li >> 3, g = li & 7;
      const int sw = row * 64 + ((g ^ (row & 7)) << 3);
      const float* src = Af + (size_t)(m0 + row) * Ss + kt + g * 8;
      const float4 v0 = *(const float4*)src;
      const float4 v1 = *(const float4*)(src + 4);
      short8t sa;
      sa[0] = (short)f2bf(v0.x); sa[1] = (short)f2bf(v0.y);
      sa[2] = (short)f2bf(v0.z); sa[3] = (short)f2bf(v0.w);
      sa[4] = (short)f2bf(v1.x); sa[5] = (short)f2bf(v1.y);
      sa[6] = (short)f2bf(v1.z); sa[7] = (short)f2bf(v1.w);
      *(short8t*)&As[sw] = sa;
      *(short8t*)&Bs[sw] = *(const short8t*)(Bt + (size_t)row * Ss + kt + g * 8);
    }
    __syncthreads();

#pragma unroll
    for (int kk = 0; kk < 2; ++kk) {
      short8t a[4], b[4];
      const int g = kk * 4 + lhi;
#pragma unroll
      for (int i = 0; i < 4; ++i) {
        const int row = wr * 64 + i * 16 + lrow;
        a[i] = *(const short8t*)&As[row * 64 + ((g ^ (row & 7)) << 3)];
      }
#pragma unroll
      for (int j = 0; j < 4; ++j) {
        const int row = wc * 64 + j * 16 + lrow;
        b[j] = *(const short8t*)&Bs[row * 64 + ((g ^ (row & 7)) << 3)];
      }
#pragma unroll
      for (int i = 0; i < 4; ++i)
#pragma unroll
        for (int j = 0; j < 4; ++j)
          acc[i][j] = __builtin_amdgcn_mfma_f32_16x16x32_bf16(a[i], b[j], acc[i][j], 0, 0, 0);
    }
    __syncthreads();
  }

  const int bb = z >> 3, hh = z & 7;
  float* outp = pvp + (size_t)ks * MROWS * Dd;
#pragma unroll
  for (int i = 0; i < 4; ++i)
#pragma unroll
    for (int j = 0; j < 4; ++j) {
      const int nn = wc * 64 + j * 16 + lrow;
#pragma unroll
      for (int r = 0; r < 4; ++r) {
        const int mm = m0 + wr * 64 + i * 16 + lhi * 4 + r;
        outp[((size_t)(bb * Ss + mm)) * Dd + hh * DKk + nn] = acc[i][j][r];
      }
    }
}

// attnb = bf16(p0 + p1)
__global__ __launch_bounds__(256) void reduce_attn(
    const float* __restrict__ pvp, ushort* __restrict__ attnb)
{
  const size_t i = ((size_t)blockIdx.x * 256 + threadIdx.x) * 4;
  const float4 a = *(const float4*)(pvp + i);
  const float4 b = *(const float4*)(pvp + (size_t)MROWS * Dd + i);
  short4t o;
  o[0] = (short)f2bf(a.x + b.x);
  o[1] = (short)f2bf(a.y + b.y);
  o[2] = (short)f2bf(a.z + b.z);
  o[3] = (short)f2bf(a.w + b.w);
  *(short4t*)(attnb + i) = o;
}

// ---------------------------------------------------------------------------
// W[1024][1024] f32 -> Wt bf16 (transposed), plain
// ---------------------------------------------------------------------------
__global__ __launch_bounds__(256) void transpose_bf16(
    const float* __restrict__ W, ushort* __restrict__ Wt)
{
  __shared__ float tile[32][33];
  const int t  = threadIdx.x;
  const int c0 = blockIdx.x * 32, r0 = blockIdx.y * 32;
  const int lr = t >> 3, lc4 = (t & 7) * 4;
  const float4 v = *(const float4*)(W + (size_t)(r0 + lr) * Dd + c0 + lc4);
  tile[lr][lc4 + 0] = v.x; tile[lr][lc4 + 1] = v.y;
  tile[lr][lc4 + 2] = v.z; tile[lr][lc4 + 3] = v.w;
  __syncthreads();
  const int oc = t >> 3, or4 = (t & 7) * 4;
  short4t o;
  o[0] = (short)f2bf(tile[or4 + 0][oc]);
  o[1] = (short)f2bf(tile[or4 + 1][oc]);
  o[2] = (short)f2bf(tile[or4 + 2][oc]);
  o[3] = (short)f2bf(tile[or4 + 3][oc]);
  *(short4t*)(Wt + (size_t)(c0 + oc) * Dd + r0 + or4) = o;
}

// ---------------------------------------------------------------------------
// W[1024][1024] f32 -> transposed hi/lo bf16 split
// ---------------------------------------------------------------------------
__global__ __launch_bounds__(256) void transpose_split(
    const float* __restrict__ W, ushort* __restrict__ Th, ushort* __restrict__ Tl)
{
  __shared__ float tile[32][33];
  const int t  = threadIdx.x;
  const int c0 = blockIdx.x * 32, r0 = blockIdx.y * 32;
  const int lr = t >> 3, lc4 = (t & 7) * 4;
  const float4 v = *(const float4*)(W + (size_t)(r0 + lr) * Dd + c0 + lc4);
  tile[lr][lc4 + 0] = v.x; tile[lr][lc4 + 1] = v.y;
  tile[lr][lc4 + 2] = v.z; tile[lr][lc4 + 3] = v.w;
  __syncthreads();
  const int oc = t >> 3, or4 = (t & 7) * 4;
  short4t oh, ol;
  HL r;
  r = split1(tile[or4 + 0][oc]); oh[0] = r.h; ol[0] = r.l;
  r = split1(tile[or4 + 1][oc]); oh[1] = r.h; ol[1] = r.l;
  r = split1(tile[or4 + 2][oc]); oh[2] = r.h; ol[2] = r.l;
  r = split1(tile[or4 + 3][oc]); oh[3] = r.h; ol[3] = r.l;
  *(short4t*)(Th + (size_t)(c0 + oc) * Dd + r0 + or4) = oh;
  *(short4t*)(Tl + (size_t)(c0 + oc) * Dd + r0 + or4) = ol;
}

// ---------------------------------------------------------------------------
// Per-row exact top-512 + softmax, in place. v5: input is already
// order-flipped u32 keys (written by mfma_scores) -> no key building.
// 11-bit histogram pass + candidate compaction + in-wave exact rank;
// exact radix fallback. Register-held exp/normalize.
// ---------------------------------------------------------------------------
__global__ __launch_bounds__(256) void topk_softmax(float* __restrict__ wts)
{
  __shared__ unsigned keys[Ss];       // 8 KB
  __shared__ unsigned hist[2048];     // 8 KB
  __shared__ unsigned candK[128];
  __shared__ unsigned wredA[4];
  __shared__ unsigned wredB[4];
  __shared__ float    fred[4];
  __shared__ unsigned sBin, sNeedK, sTie, sCnt, sT;

  const int t    = threadIdx.x;
  const int lane = t & 63;
  const int wv   = t >> 6;
  float* rowp = wts + (size_t)blockIdx.x * Ss;
  const unsigned* rowu = (const unsigned*)rowp;

  {
    const uint4 zz = {0u, 0u, 0u, 0u};
    *(uint4*)&hist[t * 8]     = zz;
    *(uint4*)&hist[t * 8 + 4] = zz;
  }
  if (t == 0) sCnt = 0u;
  __syncthreads();

  // ---- sweep 1: load keys, 11-bit histogram, running max ----
  unsigned lmax = 0u;
#pragma unroll
  for (int base = 0; base < Ss; base += 1024) {
    const uint4 k = *(const uint4*)(rowu + base + 4 * t);
    lmax = max(max(lmax, max(k.x, k.y)), max(k.z, k.w));
    *(uint4*)&keys[base + 4 * t] = k;
    atomicAdd(&hist[k.x >> 21], 1u);
    atomicAdd(&hist[k.y >> 21], 1u);
    atomicAdd(&hist[k.z >> 21], 1u);
    atomicAdd(&hist[k.w >> 21], 1u);
  }
#pragma unroll
  for (int off = 32; off > 0; off >>= 1) lmax = max(lmax, __shfl_xor(lmax, off));
  if (lane == 0) wredA[wv] = lmax;
  __syncthreads();
  const float m = key_to_float(max(max(wredA[0], wredA[1]), max(wredA[2], wredA[3])));

  // ---- scan 2048 bins ----
  unsigned needK = KTOP, b1, tieC;
  {
    unsigned b[8], lsum = 0u;
#pragma unroll
    for (int i = 0; i < 8; ++i) { b[i] = hist[t * 8 + i]; lsum += b[i]; }
    unsigned s = lsum;
#pragma unroll
    for (int off = 1; off < 64; off <<= 1) {
      const unsigned v = __shfl_down(s, off);
      if (lane + off < 64) s += v;
    }
    if (lane == 0) wredB[wv] = s;
    __syncthreads();
    unsigned stot = s;
    for (int w2 = wv + 1; w2 < 4; ++w2) stot += wredB[w2];
    unsigned run = stot - lsum;
    unsigned fb = 0u, fn = 0u, ft = 0u;
    bool found = false;
#pragma unroll
    for (int i = 7; i >= 0; --i) {
      const unsigned c = b[i];
      if (!found && c > 0u && run < needK && run + c >= needK) {
        found = true; fb = (unsigned)(t * 8 + i); fn = needK - run; ft = c;
      }
      run += c;
    }
    if (found) { sBin = fb; sNeedK = fn; sTie = ft; }
    __syncthreads();
    b1 = sBin; needK = sNeedK; tieC = sTie;
  }

  // ---- compact candidates of bin b1 (ballot-aggregated, cap 128) ----
#pragma unroll
  for (int base = 0; base < Ss; base += 1024) {
    const uint4 k = *(const uint4*)&keys[base + 4 * t];
    const unsigned a[4] = {k.x, k.y, k.z, k.w};
#pragma unroll
    for (int c = 0; c < 4; ++c) {
      const bool f = ((a[c] >> 21) == b1);
      const unsigned long long msk = __ballot(f);
      if (msk) {
        const int ldr = (int)__ffsll(msk) - 1;
        unsigned bidx = 0u;
        if (lane == ldr) bidx = atomicAdd(&sCnt, (unsigned)__popcll(msk));
        bidx = __shfl(bidx, ldr);
        if (f) {
          const unsigned pos = bidx + (unsigned)__popcll(msk & ((1ull << lane) - 1ull));
          if (pos < 128u) candK[pos] = a[c];
        }
      }
    }
  }
  __syncthreads();
  const unsigned C1 = sCnt;
  unsigned T;

  if (C1 <= 128u) {
    if (wv == 0) {
      const bool va = (unsigned)lane < C1;
      const bool vb = (unsigned)(lane + 64) < C1;
      const unsigned ka = va ? candK[lane] : 0u;
      const unsigned kb = vb ? candK[lane + 64] : 0u;
      unsigned ga = 0u, ea = 0u, gb = 0u, eb = 0u;
      for (unsigned j = 0; j < C1; ++j) {
        const unsigned kj = (j < 64u) ? __shfl(ka, (int)j) : __shfl(kb, (int)(j - 64u));
        ga += (kj > ka); ea += (kj == ka);
        gb += (kj > kb); eb += (kj == kb);
      }
      const bool fa = va && (ga < needK) && (ga + ea >= needK);
      const bool fb2 = vb && (gb < needK) && (gb + eb >= needK);
      const unsigned myT    = fa ? ka : kb;
      const unsigned myNeed = fa ? (needK - ga) : (needK - gb);
      const unsigned myTie  = fa ? ea : eb;
      const unsigned long long mm2 = __ballot(fa || fb2);
      const int src = (int)__ffsll(mm2) - 1;
      if (lane == src) { sT = myT; sNeedK = myNeed; sTie = myTie; }
    }
    __syncthreads();
    T = sT; needK = sNeedK; tieC = sTie;
  } else {
    // exact fallback: radix on bits [20:13],[12:5],[4:0]
    unsigned prefix = b1 << 21;
    unsigned maskHi = 0xFFE00000u;
    for (int p = 0; p < 3; ++p) {
      const int sh = (p == 0) ? 13 : (p == 1) ? 5 : 0;
      const unsigned bmask = (p < 2) ? 255u : 31u;
      if (t < 256) hist[t] = 0u;
      __syncthreads();
      for (int i = t; i < Ss; i += 256) {
        const unsigned k = keys[i];
        if ((k & maskHi) == prefix) atomicAdd(&hist[(k >> sh) & bmask], 1u);
      }
      __syncthreads();
      const unsigned h = ((unsigned)t <= bmask) ? hist[t] : 0u;
      unsigned s = h;
      for (int off = 1; off < 64; off <<= 1) {
        const unsigned v = __shfl_down(s, off);
        if (lane + off < 64) s += v;
      }
      if (lane == 0) wredB[wv] = s;
      __syncthreads();
      unsigned stot = s;
      for (int w2 = wv + 1; w2 < 4; ++w2) stot += wredB[w2];
      if (h > 0u && stot >= needK && stot - h < needK) {
        sBin = (unsigned)t; sNeedK = needK - (stot - h); sTie = h;
      }
      __syncthreads();
      prefix |= sBin << sh;
      needK = sNeedK; tieC = sTie;
      maskHi |= bmask << sh;
      __syncthreads();
    }
    T = prefix;
  }

  if (tieC != needK) {
    if (t == 0) {
      unsigned taken = 0u;
      for (int i = 0; i < Ss; ++i)
        if (keys[i] == T) { if (taken < needK) ++taken; else keys[i] = 0u; }
    }
    __syncthreads();
  }

  // ---- exp (registers) + Z reduce + normalized store ----
  float w[8];
  float lz = 0.f;
#pragma unroll
  for (int half = 0; half < 2; ++half) {
    const int i0 = half * 1024 + 4 * t;
    const uint4 k = *(const uint4*)&keys[i0];
    w[half * 4 + 0] = (k.x >= T) ? __expf(key_to_float(k.x) - m) : 0.f;
    w[half * 4 + 1] = (k.y >= T) ? __expf(key_to_float(k.y) - m) : 0.f;
    w[half * 4 + 2] = (k.z >= T) ? __expf(key_to_float(k.z) - m) : 0.f;
    w[half * 4 + 3] = (k.w >= T) ? __expf(key_to_float(k.w) - m) : 0.f;
    lz += (w[half * 4 + 0] + w[half * 4 + 1]) + (w[half * 4 + 2] + w[half * 4 + 3]);
  }
#pragma unroll
  for (int off = 32; off > 0; off >>= 1) lz += __shfl_xor(lz, off);
  if (lane == 0) fred[wv] = lz;
  __syncthreads();
  const float Zi = 1.0f / (fred[0] + fred[1] + fred[2] + fred[3]);

#pragma unroll
  for (int half = 0; half < 2; ++half) {
    const int i0 = half * 1024 + 4 * t;
    float4 o;
    o.x = w[half * 4 + 0] * Zi;
    o.y = w[half * 4 + 1] * Zi;
    o.z = w[half * 4 + 2] * Zi;
    o.w = w[half * 4 + 3] * Zi;
    *(float4*)(rowp + i0) = o;
  }
}

}  // namespace

extern "C" void kernel_launch(void* const* d_in, const int* in_sizes, int n_in,
                              void* d_out_v, int out_size, void* d_ws, size_t ws_size,
                              hipStream_t stream)
{
  const float* query = (const float*)d_in[0];
  const float* key   = (const float*)d_in[1];
  const float* value = (const float*)d_in[2];
  const float* Wq = (const float*)d_in[3];  const float* bq = (const float*)d_in[4];
  const float* Wk = (const float*)d_in[5];  const float* bk = (const float*)d_in[6];
  const float* Wv = (const float*)d_in[7];  const float* bv = (const float*)d_in[8];
  const float* Wo = (const float*)d_in[9];  const float* bo = (const float*)d_in[10];

  float* d_out = (float*)d_out_v;
  float* outp  = d_out;                              // [B,S,D] f32
  float* wts   = d_out + (size_t)Bb * Ss * Dd;       // [B,H,S,S] f32

  const size_t PROJ = (size_t)MROWS * Dd;            // 4M elements
  const size_t DD2  = (size_t)Dd * Dd;               // 1M elements

  ushort* ws    = (ushort*)d_ws;
  ushort* Qh    = ws;                                // 8 MB each
  ushort* Ql    = Qh + PROJ;
  ushort* Kh    = Ql + PROJ;
  ushort* Kl    = Kh + PROJ;                         // ends at 32 MB
  ushort* wreg  = Kl + PROJ;
  ushort* WqTh  = wreg;                              // 6 x 2 MB splits
  ushort* WqTl  = wreg + DD2;
  ushort* WkTh  = wreg + 2 * DD2;
  ushort* WkTl  = wreg + 3 * DD2;
  ushort* WvTh  = wreg + 4 * DD2;
  ushort* WvTl  = wreg + 5 * DD2;
  ushort* WoT   = wreg + 6 * DD2;                    // 2 MB
  ushort* Vt    = wreg + 7 * DD2;                    // bf16 V^T [16][128][2048] 8 MB
  ushort* attnb = Vt + (size_t)BH * DKk * Ss;        // bf16 attn 8 MB
  float*  pvp   = (float*)Qh;                        // pv partials alias Qh..Kl (32 MB)

  const dim3 blk(256);

  // weight prep
  transpose_split<<<dim3(32, 32), blk, 0, stream>>>(Wq, WqTh, WqTl);
  transpose_split<<<dim3(32, 32), blk, 0, stream>>>(Wk, WkTh, WkTl);
  transpose_split<<<dim3(32, 32), blk, 0, stream>>>(Wv, WvTh, WvTl);
  transpose_bf16<<<dim3(32, 32), blk, 0, stream>>>(Wo, WoT);

  // Q/K/V projections, batched (3 blocks/CU): Q,K -> pre-split hi/lo; V -> Vt
  mfma_proj<<<dim3(Dd / 128, MROWS / 128, 3), blk, 0, stream>>>(
      query, key, value, WqTh, WqTl, WkTh, WkTl, WvTh, WvTl,
      bq, bk, bv, Qh, Ql, Kh, Kl, Vt);

  // scores from pre-split Q,K -> u32 keys in wts region (SCALE folded)
  mfma_scores<<<dim3(Ss / 128, Ss / 128, BH), blk, 0, stream>>>(
      Qh, Ql, Kh, Kl, (unsigned*)wts);

  // exact top-512 + softmax, in place (keys -> f32 weights)
  topk_softmax<<<dim3(BH * Ss), blk, 0, stream>>>(wts);

  // PV split-K=2 -> f32 partials (aliasing dead Qh..Kl)
  pv_split<<<dim3(2, Ss / 128, BH), blk, 0, stream>>>(wts, Vt, pvp);
  reduce_attn<<<dim3((int)(PROJ / 1024)), blk, 0, stream>>>(pvp, attnb);

  // output projection
  mfma_oproj<<<dim3(Dd / 128, MROWS / 128), blk, 0, stream>>>(
      attnb, WoT, bo, outp);
}

// Round 11
// 453.957 us; speedup vs baseline: 1.4253x; 1.1859x over previous
//
#include <hip/hip_runtime.h>
#include <hip/hip_bf16.h>
#include <math.h>

namespace {

constexpr int Bb   = 2;
constexpr int Ss   = 2048;
constexpr int Dd   = 1024;
constexpr int Hh   = 8;
constexpr int DKk  = 128;
constexpr int KTOP = 512;
constexpr int BH    = Bb * Hh;   // 16
constexpr int MROWS = Bb * Ss;   // 4096
constexpr float SCALE = 0.08838834764831845f;  // 1/sqrt(128)

typedef __attribute__((ext_vector_type(8))) short short8t;  // 8 bf16 = 16 B
typedef __attribute__((ext_vector_type(4))) short short4t;  // 4 bf16 = 8 B
typedef __attribute__((ext_vector_type(4))) float f32x4;

__device__ inline ushort f2bf(float x) {  // f32 -> bf16 RNE
  const unsigned u = __float_as_uint(x);
  return (ushort)((u + 0x7FFFu + ((u >> 16) & 1u)) >> 16);
}
__device__ inline float bf2f(ushort h) {
  return __uint_as_float(((unsigned)h) << 16);
}
struct HL { short h, l; };
__device__ inline HL split1(float x) {
  HL r;
  const ushort hu = f2bf(x);
  r.h = (short)hu;
  r.l = (short)f2bf(x - bf2f(hu));
  return r;
}

__device__ inline unsigned key_of(float v) {
  const unsigned u = __float_as_uint(v);
  return (u & 0x80000000u) ? ~u : (u | 0x80000000u);
}
__device__ inline float key_to_float(unsigned k) {
  const unsigned u = (k & 0x80000000u) ? (k & 0x7FFFFFFFu) : ~k;
  return __uint_as_float(u);
}

// ---------------------------------------------------------------------------
// Batched Q/K/V projection, split-bf16 MFMA NT (Ah·Bh + Ah·Bl + Al·Bh).
// grid z: 0=Q, 1=K (out: hi/lo bf16 [bh][s][dk]), 2=V (out: bf16 Vt[bh][dk][s])
// ---------------------------------------------------------------------------
__global__ __launch_bounds__(256) void mfma_proj(
    const float* __restrict__ query, const float* __restrict__ keyi,
    const float* __restrict__ value,
    const ushort* __restrict__ WqTh, const ushort* __restrict__ WqTl,
    const ushort* __restrict__ WkTh, const ushort* __restrict__ WkTl,
    const ushort* __restrict__ WvTh, const ushort* __restrict__ WvTl,
    const float* __restrict__ bq, const float* __restrict__ bk,
    const float* __restrict__ bv,
    ushort* __restrict__ Qh, ushort* __restrict__ Ql,
    ushort* __restrict__ Kh, ushort* __restrict__ Kl,
    ushort* __restrict__ Vt)
{
  __shared__ ushort Ah[128 * 32];
  __shared__ ushort Al[128 * 32];
  __shared__ ushort Bh[128 * 32];
  __shared__ ushort Bl[128 * 32];
  const int t  = threadIdx.x;
  const int z  = blockIdx.z;
  const int n0 = blockIdx.x * 128;
  const int m0 = blockIdx.y * 128;
  const int l  = t & 63, wv = t >> 6;
  const int wr = wv >> 1, wc = wv & 1;
  const int lrow = l & 15, lhi = l >> 4;

  const float*  A    = (z == 0) ? query : (z == 1) ? keyi : value;
  const ushort* Bth  = (z == 0) ? WqTh  : (z == 1) ? WkTh : WvTh;
  const ushort* Btl  = (z == 0) ? WqTl  : (z == 1) ? WkTl : WvTl;
  const float*  bias = (z == 0) ? bq    : (z == 1) ? bk   : bv;

  f32x4 acc[4][4] = {};

  for (int kt = 0; kt < Dd; kt += 32) {
#pragma unroll
    for (int p = 0; p < 2; ++p) {
      const int li = p * 256 + t, row = li >> 2, g = li & 3;
      const int sw = row * 32 + ((g ^ (row & 3)) << 3);
      {
        const float* src = A + (size_t)(m0 + row) * Dd + kt + g * 8;
        const float4 v0 = *(const float4*)src;
        const float4 v1 = *(const float4*)(src + 4);
        short8t h, lo;
        HL r;
        r = split1(v0.x); h[0] = r.h; lo[0] = r.l;
        r = split1(v0.y); h[1] = r.h; lo[1] = r.l;
        r = split1(v0.z); h[2] = r.h; lo[2] = r.l;
        r = split1(v0.w); h[3] = r.h; lo[3] = r.l;
        r = split1(v1.x); h[4] = r.h; lo[4] = r.l;
        r = split1(v1.y); h[5] = r.h; lo[5] = r.l;
        r = split1(v1.z); h[6] = r.h; lo[6] = r.l;
        r = split1(v1.w); h[7] = r.h; lo[7] = r.l;
        *(short8t*)&Ah[sw] = h;
        *(short8t*)&Al[sw] = lo;
      }
      const size_t off = (size_t)(n0 + row) * Dd + kt + g * 8;
      *(short8t*)&Bh[sw] = *(const short8t*)(Bth + off);
      *(short8t*)&Bl[sw] = *(const short8t*)(Btl + off);
    }
    __syncthreads();

    short8t ah[4], al[4], bh[4], bl[4];
#pragma unroll
    for (int i = 0; i < 4; ++i) {
      const int row = wr * 64 + i * 16 + lrow;
      const int idx = row * 32 + ((lhi ^ (row & 3)) << 3);
      ah[i] = *(const short8t*)&Ah[idx];
      al[i] = *(const short8t*)&Al[idx];
    }
#pragma unroll
    for (int j = 0; j < 4; ++j) {
      const int row = wc * 64 + j * 16 + lrow;
      const int idx = row * 32 + ((lhi ^ (row & 3)) << 3);
      bh[j] = *(const short8t*)&Bh[idx];
      bl[j] = *(const short8t*)&Bl[idx];
    }
#pragma unroll
    for (int i = 0; i < 4; ++i)
#pragma unroll
      for (int j = 0; j < 4; ++j) {
        acc[i][j] = __builtin_amdgcn_mfma_f32_16x16x32_bf16(ah[i], bh[j], acc[i][j], 0, 0, 0);
        acc[i][j] = __builtin_amdgcn_mfma_f32_16x16x32_bf16(ah[i], bl[j], acc[i][j], 0, 0, 0);
        acc[i][j] = __builtin_amdgcn_mfma_f32_16x16x32_bf16(al[i], bh[j], acc[i][j], 0, 0, 0);
      }
    __syncthreads();
  }

#pragma unroll
  for (int i = 0; i < 4; ++i) {
#pragma unroll
    for (int j = 0; j < 4; ++j) {
      const int nn = n0 + wc * 64 + j * 16 + lrow;
#pragma unroll
      for (int r = 0; r < 4; ++r) {
        const int mm = m0 + wr * 64 + i * 16 + lhi * 4 + r;
        const float v = acc[i][j][r] + bias[nn];
        const int bb = mm >> 11, s = mm & (Ss - 1);
        const int hh = nn >> 7,  dk = nn & (DKk - 1);
        if (z < 2) {
          const size_t o = (((size_t)(bb * Hh + hh)) * Ss + s) * DKk + dk;
          const HL rr = split1(v);
          if (z == 0) { Qh[o] = (ushort)rr.h; Ql[o] = (ushort)rr.l; }
          else        { Kh[o] = (ushort)rr.h; Kl[o] = (ushort)rr.l; }
        } else {
          Vt[((size_t)((bb * Hh + hh) * DKk + dk)) * Ss + s] = f2bf(v);
        }
      }
    }
  }
}

// ---------------------------------------------------------------------------
// Scores from pre-split Q,K; epilogue writes order-flipped u32 keys (SCALE in)
// ---------------------------------------------------------------------------
__global__ __launch_bounds__(256) void mfma_scores(
    const ushort* __restrict__ Qh, const ushort* __restrict__ Ql,
    const ushort* __restrict__ Kh, const ushort* __restrict__ Kl,
    unsigned* __restrict__ wtsOut)
{
  __shared__ ushort Ah[128 * 32];
  __shared__ ushort Al[128 * 32];
  __shared__ ushort Bh[128 * 32];
  __shared__ ushort Bl[128 * 32];
  const int t  = threadIdx.x;
  const int z  = blockIdx.z;
  const int n0 = blockIdx.x * 128;   // j
  const int m0 = blockIdx.y * 128;   // q
  const int l  = t & 63, wv = t >> 6;
  const int wr = wv >> 1, wc = wv & 1;
  const int lrow = l & 15, lhi = l >> 4;
  const size_t boff = (size_t)z * Ss * DKk;

  f32x4 acc[4][4] = {};

  for (int kt = 0; kt < DKk; kt += 32) {
#pragma unroll
    for (int p = 0; p < 2; ++p) {
      const int li = p * 256 + t, row = li >> 2, g = li & 3;
      const int sw = row * 32 + ((g ^ (row & 3)) << 3);
      const size_t ao = boff + (size_t)(m0 + row) * DKk + kt + g * 8;
      *(short8t*)&Ah[sw] = *(const short8t*)(Qh + ao);
      *(short8t*)&Al[sw] = *(const short8t*)(Ql + ao);
      const size_t bo = boff + (size_t)(n0 + row) * DKk + kt + g * 8;
      *(short8t*)&Bh[sw] = *(const short8t*)(Kh + bo);
      *(short8t*)&Bl[sw] = *(const short8t*)(Kl + bo);
    }
    __syncthreads();

    short8t ah[4], al[4], bh[4], bl[4];
#pragma unroll
    for (int i = 0; i < 4; ++i) {
      const int row = wr * 64 + i * 16 + lrow;
      const int idx = row * 32 + ((lhi ^ (row & 3)) << 3);
      ah[i] = *(const short8t*)&Ah[idx];
      al[i] = *(const short8t*)&Al[idx];
    }
#pragma unroll
    for (int j = 0; j < 4; ++j) {
      const int row = wc * 64 + j * 16 + lrow;
      const int idx = row * 32 + ((lhi ^ (row & 3)) << 3);
      bh[j] = *(const short8t*)&Bh[idx];
      bl[j] = *(const short8t*)&Bl[idx];
    }
#pragma unroll
    for (int i = 0; i < 4; ++i)
#pragma unroll
      for (int j = 0; j < 4; ++j) {
        acc[i][j] = __builtin_amdgcn_mfma_f32_16x16x32_bf16(ah[i], bh[j], acc[i][j], 0, 0, 0);
        acc[i][j] = __builtin_amdgcn_mfma_f32_16x16x32_bf16(ah[i], bl[j], acc[i][j], 0, 0, 0);
        acc[i][j] = __builtin_amdgcn_mfma_f32_16x16x32_bf16(al[i], bh[j], acc[i][j], 0, 0, 0);
      }
    __syncthreads();
  }

#pragma unroll
  for (int i = 0; i < 4; ++i)
#pragma unroll
    for (int j = 0; j < 4; ++j) {
      const int nn = n0 + wc * 64 + j * 16 + lrow;
#pragma unroll
      for (int r = 0; r < 4; ++r) {
        const int mm = m0 + wr * 64 + i * 16 + lhi * 4 + r;
        wtsOut[(size_t)z * Ss * Ss + (size_t)mm * Ss + nn] =
            key_of(acc[i][j][r] * SCALE);
      }
    }
}

// ---------------------------------------------------------------------------
// o_proj with inline pv-partial reduce: A = bf16(p0 + p1) staged on the fly
// ---------------------------------------------------------------------------
__global__ __launch_bounds__(256) void mfma_oproj(
    const float* __restrict__ pv0, const float* __restrict__ pv1,
    const ushort* __restrict__ Bt,
    const float* __restrict__ bias, float* __restrict__ Cout)
{
  __shared__ ushort As[128 * 64];
  __shared__ ushort Bs[128 * 64];
  const int t  = threadIdx.x;
  const int n0 = blockIdx.x * 128;
  const int m0 = blockIdx.y * 128;
  const int l  = t & 63, wv = t >> 6;
  const int wr = wv >> 1, wc = wv & 1;
  const int lrow = l & 15, lhi = l >> 4;

  f32x4 acc[4][4] = {};

  for (int kt = 0; kt < Dd; kt += 64) {
#pragma unroll
    for (int p = 0; p < 4; ++p) {
      const int li = p * 256 + t, row = li >> 3, g = li & 7;
      const int sw = row * 64 + ((g ^ (row & 7)) << 3);
      const size_t ao = (size_t)(m0 + row) * Dd + kt + g * 8;
      const float4 a0 = *(const float4*)(pv0 + ao);
      const float4 a1 = *(const float4*)(pv0 + ao + 4);
      const float4 c0 = *(const float4*)(pv1 + ao);
      const float4 c1 = *(const float4*)(pv1 + ao + 4);
      short8t sa;
      sa[0] = (short)f2bf(a0.x + c0.x); sa[1] = (short)f2bf(a0.y + c0.y);
      sa[2] = (short)f2bf(a0.z + c0.z); sa[3] = (short)f2bf(a0.w + c0.w);
      sa[4] = (short)f2bf(a1.x + c1.x); sa[5] = (short)f2bf(a1.y + c1.y);
      sa[6] = (short)f2bf(a1.z + c1.z); sa[7] = (short)f2bf(a1.w + c1.w);
      *(short8t*)&As[sw] = sa;
      *(short8t*)&Bs[sw] = *(const short8t*)(Bt + (size_t)(n0 + row) * Dd + kt + g * 8);
    }
    __syncthreads();

#pragma unroll
    for (int kk = 0; kk < 2; ++kk) {
      short8t a[4], b[4];
      const int g = kk * 4 + lhi;
#pragma unroll
      for (int i = 0; i < 4; ++i) {
        const int row = wr * 64 + i * 16 + lrow;
        a[i] = *(const short8t*)&As[row * 64 + ((g ^ (row & 7)) << 3)];
      }
#pragma unroll
      for (int j = 0; j < 4; ++j) {
        const int row = wc * 64 + j * 16 + lrow;
        b[j] = *(const short8t*)&Bs[row * 64 + ((g ^ (row & 7)) << 3)];
      }
#pragma unroll
      for (int i = 0; i < 4; ++i)
#pragma unroll
        for (int j = 0; j < 4; ++j)
          acc[i][j] = __builtin_amdgcn_mfma_f32_16x16x32_bf16(a[i], b[j], acc[i][j], 0, 0, 0);
    }
    __syncthreads();
  }

#pragma unroll
  for (int i = 0; i < 4; ++i)
#pragma unroll
    for (int j = 0; j < 4; ++j) {
      const int nn = n0 + wc * 64 + j * 16 + lrow;
#pragma unroll
      for (int r = 0; r < 4; ++r) {
        const int mm = m0 + wr * 64 + i * 16 + lhi * 4 + r;
        Cout[(size_t)mm * Dd + nn] = acc[i][j][r] + bias[nn];
      }
    }
}

// ---------------------------------------------------------------------------
// PV with split-K=2: grid (2, S/128, BH); f32 partials -> pvp[ks][B,S,D]
// ---------------------------------------------------------------------------
__global__ __launch_bounds__(256) void pv_split(
    const float* __restrict__ Wts, const ushort* __restrict__ VtAll,
    float* __restrict__ pvp)
{
  __shared__ ushort As[128 * 64];
  __shared__ ushort Bs[128 * 64];
  const int t  = threadIdx.x;
  const int ks = blockIdx.x;
  const int m0 = blockIdx.y * 128;
  const int z  = blockIdx.z;
  const int l  = t & 63, wv = t >> 6;
  const int wr = wv >> 1, wc = wv & 1;
  const int lrow = l & 15, lhi = l >> 4;

  const float*  Af = Wts + (size_t)z * Ss * Ss;
  const ushort* Bt = VtAll + (size_t)z * DKk * Ss;

  f32x4 acc[4][4] = {};

  for (int kt = ks * 1024; kt < ks * 1024 + 1024; kt += 64) {
#pragma unroll
    for (int p = 0; p < 4; ++p) {
      const int li = p * 256 + t, row = li >> 3, g = li & 7;
      const int sw = row * 64 + ((g ^ (row & 7)) << 3);
      const float* src = Af + (size_t)(m0 + row) * Ss + kt + g * 8;
      const float4 v0 = *(const float4*)src;
      const float4 v1 = *(const float4*)(src + 4);
      short8t sa;
      sa[0] = (short)f2bf(v0.x); sa[1] = (short)f2bf(v0.y);
      sa[2] = (short)f2bf(v0.z); sa[3] = (short)f2bf(v0.w);
      sa[4] = (short)f2bf(v1.x); sa[5] = (short)f2bf(v1.y);
      sa[6] = (short)f2bf(v1.z); sa[7] = (short)f2bf(v1.w);
      *(short8t*)&As[sw] = sa;
      *(short8t*)&Bs[sw] = *(const short8t*)(Bt + (size_t)row * Ss + kt + g * 8);
    }
    __syncthreads();

#pragma unroll
    for (int kk = 0; kk < 2; ++kk) {
      short8t a[4], b[4];
      const int g = kk * 4 + lhi;
#pragma unroll
      for (int i = 0; i < 4; ++i) {
        const int row = wr * 64 + i * 16 + lrow;
        a[i] = *(const short8t*)&As[row * 64 + ((g ^ (row & 7)) << 3)];
      }
#pragma unroll
      for (int j = 0; j < 4; ++j) {
        const int row = wc * 64 + j * 16 + lrow;
        b[j] = *(const short8t*)&Bs[row * 64 + ((g ^ (row & 7)) << 3)];
      }
#pragma unroll
      for (int i = 0; i < 4; ++i)
#pragma unroll
        for (int j = 0; j < 4; ++j)
          acc[i][j] = __builtin_amdgcn_mfma_f32_16x16x32_bf16(a[i], b[j], acc[i][j], 0, 0, 0);
    }
    __syncthreads();
  }

  const int bb = z >> 3, hh = z & 7;
  float* outp = pvp + (size_t)ks * MROWS * Dd;
#pragma unroll
  for (int i = 0; i < 4; ++i)
#pragma unroll
    for (int j = 0; j < 4; ++j) {
      const int nn = wc * 64 + j * 16 + lrow;
#pragma unroll
      for (int r = 0; r < 4; ++r) {
        const int mm = m0 + wr * 64 + i * 16 + lhi * 4 + r;
        outp[((size_t)(bb * Ss + mm)) * Dd + hh * DKk + nn] = acc[i][j][r];
      }
    }
}

// ---------------------------------------------------------------------------
// W[1024][1024] f32 -> Wt bf16 (transposed)
// ---------------------------------------------------------------------------
__global__ __launch_bounds__(256) void transpose_bf16(
    const float* __restrict__ W, ushort* __restrict__ Wt)
{
  __shared__ float tile[32][33];
  const int t  = threadIdx.x;
  const int c0 = blockIdx.x * 32, r0 = blockIdx.y * 32;
  const int lr = t >> 3, lc4 = (t & 7) * 4;
  const float4 v = *(const float4*)(W + (size_t)(r0 + lr) * Dd + c0 + lc4);
  tile[lr][lc4 + 0] = v.x; tile[lr][lc4 + 1] = v.y;
  tile[lr][lc4 + 2] = v.z; tile[lr][lc4 + 3] = v.w;
  __syncthreads();
  const int oc = t >> 3, or4 = (t & 7) * 4;
  short4t o;
  o[0] = (short)f2bf(tile[or4 + 0][oc]);
  o[1] = (short)f2bf(tile[or4 + 1][oc]);
  o[2] = (short)f2bf(tile[or4 + 2][oc]);
  o[3] = (short)f2bf(tile[or4 + 3][oc]);
  *(short4t*)(Wt + (size_t)(c0 + oc) * Dd + r0 + or4) = o;
}

// ---------------------------------------------------------------------------
// W[1024][1024] f32 -> transposed hi/lo bf16 split
// ---------------------------------------------------------------------------
__global__ __launch_bounds__(256) void transpose_split(
    const float* __restrict__ W, ushort* __restrict__ Th, ushort* __restrict__ Tl)
{
  __shared__ float tile[32][33];
  const int t  = threadIdx.x;
  const int c0 = blockIdx.x * 32, r0 = blockIdx.y * 32;
  const int lr = t >> 3, lc4 = (t & 7) * 4;
  const float4 v = *(const float4*)(W + (size_t)(r0 + lr) * Dd + c0 + lc4);
  tile[lr][lc4 + 0] = v.x; tile[lr][lc4 + 1] = v.y;
  tile[lr][lc4 + 2] = v.z; tile[lr][lc4 + 3] = v.w;
  __syncthreads();
  const int oc = t >> 3, or4 = (t & 7) * 4;
  short4t oh, ol;
  HL r;
  r = split1(tile[or4 + 0][oc]); oh[0] = r.h; ol[0] = r.l;
  r = split1(tile[or4 + 1][oc]); oh[1] = r.h; ol[1] = r.l;
  r = split1(tile[or4 + 2][oc]); oh[2] = r.h; ol[2] = r.l;
  r = split1(tile[or4 + 3][oc]); oh[3] = r.h; ol[3] = r.l;
  *(short4t*)(Th + (size_t)(c0 + oc) * Dd + r0 + or4) = oh;
  *(short4t*)(Tl + (size_t)(c0 + oc) * Dd + r0 + or4) = ol;
}

// ---------------------------------------------------------------------------
// Per-row exact top-512 + softmax, v6: wave-per-row, 4 rows/block, ZERO
// __syncthreads. 32 keys/lane in registers (reused as weight storage).
// Exact selection = 4 wave-private radix passes (1024/256/256/64 bins =
// all 32 bits; final bin count == exact tie count, no ranking needed).
// Histograms padded b+(b>>4) against stride-16 bank aliasing.
// ---------------------------------------------------------------------------
__global__ __launch_bounds__(256) void topk_softmax(float* __restrict__ wts)
{
  __shared__ unsigned histAll[4][1088];   // 17 KB total (1024 bins + pad)

  const int lane = threadIdx.x & 63;
  const int wv   = threadIdx.x >> 6;
  const int row  = blockIdx.x * 4 + wv;
  float* rowp = wts + (size_t)row * Ss;
  unsigned* rowu = (unsigned*)rowp;
  unsigned* h = histAll[wv];

  // ---- load 32 keys/lane (interleaved, coalesced), running max ----
  unsigned k[32];
  unsigned lmax = 0u;
#pragma unroll
  for (int i = 0; i < 8; ++i) {
    const uint4 v = *(const uint4*)(rowu + i * 256 + lane * 4);
    k[i * 4 + 0] = v.x; k[i * 4 + 1] = v.y;
    k[i * 4 + 2] = v.z; k[i * 4 + 3] = v.w;
    lmax = max(max(lmax, max(v.x, v.y)), max(v.z, v.w));
  }
#pragma unroll
  for (int off = 32; off > 0; off >>= 1) lmax = max(lmax, __shfl_xor(lmax, off));
  const float m = key_to_float(lmax);

  unsigned needK = KTOP, tieC = 0u, prefix = 0u;

  // ---- pass 1: bits [31:22], 1024 bins ----
  {
#pragma unroll
    for (int i = 0; i < 17; ++i) h[lane + i * 64] = 0u;
#pragma unroll
    for (int i = 0; i < 32; ++i) {
      const unsigned b = k[i] >> 22;
      atomicAdd(&h[b + (b >> 4)], 1u);
    }
    unsigned b[16], lsum = 0u;
#pragma unroll
    for (int i = 0; i < 16; ++i) { b[i] = h[lane * 17 + i]; lsum += b[i]; }
    unsigned s = lsum;
#pragma unroll
    for (int off = 1; off < 64; off <<= 1) {
      const unsigned v = __shfl_down(s, off);
      if (lane + off < 64) s += v;
    }
    unsigned run = s - lsum;
    unsigned fb = 0u, fn = 0u, ft = 0u;
    bool found = false;
#pragma unroll
    for (int i = 15; i >= 0; --i) {
      const unsigned c = b[i];
      if (!found && c > 0u && run < needK && run + c >= needK) {
        found = true; fb = (unsigned)(lane * 16 + i); fn = needK - run; ft = c;
      }
      run += c;
    }
    const unsigned long long msk = __ballot(found);
    const int src = (int)__ffsll(msk) - 1;
    prefix = __shfl(fb, src) << 22;
    needK  = __shfl(fn, src);
    tieC   = __shfl(ft, src);
  }

  // ---- passes 2,3: 8-bit refinements (bits [21:14], [13:6]) ----
#pragma unroll
  for (int pass = 0; pass < 2; ++pass) {
    const int sh = (pass == 0) ? 14 : 6;
    const int ph = sh + 8;  // compare bits [31:ph]
#pragma unroll
    for (int i = 0; i < 5; ++i) h[lane + i * 64] = 0u;   // zero 0..319 (covers 272)
    const unsigned pcmp = prefix >> ph;
#pragma unroll
    for (int i = 0; i < 32; ++i) {
      if ((k[i] >> ph) == pcmp) {
        const unsigned b = (k[i] >> sh) & 255u;
        atomicAdd(&h[b + (b >> 4)], 1u);
      }
    }
    unsigned b4[4], lsum = 0u;
#pragma unroll
    for (int i = 0; i < 4; ++i) {
      const unsigned x = (unsigned)(lane * 4 + i);
      b4[i] = h[x + (x >> 4)];
      lsum += b4[i];
    }
    unsigned s = lsum;
#pragma unroll
    for (int off = 1; off < 64; off <<= 1) {
      const unsigned v = __shfl_down(s, off);
      if (lane + off < 64) s += v;
    }
    unsigned run = s - lsum;
    unsigned fb = 0u, fn = 0u, ft = 0u;
    bool found = false;
#pragma unroll
    for (int i = 3; i >= 0; --i) {
      const unsigned c = b4[i];
      if (!found && c > 0u && run < needK && run + c >= needK) {
        found = true; fb = (unsigned)(lane * 4 + i); fn = needK - run; ft = c;
      }
      run += c;
    }
    const unsigned long long msk = __ballot(found);
    const int src = (int)__ffsll(msk) - 1;
    prefix |= __shfl(fb, src) << sh;
    needK   = __shfl(fn, src);
    tieC    = __shfl(ft, src);
  }

  // ---- pass 4: bits [5:0], 64 bins -> exact T and tie count ----
  unsigned T;
  {
    h[lane] = 0u;
    if (lane < 4) h[64 + lane] = 0u;
    const unsigned pcmp = prefix >> 6;
#pragma unroll
    for (int i = 0; i < 32; ++i) {
      if ((k[i] >> 6) == pcmp) {
        const unsigned b = k[i] & 63u;
        atomicAdd(&h[b + (b >> 4)], 1u);
      }
    }
    const unsigned b0 = h[lane + (lane >> 4)];
    unsigned s = b0;
#pragma unroll
    for (int off = 1; off < 64; off <<= 1) {
      const unsigned v = __shfl_down(s, off);
      if (lane + off < 64) s += v;
    }
    const unsigned run = s - b0;
    const bool found = (b0 > 0u && run < needK && run + b0 >= needK);
    const unsigned long long msk = __ballot(found);
    const int src = (int)__ffsll(msk) - 1;
    T     = prefix | (unsigned)__shfl((unsigned)lane, src);
    needK = __shfl(needK - run, src);
    tieC  = __shfl(b0, src);
  }

  // ---- rare: >needK duplicates of T -> keep lowest indices (index order) ----
  if (tieC != needK) {
    unsigned R = 0u;
#pragma unroll
    for (int i = 0; i < 8; ++i) {
      unsigned myEq = 0u;
#pragma unroll
      for (int c = 0; c < 4; ++c) myEq += (k[i * 4 + c] == T);
      unsigned ps = myEq;
#pragma unroll
      for (int off = 1; off < 64; off <<= 1) {
        const unsigned v = __shfl_up(ps, off);
        if (lane >= off) ps += v;
      }
      unsigned before = R + ps - myEq;
#pragma unroll
      for (int c = 0; c < 4; ++c) {
        if (k[i * 4 + c] == T) {
          if (before >= needK) k[i * 4 + c] = 0u;
          ++before;
        }
      }
      R += __shfl(ps, 63);
    }
  }

  // ---- exp in place (k regs become weight bits), Z reduce, store ----
  float lz = 0.f;
#pragma unroll
  for (int i = 0; i < 32; ++i) {
    const unsigned kk = k[i];
    const float w = (kk >= T) ? __expf(key_to_float(kk) - m) : 0.f;
    k[i] = __float_as_uint(w);
    lz += w;
  }
#pragma unroll
  for (int off = 32; off > 0; off >>= 1) lz += __shfl_xor(lz, off);
  const float Zi = 1.0f / lz;

#pragma unroll
  for (int i = 0; i < 8; ++i) {
    float4 o;
    o.x = __uint_as_float(k[i * 4 + 0]) * Zi;
    o.y = __uint_as_float(k[i * 4 + 1]) * Zi;
    o.z = __uint_as_float(k[i * 4 + 2]) * Zi;
    o.w = __uint_as_float(k[i * 4 + 3]) * Zi;
    *(float4*)(rowu + i * 256 + lane * 4) = o;
  }
}

}  // namespace

extern "C" void kernel_launch(void* const* d_in, const int* in_sizes, int n_in,
                              void* d_out_v, int out_size, void* d_ws, size_t ws_size,
                              hipStream_t stream)
{
  const float* query = (const float*)d_in[0];
  const float* key   = (const float*)d_in[1];
  const float* value = (const float*)d_in[2];
  const float* Wq = (const float*)d_in[3];  const float* bq = (const float*)d_in[4];
  const float* Wk = (const float*)d_in[5];  const float* bk = (const float*)d_in[6];
  const float* Wv = (const float*)d_in[7];  const float* bv = (const float*)d_in[8];
  const float* Wo = (const float*)d_in[9];  const float* bo = (const float*)d_in[10];

  float* d_out = (float*)d_out_v;
  float* outp  = d_out;                              // [B,S,D] f32
  float* wts   = d_out + (size_t)Bb * Ss * Dd;       // [B,H,S,S] f32

  const size_t PROJ = (size_t)MROWS * Dd;            // 4M elements
  const size_t DD2  = (size_t)Dd * Dd;               // 1M elements

  ushort* ws    = (ushort*)d_ws;
  ushort* Qh    = ws;                                // 8 MB each
  ushort* Ql    = Qh + PROJ;
  ushort* Kh    = Ql + PROJ;
  ushort* Kl    = Kh + PROJ;                         // ends at 32 MB
  ushort* wreg  = Kl + PROJ;
  ushort* WqTh  = wreg;                              // 6 x 2 MB splits
  ushort* WqTl  = wreg + DD2;
  ushort* WkTh  = wreg + 2 * DD2;
  ushort* WkTl  = wreg + 3 * DD2;
  ushort* WvTh  = wreg + 4 * DD2;
  ushort* WvTl  = wreg + 5 * DD2;
  ushort* WoT   = wreg + 6 * DD2;                    // 2 MB
  ushort* Vt    = wreg + 7 * DD2;                    // bf16 V^T [16][128][2048] 8 MB
  float*  pvp   = (float*)Qh;                        // pv partials alias Qh..Kl (32 MB)

  const dim3 blk(256);

  // weight prep
  transpose_split<<<dim3(32, 32), blk, 0, stream>>>(Wq, WqTh, WqTl);
  transpose_split<<<dim3(32, 32), blk, 0, stream>>>(Wk, WkTh, WkTl);
  transpose_split<<<dim3(32, 32), blk, 0, stream>>>(Wv, WvTh, WvTl);
  transpose_bf16<<<dim3(32, 32), blk, 0, stream>>>(Wo, WoT);

  // Q/K/V projections, batched: Q,K -> pre-split hi/lo; V -> Vt
  mfma_proj<<<dim3(Dd / 128, MROWS / 128, 3), blk, 0, stream>>>(
      query, key, value, WqTh, WqTl, WkTh, WkTl, WvTh, WvTl,
      bq, bk, bv, Qh, Ql, Kh, Kl, Vt);

  // scores -> u32 keys in wts region (SCALE folded)
  mfma_scores<<<dim3(Ss / 128, Ss / 128, BH), blk, 0, stream>>>(
      Qh, Ql, Kh, Kl, (unsigned*)wts);

  // exact top-512 + softmax, in place (wave-per-row)
  topk_softmax<<<dim3(BH * Ss / 4), blk, 0, stream>>>(wts);

  // PV split-K=2 -> f32 partials (aliasing dead Qh..Kl)
  pv_split<<<dim3(2, Ss / 128, BH), blk, 0, stream>>>(wts, Vt, pvp);

  // output projection with inline partial-reduce
  mfma_oproj<<<dim3(Dd / 128, MROWS / 128), blk, 0, stream>>>(
      pvp, pvp + (size_t)MROWS * Dd, WoT, bo, outp);
}

// Round 12
// 436.321 us; speedup vs baseline: 1.4829x; 1.0404x over previous
//
#include <hip/hip_runtime.h>
#include <hip/hip_bf16.h>
#include <math.h>

namespace {

constexpr int Bb   = 2;
constexpr int Ss   = 2048;
constexpr int Dd   = 1024;
constexpr int Hh   = 8;
constexpr int DKk  = 128;
constexpr int KTOP = 512;
constexpr int BH    = Bb * Hh;   // 16
constexpr int MROWS = Bb * Ss;   // 4096
constexpr float SCALE = 0.08838834764831845f;  // 1/sqrt(128)

typedef __attribute__((ext_vector_type(8))) short short8t;  // 8 bf16 = 16 B
typedef __attribute__((ext_vector_type(4))) short short4t;  // 4 bf16 = 8 B
typedef __attribute__((ext_vector_type(4))) float f32x4;

__device__ inline ushort f2bf(float x) {  // f32 -> bf16 RNE
  const unsigned u = __float_as_uint(x);
  return (ushort)((u + 0x7FFFu + ((u >> 16) & 1u)) >> 16);
}
__device__ inline float bf2f(ushort h) {
  return __uint_as_float(((unsigned)h) << 16);
}
struct HL { short h, l; };
__device__ inline HL split1(float x) {
  HL r;
  const ushort hu = f2bf(x);
  r.h = (short)hu;
  r.l = (short)f2bf(x - bf2f(hu));
  return r;
}

__device__ inline unsigned key_of(float v) {
  const unsigned u = __float_as_uint(v);
  return (u & 0x80000000u) ? ~u : (u | 0x80000000u);
}
__device__ inline float key_to_float(unsigned k) {
  const unsigned u = (k & 0x80000000u) ? (k & 0x7FFFFFFFu) : ~k;
  return __uint_as_float(u);
}

// ---------------------------------------------------------------------------
// Batched Q/K/V projection, split-bf16 MFMA NT.
// v2: 128x64 tile (6 blocks/CU), grid x = M-block (XCD-local A panels),
// z: 0=Q, 1=K (3-term split, out hi/lo bf16 [bh][s][dk]),
//    2=V (1-term plain bf16, out Vt[bh][dk][s]).
// ---------------------------------------------------------------------------
__global__ __launch_bounds__(256) void mfma_proj(
    const float* __restrict__ query, const float* __restrict__ keyi,
    const float* __restrict__ value,
    const ushort* __restrict__ WqTh, const ushort* __restrict__ WqTl,
    const ushort* __restrict__ WkTh, const ushort* __restrict__ WkTl,
    const ushort* __restrict__ WvTh, const ushort* __restrict__ WvTl,
    const float* __restrict__ bq, const float* __restrict__ bk,
    const float* __restrict__ bv,
    ushort* __restrict__ Qh, ushort* __restrict__ Ql,
    ushort* __restrict__ Kh, ushort* __restrict__ Kl,
    ushort* __restrict__ Vt)
{
  __shared__ ushort AhS[128 * 32];  // 8 KB
  __shared__ ushort AlS[128 * 32];  // 8 KB
  __shared__ ushort BhS[64 * 32];   // 4 KB
  __shared__ ushort BlS[64 * 32];   // 4 KB
  const int t  = threadIdx.x;
  const int z  = blockIdx.z;
  const int m0 = blockIdx.x * 128;  // x = M-block: A-panel XCD locality
  const int n0 = blockIdx.y * 64;
  const int l  = t & 63, wv = t >> 6;
  const int wr = wv >> 1, wc = wv & 1;   // wave owns 64x32 quadrant
  const int lrow = l & 15, lhi = l >> 4;

  const float*  A    = (z == 0) ? query : (z == 1) ? keyi : value;
  const ushort* Bth  = (z == 0) ? WqTh  : (z == 1) ? WkTh : WvTh;
  const ushort* Btl  = (z == 0) ? WqTl  : (z == 1) ? WkTl : WvTl;
  const float*  bias = (z == 0) ? bq    : (z == 1) ? bk   : bv;
  const bool    splitTerms = (z < 2);

  f32x4 acc[4][2] = {};

  for (int kt = 0; kt < Dd; kt += 32) {
    // A staging (128 rows x 32 k), inline hi/lo split
#pragma unroll
    for (int p = 0; p < 2; ++p) {
      const int li = p * 256 + t, row = li >> 2, g = li & 3;
      const int sw = row * 32 + ((g ^ (row & 3)) << 3);
      const float* src = A + (size_t)(m0 + row) * Dd + kt + g * 8;
      const float4 v0 = *(const float4*)src;
      const float4 v1 = *(const float4*)(src + 4);
      short8t h, lo;
      HL r;
      r = split1(v0.x); h[0] = r.h; lo[0] = r.l;
      r = split1(v0.y); h[1] = r.h; lo[1] = r.l;
      r = split1(v0.z); h[2] = r.h; lo[2] = r.l;
      r = split1(v0.w); h[3] = r.h; lo[3] = r.l;
      r = split1(v1.x); h[4] = r.h; lo[4] = r.l;
      r = split1(v1.y); h[5] = r.h; lo[5] = r.l;
      r = split1(v1.z); h[6] = r.h; lo[6] = r.l;
      r = split1(v1.w); h[7] = r.h; lo[7] = r.l;
      *(short8t*)&AhS[sw] = h;
      if (splitTerms) *(short8t*)&AlS[sw] = lo;
    }
    // B staging (64 rows x 32 k)
    {
      const int row = t >> 2, g = t & 3;
      const int sw = row * 32 + ((g ^ (row & 3)) << 3);
      const size_t off = (size_t)(n0 + row) * Dd + kt + g * 8;
      *(short8t*)&BhS[sw] = *(const short8t*)(Bth + off);
      if (splitTerms) *(short8t*)&BlS[sw] = *(const short8t*)(Btl + off);
    }
    __syncthreads();

    short8t ah[4], al[4], bh[2], bl[2];
#pragma unroll
    for (int i = 0; i < 4; ++i) {
      const int row = wr * 64 + i * 16 + lrow;
      const int idx = row * 32 + ((lhi ^ (row & 3)) << 3);
      ah[i] = *(const short8t*)&AhS[idx];
      if (splitTerms) al[i] = *(const short8t*)&AlS[idx];
    }
#pragma unroll
    for (int j = 0; j < 2; ++j) {
      const int row = wc * 32 + j * 16 + lrow;
      const int idx = row * 32 + ((lhi ^ (row & 3)) << 3);
      bh[j] = *(const short8t*)&BhS[idx];
      if (splitTerms) bl[j] = *(const short8t*)&BlS[idx];
    }
#pragma unroll
    for (int i = 0; i < 4; ++i)
#pragma unroll
      for (int j = 0; j < 2; ++j) {
        acc[i][j] = __builtin_amdgcn_mfma_f32_16x16x32_bf16(ah[i], bh[j], acc[i][j], 0, 0, 0);
        if (splitTerms) {
          acc[i][j] = __builtin_amdgcn_mfma_f32_16x16x32_bf16(ah[i], bl[j], acc[i][j], 0, 0, 0);
          acc[i][j] = __builtin_amdgcn_mfma_f32_16x16x32_bf16(al[i], bh[j], acc[i][j], 0, 0, 0);
        }
      }
    __syncthreads();
  }

#pragma unroll
  for (int i = 0; i < 4; ++i) {
#pragma unroll
    for (int j = 0; j < 2; ++j) {
      const int nn = n0 + wc * 32 + j * 16 + lrow;
#pragma unroll
      for (int r = 0; r < 4; ++r) {
        const int mm = m0 + wr * 64 + i * 16 + lhi * 4 + r;
        const float v = acc[i][j][r] + bias[nn];
        const int bb = mm >> 11, s = mm & (Ss - 1);
        const int hh = nn >> 7,  dk = nn & (DKk - 1);
        if (z < 2) {
          const size_t o = (((size_t)(bb * Hh + hh)) * Ss + s) * DKk + dk;
          const HL rr = split1(v);
          if (z == 0) { Qh[o] = (ushort)rr.h; Ql[o] = (ushort)rr.l; }
          else        { Kh[o] = (ushort)rr.h; Kl[o] = (ushort)rr.l; }
        } else {
          Vt[((size_t)((bb * Hh + hh) * DKk + dk)) * Ss + s] = f2bf(v);
        }
      }
    }
  }
}

// ---------------------------------------------------------------------------
// Scores from pre-split Q,K; epilogue writes order-flipped u32 keys (SCALE in)
// ---------------------------------------------------------------------------
__global__ __launch_bounds__(256) void mfma_scores(
    const ushort* __restrict__ Qh, const ushort* __restrict__ Ql,
    const ushort* __restrict__ Kh, const ushort* __restrict__ Kl,
    unsigned* __restrict__ wtsOut)
{
  __shared__ ushort Ah[128 * 32];
  __shared__ ushort Al[128 * 32];
  __shared__ ushort Bh[128 * 32];
  __shared__ ushort Bl[128 * 32];
  const int t  = threadIdx.x;
  const int z  = blockIdx.z;
  const int n0 = blockIdx.x * 128;   // j
  const int m0 = blockIdx.y * 128;   // q
  const int l  = t & 63, wv = t >> 6;
  const int wr = wv >> 1, wc = wv & 1;
  const int lrow = l & 15, lhi = l >> 4;
  const size_t boff = (size_t)z * Ss * DKk;

  f32x4 acc[4][4] = {};

  for (int kt = 0; kt < DKk; kt += 32) {
#pragma unroll
    for (int p = 0; p < 2; ++p) {
      const int li = p * 256 + t, row = li >> 2, g = li & 3;
      const int sw = row * 32 + ((g ^ (row & 3)) << 3);
      const size_t ao = boff + (size_t)(m0 + row) * DKk + kt + g * 8;
      *(short8t*)&Ah[sw] = *(const short8t*)(Qh + ao);
      *(short8t*)&Al[sw] = *(const short8t*)(Ql + ao);
      const size_t bo = boff + (size_t)(n0 + row) * DKk + kt + g * 8;
      *(short8t*)&Bh[sw] = *(const short8t*)(Kh + bo);
      *(short8t*)&Bl[sw] = *(const short8t*)(Kl + bo);
    }
    __syncthreads();

    short8t ah[4], al[4], bh[4], bl[4];
#pragma unroll
    for (int i = 0; i < 4; ++i) {
      const int row = wr * 64 + i * 16 + lrow;
      const int idx = row * 32 + ((lhi ^ (row & 3)) << 3);
      ah[i] = *(const short8t*)&Ah[idx];
      al[i] = *(const short8t*)&Al[idx];
    }
#pragma unroll
    for (int j = 0; j < 4; ++j) {
      const int row = wc * 64 + j * 16 + lrow;
      const int idx = row * 32 + ((lhi ^ (row & 3)) << 3);
      bh[j] = *(const short8t*)&Bh[idx];
      bl[j] = *(const short8t*)&Bl[idx];
    }
#pragma unroll
    for (int i = 0; i < 4; ++i)
#pragma unroll
      for (int j = 0; j < 4; ++j) {
        acc[i][j] = __builtin_amdgcn_mfma_f32_16x16x32_bf16(ah[i], bh[j], acc[i][j], 0, 0, 0);
        acc[i][j] = __builtin_amdgcn_mfma_f32_16x16x32_bf16(ah[i], bl[j], acc[i][j], 0, 0, 0);
        acc[i][j] = __builtin_amdgcn_mfma_f32_16x16x32_bf16(al[i], bh[j], acc[i][j], 0, 0, 0);
      }
    __syncthreads();
  }

#pragma unroll
  for (int i = 0; i < 4; ++i)
#pragma unroll
    for (int j = 0; j < 4; ++j) {
      const int nn = n0 + wc * 64 + j * 16 + lrow;
#pragma unroll
      for (int r = 0; r < 4; ++r) {
        const int mm = m0 + wr * 64 + i * 16 + lhi * 4 + r;
        wtsOut[(size_t)z * Ss * Ss + (size_t)mm * Ss + nn] =
            key_of(acc[i][j][r] * SCALE);
      }
    }
}

// ---------------------------------------------------------------------------
// o_proj with inline pv-partial reduce; grid x = M-block (A-panel locality)
// ---------------------------------------------------------------------------
__global__ __launch_bounds__(256) void mfma_oproj(
    const float* __restrict__ pv0, const float* __restrict__ pv1,
    const ushort* __restrict__ Bt,
    const float* __restrict__ bias, float* __restrict__ Cout)
{
  __shared__ ushort As[128 * 64];
  __shared__ ushort Bs[128 * 64];
  const int t  = threadIdx.x;
  const int m0 = blockIdx.x * 128;
  const int n0 = blockIdx.y * 128;
  const int l  = t & 63, wv = t >> 6;
  const int wr = wv >> 1, wc = wv & 1;
  const int lrow = l & 15, lhi = l >> 4;

  f32x4 acc[4][4] = {};

  for (int kt = 0; kt < Dd; kt += 64) {
#pragma unroll
    for (int p = 0; p < 4; ++p) {
      const int li = p * 256 + t, row = li >> 3, g = li & 7;
      const int sw = row * 64 + ((g ^ (row & 7)) << 3);
      const size_t ao = (size_t)(m0 + row) * Dd + kt + g * 8;
      const float4 a0 = *(const float4*)(pv0 + ao);
      const float4 a1 = *(const float4*)(pv0 + ao + 4);
      const float4 c0 = *(const float4*)(pv1 + ao);
      const float4 c1 = *(const float4*)(pv1 + ao + 4);
      short8t sa;
      sa[0] = (short)f2bf(a0.x + c0.x); sa[1] = (short)f2bf(a0.y + c0.y);
      sa[2] = (short)f2bf(a0.z + c0.z); sa[3] = (short)f2bf(a0.w + c0.w);
      sa[4] = (short)f2bf(a1.x + c1.x); sa[5] = (short)f2bf(a1.y + c1.y);
      sa[6] = (short)f2bf(a1.z + c1.z); sa[7] = (short)f2bf(a1.w + c1.w);
      *(short8t*)&As[sw] = sa;
      *(short8t*)&Bs[sw] = *(const short8t*)(Bt + (size_t)(n0 + row) * Dd + kt + g * 8);
    }
    __syncthreads();

#pragma unroll
    for (int kk = 0; kk < 2; ++kk) {
      short8t a[4], b[4];
      const int g = kk * 4 + lhi;
#pragma unroll
      for (int i = 0; i < 4; ++i) {
        const int row = wr * 64 + i * 16 + lrow;
        a[i] = *(const short8t*)&As[row * 64 + ((g ^ (row & 7)) << 3)];
      }
#pragma unroll
      for (int j = 0; j < 4; ++j) {
        const int row = wc * 64 + j * 16 + lrow;
        b[j] = *(const short8t*)&Bs[row * 64 + ((g ^ (row & 7)) << 3)];
      }
#pragma unroll
      for (int i = 0; i < 4; ++i)
#pragma unroll
        for (int j = 0; j < 4; ++j)
          acc[i][j] = __builtin_amdgcn_mfma_f32_16x16x32_bf16(a[i], b[j], acc[i][j], 0, 0, 0);
    }
    __syncthreads();
  }

#pragma unroll
  for (int i = 0; i < 4; ++i)
#pragma unroll
    for (int j = 0; j < 4; ++j) {
      const int nn = n0 + wc * 64 + j * 16 + lrow;
#pragma unroll
      for (int r = 0; r < 4; ++r) {
        const int mm = m0 + wr * 64 + i * 16 + lhi * 4 + r;
        Cout[(size_t)mm * Dd + nn] = acc[i][j][r] + bias[nn];
      }
    }
}

// ---------------------------------------------------------------------------
// PV with split-K=2: grid (2, S/128, BH); f32 partials -> pvp[ks][B,S,D]
// ---------------------------------------------------------------------------
__global__ __launch_bounds__(256) void pv_split(
    const float* __restrict__ Wts, const ushort* __restrict__ VtAll,
    float* __restrict__ pvp)
{
  __shared__ ushort As[128 * 64];
  __shared__ ushort Bs[128 * 64];
  const int t  = threadIdx.x;
  const int ks = blockIdx.x;
  const int m0 = blockIdx.y * 128;
  const int z  = blockIdx.z;
  const int l  = t & 63, wv = t >> 6;
  const int wr = wv >> 1, wc = wv & 1;
  const int lrow = l & 15, lhi = l >> 4;

  const float*  Af = Wts + (size_t)z * Ss * Ss;
  const ushort* Bt = VtAll + (size_t)z * DKk * Ss;

  f32x4 acc[4][4] = {};

  for (int kt = ks * 1024; kt < ks * 1024 + 1024; kt += 64) {
#pragma unroll
    for (int p = 0; p < 4; ++p) {
      const int li = p * 256 + t, row = li >> 3, g = li & 7;
      const int sw = row * 64 + ((g ^ (row & 7)) << 3);
      const float* src = Af + (size_t)(m0 + row) * Ss + kt + g * 8;
      const float4 v0 = *(const float4*)src;
      const float4 v1 = *(const float4*)(src + 4);
      short8t sa;
      sa[0] = (short)f2bf(v0.x); sa[1] = (short)f2bf(v0.y);
      sa[2] = (short)f2bf(v0.z); sa[3] = (short)f2bf(v0.w);
      sa[4] = (short)f2bf(v1.x); sa[5] = (short)f2bf(v1.y);
      sa[6] = (short)f2bf(v1.z); sa[7] = (short)f2bf(v1.w);
      *(short8t*)&As[sw] = sa;
      *(short8t*)&Bs[sw] = *(const short8t*)(Bt + (size_t)row * Ss + kt + g * 8);
    }
    __syncthreads();

#pragma unroll
    for (int kk = 0; kk < 2; ++kk) {
      short8t a[4], b[4];
      const int g = kk * 4 + lhi;
#pragma unroll
      for (int i = 0; i < 4; ++i) {
        const int row = wr * 64 + i * 16 + lrow;
        a[i] = *(const short8t*)&As[row * 64 + ((g ^ (row & 7)) << 3)];
      }
#pragma unroll
      for (int j = 0; j < 4; ++j) {
        const int row = wc * 64 + j * 16 + lrow;
        b[j] = *(const short8t*)&Bs[row * 64 + ((g ^ (row & 7)) << 3)];
      }
#pragma unroll
      for (int i = 0; i < 4; ++i)
#pragma unroll
        for (int j = 0; j < 4; ++j)
          acc[i][j] = __builtin_amdgcn_mfma_f32_16x16x32_bf16(a[i], b[j], acc[i][j], 0, 0, 0);
    }
    __syncthreads();
  }

  const int bb = z >> 3, hh = z & 7;
  float* outp = pvp + (size_t)ks * MROWS * Dd;
#pragma unroll
  for (int i = 0; i < 4; ++i)
#pragma unroll
    for (int j = 0; j < 4; ++j) {
      const int nn = wc * 64 + j * 16 + lrow;
#pragma unroll
      for (int r = 0; r < 4; ++r) {
        const int mm = m0 + wr * 64 + i * 16 + lhi * 4 + r;
        outp[((size_t)(bb * Ss + mm)) * Dd + hh * DKk + nn] = acc[i][j][r];
      }
    }
}

// ---------------------------------------------------------------------------
// W[1024][1024] f32 -> Wt bf16 (transposed)
// ---------------------------------------------------------------------------
__global__ __launch_bounds__(256) void transpose_bf16(
    const float* __restrict__ W, ushort* __restrict__ Wt)
{
  __shared__ float tile[32][33];
  const int t  = threadIdx.x;
  const int c0 = blockIdx.x * 32, r0 = blockIdx.y * 32;
  const int lr = t >> 3, lc4 = (t & 7) * 4;
  const float4 v = *(const float4*)(W + (size_t)(r0 + lr) * Dd + c0 + lc4);
  tile[lr][lc4 + 0] = v.x; tile[lr][lc4 + 1] = v.y;
  tile[lr][lc4 + 2] = v.z; tile[lr][lc4 + 3] = v.w;
  __syncthreads();
  const int oc = t >> 3, or4 = (t & 7) * 4;
  short4t o;
  o[0] = (short)f2bf(tile[or4 + 0][oc]);
  o[1] = (short)f2bf(tile[or4 + 1][oc]);
  o[2] = (short)f2bf(tile[or4 + 2][oc]);
  o[3] = (short)f2bf(tile[or4 + 3][oc]);
  *(short4t*)(Wt + (size_t)(c0 + oc) * Dd + r0 + or4) = o;
}

// ---------------------------------------------------------------------------
// W[1024][1024] f32 -> transposed hi/lo bf16 split
// ---------------------------------------------------------------------------
__global__ __launch_bounds__(256) void transpose_split(
    const float* __restrict__ W, ushort* __restrict__ Th, ushort* __restrict__ Tl)
{
  __shared__ float tile[32][33];
  const int t  = threadIdx.x;
  const int c0 = blockIdx.x * 32, r0 = blockIdx.y * 32;
  const int lr = t >> 3, lc4 = (t & 7) * 4;
  const float4 v = *(const float4*)(W + (size_t)(r0 + lr) * Dd + c0 + lc4);
  tile[lr][lc4 + 0] = v.x; tile[lr][lc4 + 1] = v.y;
  tile[lr][lc4 + 2] = v.z; tile[lr][lc4 + 3] = v.w;
  __syncthreads();
  const int oc = t >> 3, or4 = (t & 7) * 4;
  short4t oh, ol;
  HL r;
  r = split1(tile[or4 + 0][oc]); oh[0] = r.h; ol[0] = r.l;
  r = split1(tile[or4 + 1][oc]); oh[1] = r.h; ol[1] = r.l;
  r = split1(tile[or4 + 2][oc]); oh[2] = r.h; ol[2] = r.l;
  r = split1(tile[or4 + 3][oc]); oh[3] = r.h; ol[3] = r.l;
  *(short4t*)(Th + (size_t)(c0 + oc) * Dd + r0 + or4) = oh;
  *(short4t*)(Tl + (size_t)(c0 + oc) * Dd + r0 + or4) = ol;
}

// ---------------------------------------------------------------------------
// Per-row exact top-512 + softmax, v6: wave-per-row, zero __syncthreads.
// ---------------------------------------------------------------------------
__global__ __launch_bounds__(256) void topk_softmax(float* __restrict__ wts)
{
  __shared__ unsigned histAll[4][1088];

  const int lane = threadIdx.x & 63;
  const int wv   = threadIdx.x >> 6;
  const int row  = blockIdx.x * 4 + wv;
  float* rowp = wts + (size_t)row * Ss;
  unsigned* rowu = (unsigned*)rowp;
  unsigned* h = histAll[wv];

  unsigned k[32];
  unsigned lmax = 0u;
#pragma unroll
  for (int i = 0; i < 8; ++i) {
    const uint4 v = *(const uint4*)(rowu + i * 256 + lane * 4);
    k[i * 4 + 0] = v.x; k[i * 4 + 1] = v.y;
    k[i * 4 + 2] = v.z; k[i * 4 + 3] = v.w;
    lmax = max(max(lmax, max(v.x, v.y)), max(v.z, v.w));
  }
#pragma unroll
  for (int off = 32; off > 0; off >>= 1) lmax = max(lmax, __shfl_xor(lmax, off));
  const float m = key_to_float(lmax);

  unsigned needK = KTOP, tieC = 0u, prefix = 0u;

  // pass 1: bits [31:22], 1024 bins
  {
#pragma unroll
    for (int i = 0; i < 17; ++i) h[lane + i * 64] = 0u;
#pragma unroll
    for (int i = 0; i < 32; ++i) {
      const unsigned b = k[i] >> 22;
      atomicAdd(&h[b + (b >> 4)], 1u);
    }
    unsigned b[16], lsum = 0u;
#pragma unroll
    for (int i = 0; i < 16; ++i) { b[i] = h[lane * 17 + i]; lsum += b[i]; }
    unsigned s = lsum;
#pragma unroll
    for (int off = 1; off < 64; off <<= 1) {
      const unsigned v = __shfl_down(s, off);
      if (lane + off < 64) s += v;
    }
    unsigned run = s - lsum;
    unsigned fb = 0u, fn = 0u, ft = 0u;
    bool found = false;
#pragma unroll
    for (int i = 15; i >= 0; --i) {
      const unsigned c = b[i];
      if (!found && c > 0u && run < needK && run + c >= needK) {
        found = true; fb = (unsigned)(lane * 16 + i); fn = needK - run; ft = c;
      }
      run += c;
    }
    const unsigned long long msk = __ballot(found);
    const int src = (int)__ffsll(msk) - 1;
    prefix = __shfl(fb, src) << 22;
    needK  = __shfl(fn, src);
    tieC   = __shfl(ft, src);
  }

  // passes 2,3: 8-bit refinements (bits [21:14], [13:6])
#pragma unroll
  for (int pass = 0; pass < 2; ++pass) {
    const int sh = (pass == 0) ? 14 : 6;
    const int ph = sh + 8;
#pragma unroll
    for (int i = 0; i < 5; ++i) h[lane + i * 64] = 0u;
    const unsigned pcmp = prefix >> ph;
#pragma unroll
    for (int i = 0; i < 32; ++i) {
      if ((k[i] >> ph) == pcmp) {
        const unsigned b = (k[i] >> sh) & 255u;
        atomicAdd(&h[b + (b >> 4)], 1u);
      }
    }
    unsigned b4[4], lsum = 0u;
#pragma unroll
    for (int i = 0; i < 4; ++i) {
      const unsigned x = (unsigned)(lane * 4 + i);
      b4[i] = h[x + (x >> 4)];
      lsum += b4[i];
    }
    unsigned s = lsum;
#pragma unroll
    for (int off = 1; off < 64; off <<= 1) {
      const unsigned v = __shfl_down(s, off);
      if (lane + off < 64) s += v;
    }
    unsigned run = s - lsum;
    unsigned fb = 0u, fn = 0u, ft = 0u;
    bool found = false;
#pragma unroll
    for (int i = 3; i >= 0; --i) {
      const unsigned c = b4[i];
      if (!found && c > 0u && run < needK && run + c >= needK) {
        found = true; fb = (unsigned)(lane * 4 + i); fn = needK - run; ft = c;
      }
      run += c;
    }
    const unsigned long long msk = __ballot(found);
    const int src = (int)__ffsll(msk) - 1;
    prefix |= __shfl(fb, src) << sh;
    needK   = __shfl(fn, src);
    tieC    = __shfl(ft, src);
  }

  // pass 4: bits [5:0]
  unsigned T;
  {
    h[lane] = 0u;
    if (lane < 4) h[64 + lane] = 0u;
    const unsigned pcmp = prefix >> 6;
#pragma unroll
    for (int i = 0; i < 32; ++i) {
      if ((k[i] >> 6) == pcmp) {
        const unsigned b = k[i] & 63u;
        atomicAdd(&h[b + (b >> 4)], 1u);
      }
    }
    const unsigned b0 = h[lane + (lane >> 4)];
    unsigned s = b0;
#pragma unroll
    for (int off = 1; off < 64; off <<= 1) {
      const unsigned v = __shfl_down(s, off);
      if (lane + off < 64) s += v;
    }
    const unsigned run = s - b0;
    const bool found = (b0 > 0u && run < needK && run + b0 >= needK);
    const unsigned long long msk = __ballot(found);
    const int src = (int)__ffsll(msk) - 1;
    T     = prefix | (unsigned)__shfl((unsigned)lane, src);
    needK = __shfl(needK - run, src);
    tieC  = __shfl(b0, src);
  }

  if (tieC != needK) {
    unsigned R = 0u;
#pragma unroll
    for (int i = 0; i < 8; ++i) {
      unsigned myEq = 0u;
#pragma unroll
      for (int c = 0; c < 4; ++c) myEq += (k[i * 4 + c] == T);
      unsigned ps = myEq;
#pragma unroll
      for (int off = 1; off < 64; off <<= 1) {
        const unsigned v = __shfl_up(ps, off);
        if (lane >= off) ps += v;
      }
      unsigned before = R + ps - myEq;
#pragma unroll
      for (int c = 0; c < 4; ++c) {
        if (k[i * 4 + c] == T) {
          if (before >= needK) k[i * 4 + c] = 0u;
          ++before;
        }
      }
      R += __shfl(ps, 63);
    }
  }

  float lz = 0.f;
#pragma unroll
  for (int i = 0; i < 32; ++i) {
    const unsigned kk = k[i];
    const float w = (kk >= T) ? __expf(key_to_float(kk) - m) : 0.f;
    k[i] = __float_as_uint(w);
    lz += w;
  }
#pragma unroll
  for (int off = 32; off > 0; off >>= 1) lz += __shfl_xor(lz, off);
  const float Zi = 1.0f / lz;

#pragma unroll
  for (int i = 0; i < 8; ++i) {
    float4 o;
    o.x = __uint_as_float(k[i * 4 + 0]) * Zi;
    o.y = __uint_as_float(k[i * 4 + 1]) * Zi;
    o.z = __uint_as_float(k[i * 4 + 2]) * Zi;
    o.w = __uint_as_float(k[i * 4 + 3]) * Zi;
    *(float4*)(rowu + i * 256 + lane * 4) = o;
  }
}

}  // namespace

extern "C" void kernel_launch(void* const* d_in, const int* in_sizes, int n_in,
                              void* d_out_v, int out_size, void* d_ws, size_t ws_size,
                              hipStream_t stream)
{
  const float* query = (const float*)d_in[0];
  const float* key   = (const float*)d_in[1];
  const float* value = (const float*)d_in[2];
  const float* Wq = (const float*)d_in[3];  const float* bq = (const float*)d_in[4];
  const float* Wk = (const float*)d_in[5];  const float* bk = (const float*)d_in[6];
  const float* Wv = (const float*)d_in[7];  const float* bv = (const float*)d_in[8];
  const float* Wo = (const float*)d_in[9];  const float* bo = (const float*)d_in[10];

  float* d_out = (float*)d_out_v;
  float* outp  = d_out;                              // [B,S,D] f32
  float* wts   = d_out + (size_t)Bb * Ss * Dd;       // [B,H,S,S] f32

  const size_t PROJ = (size_t)MROWS * Dd;            // 4M elements
  const size_t DD2  = (size_t)Dd * Dd;               // 1M elements

  ushort* ws    = (ushort*)d_ws;
  ushort* Qh    = ws;                                // 8 MB each
  ushort* Ql    = Qh + PROJ;
  ushort* Kh    = Ql + PROJ;
  ushort* Kl    = Kh + PROJ;                         // ends at 32 MB
  ushort* wreg  = Kl + PROJ;
  ushort* WqTh  = wreg;                              // 6 x 2 MB splits
  ushort* WqTl  = wreg + DD2;
  ushort* WkTh  = wreg + 2 * DD2;
  ushort* WkTl  = wreg + 3 * DD2;
  ushort* WvTh  = wreg + 4 * DD2;
  ushort* WvTl  = wreg + 5 * DD2;
  ushort* WoT   = wreg + 6 * DD2;                    // 2 MB
  ushort* Vt    = wreg + 7 * DD2;                    // bf16 V^T [16][128][2048] 8 MB
  float*  pvp   = (float*)Qh;                        // pv partials alias Qh..Kl (32 MB)

  const dim3 blk(256);

  // weight prep
  transpose_split<<<dim3(32, 32), blk, 0, stream>>>(Wq, WqTh, WqTl);
  transpose_split<<<dim3(32, 32), blk, 0, stream>>>(Wk, WkTh, WkTl);
  transpose_split<<<dim3(32, 32), blk, 0, stream>>>(Wv, WvTh, WvTl);
  transpose_bf16<<<dim3(32, 32), blk, 0, stream>>>(Wo, WoT);

  // Q/K/V projections, batched, 128x64 tile, x = M-block (XCD-local A)
  mfma_proj<<<dim3(MROWS / 128, Dd / 64, 3), blk, 0, stream>>>(
      query, key, value, WqTh, WqTl, WkTh, WkTl, WvTh, WvTl,
      bq, bk, bv, Qh, Ql, Kh, Kl, Vt);

  // scores -> u32 keys in wts region (SCALE folded)
  mfma_scores<<<dim3(Ss / 128, Ss / 128, BH), blk, 0, stream>>>(
      Qh, Ql, Kh, Kl, (unsigned*)wts);

  // exact top-512 + softmax, in place (wave-per-row)
  topk_softmax<<<dim3(BH * Ss / 4), blk, 0, stream>>>(wts);

  // PV split-K=2 -> f32 partials (aliasing dead Qh..Kl)
  pv_split<<<dim3(2, Ss / 128, BH), blk, 0, stream>>>(wts, Vt, pvp);

  // output projection with inline partial-reduce, x = M-block
  mfma_oproj<<<dim3(MROWS / 128, Dd / 128), blk, 0, stream>>>(
      pvp, pvp + (size_t)MROWS * Dd, WoT, bo, outp);
}

// Round 13
// 416.198 us; speedup vs baseline: 1.5546x; 1.0484x over previous
//
#include <hip/hip_runtime.h>
#include <hip/hip_bf16.h>
#include <math.h>

namespace {

constexpr int Bb   = 2;
constexpr int Ss   = 2048;
constexpr int Dd   = 1024;
constexpr int Hh   = 8;
constexpr int DKk  = 128;
constexpr int KTOP = 512;
constexpr int BH    = Bb * Hh;   // 16
constexpr int MROWS = Bb * Ss;   // 4096
constexpr float SCALE = 0.08838834764831845f;  // 1/sqrt(128)

typedef __attribute__((ext_vector_type(8))) short short8t;  // 8 bf16 = 16 B
typedef __attribute__((ext_vector_type(4))) short short4t;  // 4 bf16 = 8 B
typedef __attribute__((ext_vector_type(4))) float f32x4;

__device__ inline ushort f2bf(float x) {  // f32 -> bf16 RNE
  const unsigned u = __float_as_uint(x);
  return (ushort)((u + 0x7FFFu + ((u >> 16) & 1u)) >> 16);
}
__device__ inline float bf2f(ushort h) {
  return __uint_as_float(((unsigned)h) << 16);
}
struct HL { short h, l; };
__device__ inline HL split1(float x) {
  HL r;
  const ushort hu = f2bf(x);
  r.h = (short)hu;
  r.l = (short)f2bf(x - bf2f(hu));
  return r;
}

__device__ inline unsigned key_of(float v) {
  const unsigned u = __float_as_uint(v);
  return (u & 0x80000000u) ? ~u : (u | 0x80000000u);
}
__device__ inline float key_to_float(unsigned k) {
  const unsigned u = (k & 0x80000000u) ? (k & 0x7FFFFFFFu) : ~k;
  return __uint_as_float(u);
}

// ---------------------------------------------------------------------------
// Pre-split raw inputs ONCE: z=0 query->hi/lo, z=1 key->hi/lo, z=2 value->bf16
// (hoists the 12-op/element split out of the GEMM tile loop where it was
// recomputed 16x per element)
// ---------------------------------------------------------------------------
__global__ __launch_bounds__(256) void split_inputs(
    const float* __restrict__ query, const float* __restrict__ keyi,
    const float* __restrict__ value,
    ushort* __restrict__ qsh, ushort* __restrict__ qsl,
    ushort* __restrict__ ksh, ushort* __restrict__ ksl,
    ushort* __restrict__ vsb)
{
  const int z = blockIdx.y;
  const size_t i = ((size_t)blockIdx.x * 256 + threadIdx.x) * 8;
  const float* src = (z == 0) ? query : (z == 1) ? keyi : value;
  const float4 v0 = *(const float4*)(src + i);
  const float4 v1 = *(const float4*)(src + i + 4);
  if (z < 2) {
    ushort* oh = (z == 0) ? qsh : ksh;
    ushort* ol = (z == 0) ? qsl : ksl;
    short8t h, lo;
    HL r;
    r = split1(v0.x); h[0] = r.h; lo[0] = r.l;
    r = split1(v0.y); h[1] = r.h; lo[1] = r.l;
    r = split1(v0.z); h[2] = r.h; lo[2] = r.l;
    r = split1(v0.w); h[3] = r.h; lo[3] = r.l;
    r = split1(v1.x); h[4] = r.h; lo[4] = r.l;
    r = split1(v1.y); h[5] = r.h; lo[5] = r.l;
    r = split1(v1.z); h[6] = r.h; lo[6] = r.l;
    r = split1(v1.w); h[7] = r.h; lo[7] = r.l;
    *(short8t*)(oh + i) = h;
    *(short8t*)(ol + i) = lo;
  } else {
    short8t h;
    h[0] = (short)f2bf(v0.x); h[1] = (short)f2bf(v0.y);
    h[2] = (short)f2bf(v0.z); h[3] = (short)f2bf(v0.w);
    h[4] = (short)f2bf(v1.x); h[5] = (short)f2bf(v1.y);
    h[6] = (short)f2bf(v1.z); h[7] = (short)f2bf(v1.w);
    *(short8t*)(vsb + i) = h;
  }
}

// ---------------------------------------------------------------------------
// Batched Q/K/V projection, split-bf16 MFMA NT, v3: stages PRE-SPLIT inputs
// (pure short8 loads, no per-tile split VALU). 128x64 tile, x = M-block.
// z: 0=Q, 1=K (3-term, out hi/lo [bh][s][dk]); 2=V (1-term, out Vt).
// ---------------------------------------------------------------------------
__global__ __launch_bounds__(256) void mfma_proj(
    const ushort* __restrict__ qsh, const ushort* __restrict__ qsl,
    const ushort* __restrict__ ksh, const ushort* __restrict__ ksl,
    const ushort* __restrict__ vsb,
    const ushort* __restrict__ WqTh, const ushort* __restrict__ WqTl,
    const ushort* __restrict__ WkTh, const ushort* __restrict__ WkTl,
    const ushort* __restrict__ WvT,
    const float* __restrict__ bq, const float* __restrict__ bk,
    const float* __restrict__ bv,
    ushort* __restrict__ Qh, ushort* __restrict__ Ql,
    ushort* __restrict__ Kh, ushort* __restrict__ Kl,
    ushort* __restrict__ Vt)
{
  __shared__ ushort AhS[128 * 32];  // 8 KB
  __shared__ ushort AlS[128 * 32];  // 8 KB
  __shared__ ushort BhS[64 * 32];   // 4 KB
  __shared__ ushort BlS[64 * 32];   // 4 KB
  const int t  = threadIdx.x;
  const int z  = blockIdx.z;
  const int m0 = blockIdx.x * 128;  // x = M-block: A-panel XCD locality
  const int n0 = blockIdx.y * 64;
  const int l  = t & 63, wv = t >> 6;
  const int wr = wv >> 1, wc = wv & 1;   // wave owns 64x32 quadrant
  const int lrow = l & 15, lhi = l >> 4;

  const ushort* Ah_g = (z == 0) ? qsh : (z == 1) ? ksh : vsb;
  const ushort* Al_g = (z == 0) ? qsl : (z == 1) ? ksl : nullptr;
  const ushort* Bth  = (z == 0) ? WqTh : (z == 1) ? WkTh : WvT;
  const ushort* Btl  = (z == 0) ? WqTl : (z == 1) ? WkTl : nullptr;
  const float*  bias = (z == 0) ? bq   : (z == 1) ? bk   : bv;
  const bool    splitTerms = (z < 2);

  f32x4 acc[4][2] = {};

  for (int kt = 0; kt < Dd; kt += 32) {
    // A staging (128 rows x 32 k), pure loads
#pragma unroll
    for (int p = 0; p < 2; ++p) {
      const int li = p * 256 + t, row = li >> 2, g = li & 3;
      const int sw = row * 32 + ((g ^ (row & 3)) << 3);
      const size_t ao = (size_t)(m0 + row) * Dd + kt + g * 8;
      *(short8t*)&AhS[sw] = *(const short8t*)(Ah_g + ao);
      if (splitTerms) *(short8t*)&AlS[sw] = *(const short8t*)(Al_g + ao);
    }
    // B staging (64 rows x 32 k)
    {
      const int row = t >> 2, g = t & 3;
      const int sw = row * 32 + ((g ^ (row & 3)) << 3);
      const size_t off = (size_t)(n0 + row) * Dd + kt + g * 8;
      *(short8t*)&BhS[sw] = *(const short8t*)(Bth + off);
      if (splitTerms) *(short8t*)&BlS[sw] = *(const short8t*)(Btl + off);
    }
    __syncthreads();

    short8t ah[4], al[4], bh[2], bl[2];
#pragma unroll
    for (int i = 0; i < 4; ++i) {
      const int row = wr * 64 + i * 16 + lrow;
      const int idx = row * 32 + ((lhi ^ (row & 3)) << 3);
      ah[i] = *(const short8t*)&AhS[idx];
      if (splitTerms) al[i] = *(const short8t*)&AlS[idx];
    }
#pragma unroll
    for (int j = 0; j < 2; ++j) {
      const int row = wc * 32 + j * 16 + lrow;
      const int idx = row * 32 + ((lhi ^ (row & 3)) << 3);
      bh[j] = *(const short8t*)&BhS[idx];
      if (splitTerms) bl[j] = *(const short8t*)&BlS[idx];
    }
#pragma unroll
    for (int i = 0; i < 4; ++i)
#pragma unroll
      for (int j = 0; j < 2; ++j) {
        acc[i][j] = __builtin_amdgcn_mfma_f32_16x16x32_bf16(ah[i], bh[j], acc[i][j], 0, 0, 0);
        if (splitTerms) {
          acc[i][j] = __builtin_amdgcn_mfma_f32_16x16x32_bf16(ah[i], bl[j], acc[i][j], 0, 0, 0);
          acc[i][j] = __builtin_amdgcn_mfma_f32_16x16x32_bf16(al[i], bh[j], acc[i][j], 0, 0, 0);
        }
      }
    __syncthreads();
  }

#pragma unroll
  for (int i = 0; i < 4; ++i) {
#pragma unroll
    for (int j = 0; j < 2; ++j) {
      const int nn = n0 + wc * 32 + j * 16 + lrow;
#pragma unroll
      for (int r = 0; r < 4; ++r) {
        const int mm = m0 + wr * 64 + i * 16 + lhi * 4 + r;
        const float v = acc[i][j][r] + bias[nn];
        const int bb = mm >> 11, s = mm & (Ss - 1);
        const int hh = nn >> 7,  dk = nn & (DKk - 1);
        if (z < 2) {
          const size_t o = (((size_t)(bb * Hh + hh)) * Ss + s) * DKk + dk;
          const HL rr = split1(v);
          if (z == 0) { Qh[o] = (ushort)rr.h; Ql[o] = (ushort)rr.l; }
          else        { Kh[o] = (ushort)rr.h; Kl[o] = (ushort)rr.l; }
        } else {
          Vt[((size_t)((bb * Hh + hh) * DKk + dk)) * Ss + s] = f2bf(v);
        }
      }
    }
  }
}

// ---------------------------------------------------------------------------
// Scores from pre-split Q,K; epilogue writes order-flipped u32 keys (SCALE in)
// ---------------------------------------------------------------------------
__global__ __launch_bounds__(256) void mfma_scores(
    const ushort* __restrict__ Qh, const ushort* __restrict__ Ql,
    const ushort* __restrict__ Kh, const ushort* __restrict__ Kl,
    unsigned* __restrict__ wtsOut)
{
  __shared__ ushort Ah[128 * 32];
  __shared__ ushort Al[128 * 32];
  __shared__ ushort Bh[128 * 32];
  __shared__ ushort Bl[128 * 32];
  const int t  = threadIdx.x;
  const int z  = blockIdx.z;
  const int n0 = blockIdx.x * 128;   // j
  const int m0 = blockIdx.y * 128;   // q
  const int l  = t & 63, wv = t >> 6;
  const int wr = wv >> 1, wc = wv & 1;
  const int lrow = l & 15, lhi = l >> 4;
  const size_t boff = (size_t)z * Ss * DKk;

  f32x4 acc[4][4] = {};

  for (int kt = 0; kt < DKk; kt += 32) {
#pragma unroll
    for (int p = 0; p < 2; ++p) {
      const int li = p * 256 + t, row = li >> 2, g = li & 3;
      const int sw = row * 32 + ((g ^ (row & 3)) << 3);
      const size_t ao = boff + (size_t)(m0 + row) * DKk + kt + g * 8;
      *(short8t*)&Ah[sw] = *(const short8t*)(Qh + ao);
      *(short8t*)&Al[sw] = *(const short8t*)(Ql + ao);
      const size_t bo = boff + (size_t)(n0 + row) * DKk + kt + g * 8;
      *(short8t*)&Bh[sw] = *(const short8t*)(Kh + bo);
      *(short8t*)&Bl[sw] = *(const short8t*)(Kl + bo);
    }
    __syncthreads();

    short8t ah[4], al[4], bh[4], bl[4];
#pragma unroll
    for (int i = 0; i < 4; ++i) {
      const int row = wr * 64 + i * 16 + lrow;
      const int idx = row * 32 + ((lhi ^ (row & 3)) << 3);
      ah[i] = *(const short8t*)&Ah[idx];
      al[i] = *(const short8t*)&Al[idx];
    }
#pragma unroll
    for (int j = 0; j < 4; ++j) {
      const int row = wc * 64 + j * 16 + lrow;
      const int idx = row * 32 + ((lhi ^ (row & 3)) << 3);
      bh[j] = *(const short8t*)&Bh[idx];
      bl[j] = *(const short8t*)&Bl[idx];
    }
#pragma unroll
    for (int i = 0; i < 4; ++i)
#pragma unroll
      for (int j = 0; j < 4; ++j) {
        acc[i][j] = __builtin_amdgcn_mfma_f32_16x16x32_bf16(ah[i], bh[j], acc[i][j], 0, 0, 0);
        acc[i][j] = __builtin_amdgcn_mfma_f32_16x16x32_bf16(ah[i], bl[j], acc[i][j], 0, 0, 0);
        acc[i][j] = __builtin_amdgcn_mfma_f32_16x16x32_bf16(al[i], bh[j], acc[i][j], 0, 0, 0);
      }
    __syncthreads();
  }

#pragma unroll
  for (int i = 0; i < 4; ++i)
#pragma unroll
    for (int j = 0; j < 4; ++j) {
      const int nn = n0 + wc * 64 + j * 16 + lrow;
#pragma unroll
      for (int r = 0; r < 4; ++r) {
        const int mm = m0 + wr * 64 + i * 16 + lhi * 4 + r;
        wtsOut[(size_t)z * Ss * Ss + (size_t)mm * Ss + nn] =
            key_of(acc[i][j][r] * SCALE);
      }
    }
}

// ---------------------------------------------------------------------------
// o_proj with inline pv-partial reduce; grid x = M-block (A-panel locality)
// ---------------------------------------------------------------------------
__global__ __launch_bounds__(256) void mfma_oproj(
    const float* __restrict__ pv0, const float* __restrict__ pv1,
    const ushort* __restrict__ Bt,
    const float* __restrict__ bias, float* __restrict__ Cout)
{
  __shared__ ushort As[128 * 64];
  __shared__ ushort Bs[128 * 64];
  const int t  = threadIdx.x;
  const int m0 = blockIdx.x * 128;
  const int n0 = blockIdx.y * 128;
  const int l  = t & 63, wv = t >> 6;
  const int wr = wv >> 1, wc = wv & 1;
  const int lrow = l & 15, lhi = l >> 4;

  f32x4 acc[4][4] = {};

  for (int kt = 0; kt < Dd; kt += 64) {
#pragma unroll
    for (int p = 0; p < 4; ++p) {
      const int li = p * 256 + t, row = li >> 3, g = li & 7;
      const int sw = row * 64 + ((g ^ (row & 7)) << 3);
      const size_t ao = (size_t)(m0 + row) * Dd + kt + g * 8;
      const float4 a0 = *(const float4*)(pv0 + ao);
      const float4 a1 = *(const float4*)(pv0 + ao + 4);
      const float4 c0 = *(const float4*)(pv1 + ao);
      const float4 c1 = *(const float4*)(pv1 + ao + 4);
      short8t sa;
      sa[0] = (short)f2bf(a0.x + c0.x); sa[1] = (short)f2bf(a0.y + c0.y);
      sa[2] = (short)f2bf(a0.z + c0.z); sa[3] = (short)f2bf(a0.w + c0.w);
      sa[4] = (short)f2bf(a1.x + c1.x); sa[5] = (short)f2bf(a1.y + c1.y);
      sa[6] = (short)f2bf(a1.z + c1.z); sa[7] = (short)f2bf(a1.w + c1.w);
      *(short8t*)&As[sw] = sa;
      *(short8t*)&Bs[sw] = *(const short8t*)(Bt + (size_t)(n0 + row) * Dd + kt + g * 8);
    }
    __syncthreads();

#pragma unroll
    for (int kk = 0; kk < 2; ++kk) {
      short8t a[4], b[4];
      const int g = kk * 4 + lhi;
#pragma unroll
      for (int i = 0; i < 4; ++i) {
        const int row = wr * 64 + i * 16 + lrow;
        a[i] = *(const short8t*)&As[row * 64 + ((g ^ (row & 7)) << 3)];
      }
#pragma unroll
      for (int j = 0; j < 4; ++j) {
        const int row = wc * 64 + j * 16 + lrow;
        b[j] = *(const short8t*)&Bs[row * 64 + ((g ^ (row & 7)) << 3)];
      }
#pragma unroll
      for (int i = 0; i < 4; ++i)
#pragma unroll
        for (int j = 0; j < 4; ++j)
          acc[i][j] = __builtin_amdgcn_mfma_f32_16x16x32_bf16(a[i], b[j], acc[i][j], 0, 0, 0);
    }
    __syncthreads();
  }

#pragma unroll
  for (int i = 0; i < 4; ++i)
#pragma unroll
    for (int j = 0; j < 4; ++j) {
      const int nn = n0 + wc * 64 + j * 16 + lrow;
#pragma unroll
      for (int r = 0; r < 4; ++r) {
        const int mm = m0 + wr * 64 + i * 16 + lhi * 4 + r;
        Cout[(size_t)mm * Dd + nn] = acc[i][j][r] + bias[nn];
      }
    }
}

// ---------------------------------------------------------------------------
// PV with split-K=2: grid (2, S/128, BH); f32 partials -> pvp[ks][B,S,D]
// ---------------------------------------------------------------------------
__global__ __launch_bounds__(256) void pv_split(
    const float* __restrict__ Wts, const ushort* __restrict__ VtAll,
    float* __restrict__ pvp)
{
  __shared__ ushort As[128 * 64];
  __shared__ ushort Bs[128 * 64];
  const int t  = threadIdx.x;
  const int ks = blockIdx.x;
  const int m0 = blockIdx.y * 128;
  const int z  = blockIdx.z;
  const int l  = t & 63, wv = t >> 6;
  const int wr = wv >> 1, wc = wv & 1;
  const int lrow = l & 15, lhi = l >> 4;

  const float*  Af = Wts + (size_t)z * Ss * Ss;
  const ushort* Bt = VtAll + (size_t)z * DKk * Ss;

  f32x4 acc[4][4] = {};

  for (int kt = ks * 1024; kt < ks * 1024 + 1024; kt += 64) {
#pragma unroll
    for (int p = 0; p < 4; ++p) {
      const int li = p * 256 + t, row = li >> 3, g = li & 7;
      const int sw = row * 64 + ((g ^ (row & 7)) << 3);
      const float* src = Af + (size_t)(m0 + row) * Ss + kt + g * 8;
      const float4 v0 = *(const float4*)src;
      const float4 v1 = *(const float4*)(src + 4);
      short8t sa;
      sa[0] = (short)f2bf(v0.x); sa[1] = (short)f2bf(v0.y);
      sa[2] = (short)f2bf(v0.z); sa[3] = (short)f2bf(v0.w);
      sa[4] = (short)f2bf(v1.x); sa[5] = (short)f2bf(v1.y);
      sa[6] = (short)f2bf(v1.z); sa[7] = (short)f2bf(v1.w);
      *(short8t*)&As[sw] = sa;
      *(short8t*)&Bs[sw] = *(const short8t*)(Bt + (size_t)row * Ss + kt + g * 8);
    }
    __syncthreads();

#pragma unroll
    for (int kk = 0; kk < 2; ++kk) {
      short8t a[4], b[4];
      const int g = kk * 4 + lhi;
#pragma unroll
      for (int i = 0; i < 4; ++i) {
        const int row = wr * 64 + i * 16 + lrow;
        a[i] = *(const short8t*)&As[row * 64 + ((g ^ (row & 7)) << 3)];
      }
#pragma unroll
      for (int j = 0; j < 4; ++j) {
        const int row = wc * 64 + j * 16 + lrow;
        b[j] = *(const short8t*)&Bs[row * 64 + ((g ^ (row & 7)) << 3)];
      }
#pragma unroll
      for (int i = 0; i < 4; ++i)
#pragma unroll
        for (int j = 0; j < 4; ++j)
          acc[i][j] = __builtin_amdgcn_mfma_f32_16x16x32_bf16(a[i], b[j], acc[i][j], 0, 0, 0);
    }
    __syncthreads();
  }

  const int bb = z >> 3, hh = z & 7;
  float* outp = pvp + (size_t)ks * MROWS * Dd;
#pragma unroll
  for (int i = 0; i < 4; ++i)
#pragma unroll
    for (int j = 0; j < 4; ++j) {
      const int nn = wc * 64 + j * 16 + lrow;
#pragma unroll
      for (int r = 0; r < 4; ++r) {
        const int mm = m0 + wr * 64 + i * 16 + lhi * 4 + r;
        outp[((size_t)(bb * Ss + mm)) * Dd + hh * DKk + nn] = acc[i][j][r];
      }
    }
}

// ---------------------------------------------------------------------------
// W[1024][1024] f32 -> Wt bf16 (transposed)
// ---------------------------------------------------------------------------
__global__ __launch_bounds__(256) void transpose_bf16(
    const float* __restrict__ W, ushort* __restrict__ Wt)
{
  __shared__ float tile[32][33];
  const int t  = threadIdx.x;
  const int c0 = blockIdx.x * 32, r0 = blockIdx.y * 32;
  const int lr = t >> 3, lc4 = (t & 7) * 4;
  const float4 v = *(const float4*)(W + (size_t)(r0 + lr) * Dd + c0 + lc4);
  tile[lr][lc4 + 0] = v.x; tile[lr][lc4 + 1] = v.y;
  tile[lr][lc4 + 2] = v.z; tile[lr][lc4 + 3] = v.w;
  __syncthreads();
  const int oc = t >> 3, or4 = (t & 7) * 4;
  short4t o;
  o[0] = (short)f2bf(tile[or4 + 0][oc]);
  o[1] = (short)f2bf(tile[or4 + 1][oc]);
  o[2] = (short)f2bf(tile[or4 + 2][oc]);
  o[3] = (short)f2bf(tile[or4 + 3][oc]);
  *(short4t*)(Wt + (size_t)(c0 + oc) * Dd + r0 + or4) = o;
}

// ---------------------------------------------------------------------------
// W[1024][1024] f32 -> transposed hi/lo bf16 split
// ---------------------------------------------------------------------------
__global__ __launch_bounds__(256) void transpose_split(
    const float* __restrict__ W, ushort* __restrict__ Th, ushort* __restrict__ Tl)
{
  __shared__ float tile[32][33];
  const int t  = threadIdx.x;
  const int c0 = blockIdx.x * 32, r0 = blockIdx.y * 32;
  const int lr = t >> 3, lc4 = (t & 7) * 4;
  const float4 v = *(const float4*)(W + (size_t)(r0 + lr) * Dd + c0 + lc4);
  tile[lr][lc4 + 0] = v.x; tile[lr][lc4 + 1] = v.y;
  tile[lr][lc4 + 2] = v.z; tile[lr][lc4 + 3] = v.w;
  __syncthreads();
  const int oc = t >> 3, or4 = (t & 7) * 4;
  short4t oh, ol;
  HL r;
  r = split1(tile[or4 + 0][oc]); oh[0] = r.h; ol[0] = r.l;
  r = split1(tile[or4 + 1][oc]); oh[1] = r.h; ol[1] = r.l;
  r = split1(tile[or4 + 2][oc]); oh[2] = r.h; ol[2] = r.l;
  r = split1(tile[or4 + 3][oc]); oh[3] = r.h; ol[3] = r.l;
  *(short4t*)(Th + (size_t)(c0 + oc) * Dd + r0 + or4) = oh;
  *(short4t*)(Tl + (size_t)(c0 + oc) * Dd + r0 + or4) = ol;
}

// ---------------------------------------------------------------------------
// Per-row exact top-512 + softmax, v6: wave-per-row, zero __syncthreads.
// ---------------------------------------------------------------------------
__global__ __launch_bounds__(256) void topk_softmax(float* __restrict__ wts)
{
  __shared__ unsigned histAll[4][1088];

  const int lane = threadIdx.x & 63;
  const int wv   = threadIdx.x >> 6;
  const int row  = blockIdx.x * 4 + wv;
  float* rowp = wts + (size_t)row * Ss;
  unsigned* rowu = (unsigned*)rowp;
  unsigned* h = histAll[wv];

  unsigned k[32];
  unsigned lmax = 0u;
#pragma unroll
  for (int i = 0; i < 8; ++i) {
    const uint4 v = *(const uint4*)(rowu + i * 256 + lane * 4);
    k[i * 4 + 0] = v.x; k[i * 4 + 1] = v.y;
    k[i * 4 + 2] = v.z; k[i * 4 + 3] = v.w;
    lmax = max(max(lmax, max(v.x, v.y)), max(v.z, v.w));
  }
#pragma unroll
  for (int off = 32; off > 0; off >>= 1) lmax = max(lmax, __shfl_xor(lmax, off));
  const float m = key_to_float(lmax);

  unsigned needK = KTOP, tieC = 0u, prefix = 0u;

  // pass 1: bits [31:22], 1024 bins
  {
#pragma unroll
    for (int i = 0; i < 17; ++i) h[lane + i * 64] = 0u;
#pragma unroll
    for (int i = 0; i < 32; ++i) {
      const unsigned b = k[i] >> 22;
      atomicAdd(&h[b + (b >> 4)], 1u);
    }
    unsigned b[16], lsum = 0u;
#pragma unroll
    for (int i = 0; i < 16; ++i) { b[i] = h[lane * 17 + i]; lsum += b[i]; }
    unsigned s = lsum;
#pragma unroll
    for (int off = 1; off < 64; off <<= 1) {
      const unsigned v = __shfl_down(s, off);
      if (lane + off < 64) s += v;
    }
    unsigned run = s - lsum;
    unsigned fb = 0u, fn = 0u, ft = 0u;
    bool found = false;
#pragma unroll
    for (int i = 15; i >= 0; --i) {
      const unsigned c = b[i];
      if (!found && c > 0u && run < needK && run + c >= needK) {
        found = true; fb = (unsigned)(lane * 16 + i); fn = needK - run; ft = c;
      }
      run += c;
    }
    const unsigned long long msk = __ballot(found);
    const int src = (int)__ffsll(msk) - 1;
    prefix = __shfl(fb, src) << 22;
    needK  = __shfl(fn, src);
    tieC   = __shfl(ft, src);
  }

  // passes 2,3: 8-bit refinements (bits [21:14], [13:6])
#pragma unroll
  for (int pass = 0; pass < 2; ++pass) {
    const int sh = (pass == 0) ? 14 : 6;
    const int ph = sh + 8;
#pragma unroll
    for (int i = 0; i < 5; ++i) h[lane + i * 64] = 0u;
    const unsigned pcmp = prefix >> ph;
#pragma unroll
    for (int i = 0; i < 32; ++i) {
      if ((k[i] >> ph) == pcmp) {
        const unsigned b = (k[i] >> sh) & 255u;
        atomicAdd(&h[b + (b >> 4)], 1u);
      }
    }
    unsigned b4[4], lsum = 0u;
#pragma unroll
    for (int i = 0; i < 4; ++i) {
      const unsigned x = (unsigned)(lane * 4 + i);
      b4[i] = h[x + (x >> 4)];
      lsum += b4[i];
    }
    unsigned s = lsum;
#pragma unroll
    for (int off = 1; off < 64; off <<= 1) {
      const unsigned v = __shfl_down(s, off);
      if (lane + off < 64) s += v;
    }
    unsigned run = s - lsum;
    unsigned fb = 0u, fn = 0u, ft = 0u;
    bool found = false;
#pragma unroll
    for (int i = 3; i >= 0; --i) {
      const unsigned c = b4[i];
      if (!found && c > 0u && run < needK && run + c >= needK) {
        found = true; fb = (unsigned)(lane * 4 + i); fn = needK - run; ft = c;
      }
      run += c;
    }
    const unsigned long long msk = __ballot(found);
    const int src = (int)__ffsll(msk) - 1;
    prefix |= __shfl(fb, src) << sh;
    needK   = __shfl(fn, src);
    tieC    = __shfl(ft, src);
  }

  // pass 4: bits [5:0]
  unsigned T;
  {
    h[lane] = 0u;
    if (lane < 4) h[64 + lane] = 0u;
    const unsigned pcmp = prefix >> 6;
#pragma unroll
    for (int i = 0; i < 32; ++i) {
      if ((k[i] >> 6) == pcmp) {
        const unsigned b = k[i] & 63u;
        atomicAdd(&h[b + (b >> 4)], 1u);
      }
    }
    const unsigned b0 = h[lane + (lane >> 4)];
    unsigned s = b0;
#pragma unroll
    for (int off = 1; off < 64; off <<= 1) {
      const unsigned v = __shfl_down(s, off);
      if (lane + off < 64) s += v;
    }
    const unsigned run = s - b0;
    const bool found = (b0 > 0u && run < needK && run + b0 >= needK);
    const unsigned long long msk = __ballot(found);
    const int src = (int)__ffsll(msk) - 1;
    T     = prefix | (unsigned)__shfl((unsigned)lane, src);
    needK = __shfl(needK - run, src);
    tieC  = __shfl(b0, src);
  }

  if (tieC != needK) {
    unsigned R = 0u;
#pragma unroll
    for (int i = 0; i < 8; ++i) {
      unsigned myEq = 0u;
#pragma unroll
      for (int c = 0; c < 4; ++c) myEq += (k[i * 4 + c] == T);
      unsigned ps = myEq;
#pragma unroll
      for (int off = 1; off < 64; off <<= 1) {
        const unsigned v = __shfl_up(ps, off);
        if (lane >= off) ps += v;
      }
      unsigned before = R + ps - myEq;
#pragma unroll
      for (int c = 0; c < 4; ++c) {
        if (k[i * 4 + c] == T) {
          if (before >= needK) k[i * 4 + c] = 0u;
          ++before;
        }
      }
      R += __shfl(ps, 63);
    }
  }

  float lz = 0.f;
#pragma unroll
  for (int i = 0; i < 32; ++i) {
    const unsigned kk = k[i];
    const float w = (kk >= T) ? __expf(key_to_float(kk) - m) : 0.f;
    k[i] = __float_as_uint(w);
    lz += w;
  }
#pragma unroll
  for (int off = 32; off > 0; off >>= 1) lz += __shfl_xor(lz, off);
  const float Zi = 1.0f / lz;

#pragma unroll
  for (int i = 0; i < 8; ++i) {
    float4 o;
    o.x = __uint_as_float(k[i * 4 + 0]) * Zi;
    o.y = __uint_as_float(k[i * 4 + 1]) * Zi;
    o.z = __uint_as_float(k[i * 4 + 2]) * Zi;
    o.w = __uint_as_float(k[i * 4 + 3]) * Zi;
    *(float4*)(rowu + i * 256 + lane * 4) = o;
  }
}

}  // namespace

extern "C" void kernel_launch(void* const* d_in, const int* in_sizes, int n_in,
                              void* d_out_v, int out_size, void* d_ws, size_t ws_size,
                              hipStream_t stream)
{
  const float* query = (const float*)d_in[0];
  const float* key   = (const float*)d_in[1];
  const float* value = (const float*)d_in[2];
  const float* Wq = (const float*)d_in[3];  const float* bq = (const float*)d_in[4];
  const float* Wk = (const float*)d_in[5];  const float* bk = (const float*)d_in[6];
  const float* Wv = (const float*)d_in[7];  const float* bv = (const float*)d_in[8];
  const float* Wo = (const float*)d_in[9];  const float* bo = (const float*)d_in[10];

  float* d_out = (float*)d_out_v;
  float* outp  = d_out;                              // [B,S,D] f32
  float* wts   = d_out + (size_t)Bb * Ss * Dd;       // [B,H,S,S] f32

  const size_t PROJ = (size_t)MROWS * Dd;            // 4M elements
  const size_t DD2  = (size_t)Dd * Dd;               // 1M elements

  ushort* ws    = (ushort*)d_ws;
  ushort* Qh    = ws;                                // 8 MB each
  ushort* Ql    = Qh + PROJ;
  ushort* Kh    = Ql + PROJ;
  ushort* Kl    = Kh + PROJ;                         // ends at 32 MB
  ushort* wreg  = Kl + PROJ;
  ushort* WqTh  = wreg;                              // 4 x 2 MB splits
  ushort* WqTl  = wreg + DD2;
  ushort* WkTh  = wreg + 2 * DD2;
  ushort* WkTl  = wreg + 3 * DD2;
  ushort* WvT   = wreg + 4 * DD2;                    // 2 MB
  ushort* WoT   = wreg + 5 * DD2;                    // 2 MB
  ushort* Vt    = wreg + 6 * DD2;                    // bf16 V^T [16][128][2048] 8 MB
  float*  pvp   = (float*)Qh;                        // pv partials alias Qh..Kl (32 MB)

  // pre-split raw inputs live in the (not-yet-written) wts region of d_out:
  // 40 MB << 268 MB; dead once mfma_scores overwrites wts (stream-ordered).
  ushort* qsh = (ushort*)wts;
  ushort* qsl = qsh + PROJ;
  ushort* ksh = qsh + 2 * PROJ;
  ushort* ksl = qsh + 3 * PROJ;
  ushort* vsb = qsh + 4 * PROJ;

  const dim3 blk(256);

  // weight prep
  transpose_split<<<dim3(32, 32), blk, 0, stream>>>(Wq, WqTh, WqTl);
  transpose_split<<<dim3(32, 32), blk, 0, stream>>>(Wk, WkTh, WkTl);
  transpose_bf16<<<dim3(32, 32), blk, 0, stream>>>(Wv, WvT);
  transpose_bf16<<<dim3(32, 32), blk, 0, stream>>>(Wo, WoT);

  // pre-split inputs (once, elementwise)
  split_inputs<<<dim3((int)(PROJ / 2048), 3), blk, 0, stream>>>(
      query, key, value, qsh, qsl, ksh, ksl, vsb);

  // Q/K/V projections, batched, 128x64 tile, x = M-block (XCD-local A)
  mfma_proj<<<dim3(MROWS / 128, Dd / 64, 3), blk, 0, stream>>>(
      qsh, qsl, ksh, ksl, vsb, WqTh, WqTl, WkTh, WkTl, WvT,
      bq, bk, bv, Qh, Ql, Kh, Kl, Vt);

  // scores -> u32 keys in wts region (SCALE folded)
  mfma_scores<<<dim3(Ss / 128, Ss / 128, BH), blk, 0, stream>>>(
      Qh, Ql, Kh, Kl, (unsigned*)wts);

  // exact top-512 + softmax, in place (wave-per-row)
  topk_softmax<<<dim3(BH * Ss / 4), blk, 0, stream>>>(wts);

  // PV split-K=2 -> f32 partials (aliasing dead Qh..Kl)
  pv_split<<<dim3(2, Ss / 128, BH), blk, 0, stream>>>(wts, Vt, pvp);

  // output projection with inline partial-reduce, x = M-block
  mfma_oproj<<<dim3(MROWS / 128, Dd / 128), blk, 0, stream>>>(
      pvp, pvp + (size_t)MROWS * Dd, WoT, bo, outp);
}

// Round 14
// 392.113 us; speedup vs baseline: 1.6501x; 1.0614x over previous
//
#include <hip/hip_runtime.h>
#include <hip/hip_bf16.h>
#include <math.h>

namespace {

constexpr int Bb   = 2;
constexpr int Ss   = 2048;
constexpr int Dd   = 1024;
constexpr int Hh   = 8;
constexpr int DKk  = 128;
constexpr int KTOP = 512;
constexpr int BH    = Bb * Hh;   // 16
constexpr int MROWS = Bb * Ss;   // 4096
constexpr float SCALE = 0.08838834764831845f;  // 1/sqrt(128)

typedef __attribute__((ext_vector_type(8))) short short8t;  // 8 bf16 = 16 B
typedef __attribute__((ext_vector_type(4))) short short4t;  // 4 bf16 = 8 B
typedef __attribute__((ext_vector_type(4))) float f32x4;

__device__ inline ushort f2bf(float x) {  // f32 -> bf16 RNE
  const unsigned u = __float_as_uint(x);
  return (ushort)((u + 0x7FFFu + ((u >> 16) & 1u)) >> 16);
}
__device__ inline float bf2f(ushort h) {
  return __uint_as_float(((unsigned)h) << 16);
}
struct HL { short h, l; };
__device__ inline HL split1(float x) {
  HL r;
  const ushort hu = f2bf(x);
  r.h = (short)hu;
  r.l = (short)f2bf(x - bf2f(hu));
  return r;
}

__device__ inline unsigned key_of(float v) {
  const unsigned u = __float_as_uint(v);
  return (u & 0x80000000u) ? ~u : (u | 0x80000000u);
}
__device__ inline float key_to_float(unsigned k) {
  const unsigned u = (k & 0x80000000u) ? (k & 0x7FFFFFFFu) : ~k;
  return __uint_as_float(u);
}

// ---------------------------------------------------------------------------
// Pre-split raw inputs ONCE: z=0 query->hi/lo, z=1 key->hi/lo, z=2 value->bf16
// ---------------------------------------------------------------------------
__global__ __launch_bounds__(256) void split_inputs(
    const float* __restrict__ query, const float* __restrict__ keyi,
    const float* __restrict__ value,
    ushort* __restrict__ qsh, ushort* __restrict__ qsl,
    ushort* __restrict__ ksh, ushort* __restrict__ ksl,
    ushort* __restrict__ vsb)
{
  const int z = blockIdx.y;
  const size_t i = ((size_t)blockIdx.x * 256 + threadIdx.x) * 8;
  const float* src = (z == 0) ? query : (z == 1) ? keyi : value;
  const float4 v0 = *(const float4*)(src + i);
  const float4 v1 = *(const float4*)(src + i + 4);
  if (z < 2) {
    ushort* oh = (z == 0) ? qsh : ksh;
    ushort* ol = (z == 0) ? qsl : ksl;
    short8t h, lo;
    HL r;
    r = split1(v0.x); h[0] = r.h; lo[0] = r.l;
    r = split1(v0.y); h[1] = r.h; lo[1] = r.l;
    r = split1(v0.z); h[2] = r.h; lo[2] = r.l;
    r = split1(v0.w); h[3] = r.h; lo[3] = r.l;
    r = split1(v1.x); h[4] = r.h; lo[4] = r.l;
    r = split1(v1.y); h[5] = r.h; lo[5] = r.l;
    r = split1(v1.z); h[6] = r.h; lo[6] = r.l;
    r = split1(v1.w); h[7] = r.h; lo[7] = r.l;
    *(short8t*)(oh + i) = h;
    *(short8t*)(ol + i) = lo;
  } else {
    short8t h;
    h[0] = (short)f2bf(v0.x); h[1] = (short)f2bf(v0.y);
    h[2] = (short)f2bf(v0.z); h[3] = (short)f2bf(v0.w);
    h[4] = (short)f2bf(v1.x); h[5] = (short)f2bf(v1.y);
    h[6] = (short)f2bf(v1.z); h[7] = (short)f2bf(v1.w);
    *(short8t*)(vsb + i) = h;
  }
}

// ---------------------------------------------------------------------------
// Batched Q/K/V projection, v4: 128x128 tile / BK=32 / 4 waves — the exact
// structure of mfma_scores (794 TF effective there). Stages pre-split inputs.
// z: 0=Q, 1=K (3-term, out hi/lo [bh][s][dk]); 2=V (1-term, out Vt).
// ---------------------------------------------------------------------------
__global__ __launch_bounds__(256) void mfma_proj(
    const ushort* __restrict__ qsh, const ushort* __restrict__ qsl,
    const ushort* __restrict__ ksh, const ushort* __restrict__ ksl,
    const ushort* __restrict__ vsb,
    const ushort* __restrict__ WqTh, const ushort* __restrict__ WqTl,
    const ushort* __restrict__ WkTh, const ushort* __restrict__ WkTl,
    const ushort* __restrict__ WvT,
    const float* __restrict__ bq, const float* __restrict__ bk,
    const float* __restrict__ bv,
    ushort* __restrict__ Qh, ushort* __restrict__ Ql,
    ushort* __restrict__ Kh, ushort* __restrict__ Kl,
    ushort* __restrict__ Vt)
{
  __shared__ ushort Ah[128 * 32];
  __shared__ ushort Al[128 * 32];
  __shared__ ushort Bh[128 * 32];
  __shared__ ushort Bl[128 * 32];
  const int t  = threadIdx.x;
  const int z  = blockIdx.z;
  const int m0 = blockIdx.x * 128;  // m fastest -> per-XCD A-panel locality
  const int n0 = blockIdx.y * 128;
  const int l  = t & 63, wv = t >> 6;
  const int wr = wv >> 1, wc = wv & 1;
  const int lrow = l & 15, lhi = l >> 4;

  const ushort* Ah_g = (z == 0) ? qsh : (z == 1) ? ksh : vsb;
  const ushort* Al_g = (z == 0) ? qsl : (z == 1) ? ksl : nullptr;
  const ushort* Bth  = (z == 0) ? WqTh : (z == 1) ? WkTh : WvT;
  const ushort* Btl  = (z == 0) ? WqTl : (z == 1) ? WkTl : nullptr;
  const float*  bias = (z == 0) ? bq   : (z == 1) ? bk   : bv;
  const bool    splitTerms = (z < 2);

  f32x4 acc[4][4] = {};

  for (int kt = 0; kt < Dd; kt += 32) {
#pragma unroll
    for (int p = 0; p < 2; ++p) {
      const int li = p * 256 + t, row = li >> 2, g = li & 3;
      const int sw = row * 32 + ((g ^ (row & 3)) << 3);
      const size_t ao = (size_t)(m0 + row) * Dd + kt + g * 8;
      *(short8t*)&Ah[sw] = *(const short8t*)(Ah_g + ao);
      if (splitTerms) *(short8t*)&Al[sw] = *(const short8t*)(Al_g + ao);
      const size_t bo = (size_t)(n0 + row) * Dd + kt + g * 8;
      *(short8t*)&Bh[sw] = *(const short8t*)(Bth + bo);
      if (splitTerms) *(short8t*)&Bl[sw] = *(const short8t*)(Btl + bo);
    }
    __syncthreads();

    short8t ah[4], al[4], bh[4], bl[4];
#pragma unroll
    for (int i = 0; i < 4; ++i) {
      const int row = wr * 64 + i * 16 + lrow;
      const int idx = row * 32 + ((lhi ^ (row & 3)) << 3);
      ah[i] = *(const short8t*)&Ah[idx];
      if (splitTerms) al[i] = *(const short8t*)&Al[idx];
    }
#pragma unroll
    for (int j = 0; j < 4; ++j) {
      const int row = wc * 64 + j * 16 + lrow;
      const int idx = row * 32 + ((lhi ^ (row & 3)) << 3);
      bh[j] = *(const short8t*)&Bh[idx];
      if (splitTerms) bl[j] = *(const short8t*)&Bl[idx];
    }
#pragma unroll
    for (int i = 0; i < 4; ++i)
#pragma unroll
      for (int j = 0; j < 4; ++j) {
        acc[i][j] = __builtin_amdgcn_mfma_f32_16x16x32_bf16(ah[i], bh[j], acc[i][j], 0, 0, 0);
        if (splitTerms) {
          acc[i][j] = __builtin_amdgcn_mfma_f32_16x16x32_bf16(ah[i], bl[j], acc[i][j], 0, 0, 0);
          acc[i][j] = __builtin_amdgcn_mfma_f32_16x16x32_bf16(al[i], bh[j], acc[i][j], 0, 0, 0);
        }
      }
    __syncthreads();
  }

#pragma unroll
  for (int i = 0; i < 4; ++i) {
#pragma unroll
    for (int j = 0; j < 4; ++j) {
      const int nn = n0 + wc * 64 + j * 16 + lrow;
#pragma unroll
      for (int r = 0; r < 4; ++r) {
        const int mm = m0 + wr * 64 + i * 16 + lhi * 4 + r;
        const float v = acc[i][j][r] + bias[nn];
        const int bb = mm >> 11, s = mm & (Ss - 1);
        const int hh = nn >> 7,  dk = nn & (DKk - 1);
        if (z < 2) {
          const size_t o = (((size_t)(bb * Hh + hh)) * Ss + s) * DKk + dk;
          const HL rr = split1(v);
          if (z == 0) { Qh[o] = (ushort)rr.h; Ql[o] = (ushort)rr.l; }
          else        { Kh[o] = (ushort)rr.h; Kl[o] = (ushort)rr.l; }
        } else {
          Vt[((size_t)((bb * Hh + hh) * DKk + dk)) * Ss + s] = f2bf(v);
        }
      }
    }
  }
}

// ---------------------------------------------------------------------------
// Scores from pre-split Q,K; epilogue writes order-flipped u32 keys (SCALE in)
// ---------------------------------------------------------------------------
__global__ __launch_bounds__(256) void mfma_scores(
    const ushort* __restrict__ Qh, const ushort* __restrict__ Ql,
    const ushort* __restrict__ Kh, const ushort* __restrict__ Kl,
    unsigned* __restrict__ wtsOut)
{
  __shared__ ushort Ah[128 * 32];
  __shared__ ushort Al[128 * 32];
  __shared__ ushort Bh[128 * 32];
  __shared__ ushort Bl[128 * 32];
  const int t  = threadIdx.x;
  const int z  = blockIdx.z;
  const int n0 = blockIdx.x * 128;   // j
  const int m0 = blockIdx.y * 128;   // q
  const int l  = t & 63, wv = t >> 6;
  const int wr = wv >> 1, wc = wv & 1;
  const int lrow = l & 15, lhi = l >> 4;
  const size_t boff = (size_t)z * Ss * DKk;

  f32x4 acc[4][4] = {};

  for (int kt = 0; kt < DKk; kt += 32) {
#pragma unroll
    for (int p = 0; p < 2; ++p) {
      const int li = p * 256 + t, row = li >> 2, g = li & 3;
      const int sw = row * 32 + ((g ^ (row & 3)) << 3);
      const size_t ao = boff + (size_t)(m0 + row) * DKk + kt + g * 8;
      *(short8t*)&Ah[sw] = *(const short8t*)(Qh + ao);
      *(short8t*)&Al[sw] = *(const short8t*)(Ql + ao);
      const size_t bo = boff + (size_t)(n0 + row) * DKk + kt + g * 8;
      *(short8t*)&Bh[sw] = *(const short8t*)(Kh + bo);
      *(short8t*)&Bl[sw] = *(const short8t*)(Kl + bo);
    }
    __syncthreads();

    short8t ah[4], al[4], bh[4], bl[4];
#pragma unroll
    for (int i = 0; i < 4; ++i) {
      const int row = wr * 64 + i * 16 + lrow;
      const int idx = row * 32 + ((lhi ^ (row & 3)) << 3);
      ah[i] = *(const short8t*)&Ah[idx];
      al[i] = *(const short8t*)&Al[idx];
    }
#pragma unroll
    for (int j = 0; j < 4; ++j) {
      const int row = wc * 64 + j * 16 + lrow;
      const int idx = row * 32 + ((lhi ^ (row & 3)) << 3);
      bh[j] = *(const short8t*)&Bh[idx];
      bl[j] = *(const short8t*)&Bl[idx];
    }
#pragma unroll
    for (int i = 0; i < 4; ++i)
#pragma unroll
      for (int j = 0; j < 4; ++j) {
        acc[i][j] = __builtin_amdgcn_mfma_f32_16x16x32_bf16(ah[i], bh[j], acc[i][j], 0, 0, 0);
        acc[i][j] = __builtin_amdgcn_mfma_f32_16x16x32_bf16(ah[i], bl[j], acc[i][j], 0, 0, 0);
        acc[i][j] = __builtin_amdgcn_mfma_f32_16x16x32_bf16(al[i], bh[j], acc[i][j], 0, 0, 0);
      }
    __syncthreads();
  }

#pragma unroll
  for (int i = 0; i < 4; ++i)
#pragma unroll
    for (int j = 0; j < 4; ++j) {
      const int nn = n0 + wc * 64 + j * 16 + lrow;
#pragma unroll
      for (int r = 0; r < 4; ++r) {
        const int mm = m0 + wr * 64 + i * 16 + lhi * 4 + r;
        wtsOut[(size_t)z * Ss * Ss + (size_t)mm * Ss + nn] =
            key_of(acc[i][j][r] * SCALE);
      }
    }
}

// ---------------------------------------------------------------------------
// o_proj with inline pv-partial reduce; grid x = M-block (A-panel locality)
// ---------------------------------------------------------------------------
__global__ __launch_bounds__(256) void mfma_oproj(
    const float* __restrict__ pv0, const float* __restrict__ pv1,
    const ushort* __restrict__ Bt,
    const float* __restrict__ bias, float* __restrict__ Cout)
{
  __shared__ ushort As[128 * 64];
  __shared__ ushort Bs[128 * 64];
  const int t  = threadIdx.x;
  const int m0 = blockIdx.x * 128;
  const int n0 = blockIdx.y * 128;
  const int l  = t & 63, wv = t >> 6;
  const int wr = wv >> 1, wc = wv & 1;
  const int lrow = l & 15, lhi = l >> 4;

  f32x4 acc[4][4] = {};

  for (int kt = 0; kt < Dd; kt += 64) {
#pragma unroll
    for (int p = 0; p < 4; ++p) {
      const int li = p * 256 + t, row = li >> 3, g = li & 7;
      const int sw = row * 64 + ((g ^ (row & 7)) << 3);
      const size_t ao = (size_t)(m0 + row) * Dd + kt + g * 8;
      const float4 a0 = *(const float4*)(pv0 + ao);
      const float4 a1 = *(const float4*)(pv0 + ao + 4);
      const float4 c0 = *(const float4*)(pv1 + ao);
      const float4 c1 = *(const float4*)(pv1 + ao + 4);
      short8t sa;
      sa[0] = (short)f2bf(a0.x + c0.x); sa[1] = (short)f2bf(a0.y + c0.y);
      sa[2] = (short)f2bf(a0.z + c0.z); sa[3] = (short)f2bf(a0.w + c0.w);
      sa[4] = (short)f2bf(a1.x + c1.x); sa[5] = (short)f2bf(a1.y + c1.y);
      sa[6] = (short)f2bf(a1.z + c1.z); sa[7] = (short)f2bf(a1.w + c1.w);
      *(short8t*)&As[sw] = sa;
      *(short8t*)&Bs[sw] = *(const short8t*)(Bt + (size_t)(n0 + row) * Dd + kt + g * 8);
    }
    __syncthreads();

#pragma unroll
    for (int kk = 0; kk < 2; ++kk) {
      short8t a[4], b[4];
      const int g = kk * 4 + lhi;
#pragma unroll
      for (int i = 0; i < 4; ++i) {
        const int row = wr * 64 + i * 16 + lrow;
        a[i] = *(const short8t*)&As[row * 64 + ((g ^ (row & 7)) << 3)];
      }
#pragma unroll
      for (int j = 0; j < 4; ++j) {
        const int row = wc * 64 + j * 16 + lrow;
        b[j] = *(const short8t*)&Bs[row * 64 + ((g ^ (row & 7)) << 3)];
      }
#pragma unroll
      for (int i = 0; i < 4; ++i)
#pragma unroll
        for (int j = 0; j < 4; ++j)
          acc[i][j] = __builtin_amdgcn_mfma_f32_16x16x32_bf16(a[i], b[j], acc[i][j], 0, 0, 0);
    }
    __syncthreads();
  }

#pragma unroll
  for (int i = 0; i < 4; ++i)
#pragma unroll
    for (int j = 0; j < 4; ++j) {
      const int nn = n0 + wc * 64 + j * 16 + lrow;
#pragma unroll
      for (int r = 0; r < 4; ++r) {
        const int mm = m0 + wr * 64 + i * 16 + lhi * 4 + r;
        Cout[(size_t)mm * Dd + nn] = acc[i][j][r] + bias[nn];
      }
    }
}

// ---------------------------------------------------------------------------
// PV with split-K=2: grid (2, S/128, BH); f32 partials -> pvp[ks][B,S,D]
// ---------------------------------------------------------------------------
__global__ __launch_bounds__(256) void pv_split(
    const float* __restrict__ Wts, const ushort* __restrict__ VtAll,
    float* __restrict__ pvp)
{
  __shared__ ushort As[128 * 64];
  __shared__ ushort Bs[128 * 64];
  const int t  = threadIdx.x;
  const int ks = blockIdx.x;
  const int m0 = blockIdx.y * 128;
  const int z  = blockIdx.z;
  const int l  = t & 63, wv = t >> 6;
  const int wr = wv >> 1, wc = wv & 1;
  const int lrow = l & 15, lhi = l >> 4;

  const float*  Af = Wts + (size_t)z * Ss * Ss;
  const ushort* Bt = VtAll + (size_t)z * DKk * Ss;

  f32x4 acc[4][4] = {};

  for (int kt = ks * 1024; kt < ks * 1024 + 1024; kt += 64) {
#pragma unroll
    for (int p = 0; p < 4; ++p) {
      const int li = p * 256 + t, row = li >> 3, g = li & 7;
      const int sw = row * 64 + ((g ^ (row & 7)) << 3);
      const float* src = Af + (size_t)(m0 + row) * Ss + kt + g * 8;
      const float4 v0 = *(const float4*)src;
      const float4 v1 = *(const float4*)(src + 4);
      short8t sa;
      sa[0] = (short)f2bf(v0.x); sa[1] = (short)f2bf(v0.y);
      sa[2] = (short)f2bf(v0.z); sa[3] = (short)f2bf(v0.w);
      sa[4] = (short)f2bf(v1.x); sa[5] = (short)f2bf(v1.y);
      sa[6] = (short)f2bf(v1.z); sa[7] = (short)f2bf(v1.w);
      *(short8t*)&As[sw] = sa;
      *(short8t*)&Bs[sw] = *(const short8t*)(Bt + (size_t)row * Ss + kt + g * 8);
    }
    __syncthreads();

#pragma unroll
    for (int kk = 0; kk < 2; ++kk) {
      short8t a[4], b[4];
      const int g = kk * 4 + lhi;
#pragma unroll
      for (int i = 0; i < 4; ++i) {
        const int row = wr * 64 + i * 16 + lrow;
        a[i] = *(const short8t*)&As[row * 64 + ((g ^ (row & 7)) << 3)];
      }
#pragma unroll
      for (int j = 0; j < 4; ++j) {
        const int row = wc * 64 + j * 16 + lrow;
        b[j] = *(const short8t*)&Bs[row * 64 + ((g ^ (row & 7)) << 3)];
      }
#pragma unroll
      for (int i = 0; i < 4; ++i)
#pragma unroll
        for (int j = 0; j < 4; ++j)
          acc[i][j] = __builtin_amdgcn_mfma_f32_16x16x32_bf16(a[i], b[j], acc[i][j], 0, 0, 0);
    }
    __syncthreads();
  }

  const int bb = z >> 3, hh = z & 7;
  float* outp = pvp + (size_t)ks * MROWS * Dd;
#pragma unroll
  for (int i = 0; i < 4; ++i)
#pragma unroll
    for (int j = 0; j < 4; ++j) {
      const int nn = wc * 64 + j * 16 + lrow;
#pragma unroll
      for (int r = 0; r < 4; ++r) {
        const int mm = m0 + wr * 64 + i * 16 + lhi * 4 + r;
        outp[((size_t)(bb * Ss + mm)) * Dd + hh * DKk + nn] = acc[i][j][r];
      }
    }
}

// ---------------------------------------------------------------------------
// W[1024][1024] f32 -> Wt bf16 (transposed)
// ---------------------------------------------------------------------------
__global__ __launch_bounds__(256) void transpose_bf16(
    const float* __restrict__ W, ushort* __restrict__ Wt)
{
  __shared__ float tile[32][33];
  const int t  = threadIdx.x;
  const int c0 = blockIdx.x * 32, r0 = blockIdx.y * 32;
  const int lr = t >> 3, lc4 = (t & 7) * 4;
  const float4 v = *(const float4*)(W + (size_t)(r0 + lr) * Dd + c0 + lc4);
  tile[lr][lc4 + 0] = v.x; tile[lr][lc4 + 1] = v.y;
  tile[lr][lc4 + 2] = v.z; tile[lr][lc4 + 3] = v.w;
  __syncthreads();
  const int oc = t >> 3, or4 = (t & 7) * 4;
  short4t o;
  o[0] = (short)f2bf(tile[or4 + 0][oc]);
  o[1] = (short)f2bf(tile[or4 + 1][oc]);
  o[2] = (short)f2bf(tile[or4 + 2][oc]);
  o[3] = (short)f2bf(tile[or4 + 3][oc]);
  *(short4t*)(Wt + (size_t)(c0 + oc) * Dd + r0 + or4) = o;
}

// ---------------------------------------------------------------------------
// W[1024][1024] f32 -> transposed hi/lo bf16 split
// ---------------------------------------------------------------------------
__global__ __launch_bounds__(256) void transpose_split(
    const float* __restrict__ W, ushort* __restrict__ Th, ushort* __restrict__ Tl)
{
  __shared__ float tile[32][33];
  const int t  = threadIdx.x;
  const int c0 = blockIdx.x * 32, r0 = blockIdx.y * 32;
  const int lr = t >> 3, lc4 = (t & 7) * 4;
  const float4 v = *(const float4*)(W + (size_t)(r0 + lr) * Dd + c0 + lc4);
  tile[lr][lc4 + 0] = v.x; tile[lr][lc4 + 1] = v.y;
  tile[lr][lc4 + 2] = v.z; tile[lr][lc4 + 3] = v.w;
  __syncthreads();
  const int oc = t >> 3, or4 = (t & 7) * 4;
  short4t oh, ol;
  HL r;
  r = split1(tile[or4 + 0][oc]); oh[0] = r.h; ol[0] = r.l;
  r = split1(tile[or4 + 1][oc]); oh[1] = r.h; ol[1] = r.l;
  r = split1(tile[or4 + 2][oc]); oh[2] = r.h; ol[2] = r.l;
  r = split1(tile[or4 + 3][oc]); oh[3] = r.h; ol[3] = r.l;
  *(short4t*)(Th + (size_t)(c0 + oc) * Dd + r0 + or4) = oh;
  *(short4t*)(Tl + (size_t)(c0 + oc) * Dd + r0 + or4) = ol;
}

// ---------------------------------------------------------------------------
// Per-row exact top-512 + softmax, v6: wave-per-row, zero __syncthreads.
// ---------------------------------------------------------------------------
__global__ __launch_bounds__(256) void topk_softmax(float* __restrict__ wts)
{
  __shared__ unsigned histAll[4][1088];

  const int lane = threadIdx.x & 63;
  const int wv   = threadIdx.x >> 6;
  const int row  = blockIdx.x * 4 + wv;
  float* rowp = wts + (size_t)row * Ss;
  unsigned* rowu = (unsigned*)rowp;
  unsigned* h = histAll[wv];

  unsigned k[32];
  unsigned lmax = 0u;
#pragma unroll
  for (int i = 0; i < 8; ++i) {
    const uint4 v = *(const uint4*)(rowu + i * 256 + lane * 4);
    k[i * 4 + 0] = v.x; k[i * 4 + 1] = v.y;
    k[i * 4 + 2] = v.z; k[i * 4 + 3] = v.w;
    lmax = max(max(lmax, max(v.x, v.y)), max(v.z, v.w));
  }
#pragma unroll
  for (int off = 32; off > 0; off >>= 1) lmax = max(lmax, __shfl_xor(lmax, off));
  const float m = key_to_float(lmax);

  unsigned needK = KTOP, tieC = 0u, prefix = 0u;

  // pass 1: bits [31:22], 1024 bins
  {
#pragma unroll
    for (int i = 0; i < 17; ++i) h[lane + i * 64] = 0u;
#pragma unroll
    for (int i = 0; i < 32; ++i) {
      const unsigned b = k[i] >> 22;
      atomicAdd(&h[b + (b >> 4)], 1u);
    }
    unsigned b[16], lsum = 0u;
#pragma unroll
    for (int i = 0; i < 16; ++i) { b[i] = h[lane * 17 + i]; lsum += b[i]; }
    unsigned s = lsum;
#pragma unroll
    for (int off = 1; off < 64; off <<= 1) {
      const unsigned v = __shfl_down(s, off);
      if (lane + off < 64) s += v;
    }
    unsigned run = s - lsum;
    unsigned fb = 0u, fn = 0u, ft = 0u;
    bool found = false;
#pragma unroll
    for (int i = 15; i >= 0; --i) {
      const unsigned c = b[i];
      if (!found && c > 0u && run < needK && run + c >= needK) {
        found = true; fb = (unsigned)(lane * 16 + i); fn = needK - run; ft = c;
      }
      run += c;
    }
    const unsigned long long msk = __ballot(found);
    const int src = (int)__ffsll(msk) - 1;
    prefix = __shfl(fb, src) << 22;
    needK  = __shfl(fn, src);
    tieC   = __shfl(ft, src);
  }

  // passes 2,3: 8-bit refinements (bits [21:14], [13:6])
#pragma unroll
  for (int pass = 0; pass < 2; ++pass) {
    const int sh = (pass == 0) ? 14 : 6;
    const int ph = sh + 8;
#pragma unroll
    for (int i = 0; i < 5; ++i) h[lane + i * 64] = 0u;
    const unsigned pcmp = prefix >> ph;
#pragma unroll
    for (int i = 0; i < 32; ++i) {
      if ((k[i] >> ph) == pcmp) {
        const unsigned b = (k[i] >> sh) & 255u;
        atomicAdd(&h[b + (b >> 4)], 1u);
      }
    }
    unsigned b4[4], lsum = 0u;
#pragma unroll
    for (int i = 0; i < 4; ++i) {
      const unsigned x = (unsigned)(lane * 4 + i);
      b4[i] = h[x + (x >> 4)];
      lsum += b4[i];
    }
    unsigned s = lsum;
#pragma unroll
    for (int off = 1; off < 64; off <<= 1) {
      const unsigned v = __shfl_down(s, off);
      if (lane + off < 64) s += v;
    }
    unsigned run = s - lsum;
    unsigned fb = 0u, fn = 0u, ft = 0u;
    bool found = false;
#pragma unroll
    for (int i = 3; i >= 0; --i) {
      const unsigned c = b4[i];
      if (!found && c > 0u && run < needK && run + c >= needK) {
        found = true; fb = (unsigned)(lane * 4 + i); fn = needK - run; ft = c;
      }
      run += c;
    }
    const unsigned long long msk = __ballot(found);
    const int src = (int)__ffsll(msk) - 1;
    prefix |= __shfl(fb, src) << sh;
    needK   = __shfl(fn, src);
    tieC    = __shfl(ft, src);
  }

  // pass 4: bits [5:0]
  unsigned T;
  {
    h[lane] = 0u;
    if (lane < 4) h[64 + lane] = 0u;
    const unsigned pcmp = prefix >> 6;
#pragma unroll
    for (int i = 0; i < 32; ++i) {
      if ((k[i] >> 6) == pcmp) {
        const unsigned b = k[i] & 63u;
        atomicAdd(&h[b + (b >> 4)], 1u);
      }
    }
    const unsigned b0 = h[lane + (lane >> 4)];
    unsigned s = b0;
#pragma unroll
    for (int off = 1; off < 64; off <<= 1) {
      const unsigned v = __shfl_down(s, off);
      if (lane + off < 64) s += v;
    }
    const unsigned run = s - b0;
    const bool found = (b0 > 0u && run < needK && run + b0 >= needK);
    const unsigned long long msk = __ballot(found);
    const int src = (int)__ffsll(msk) - 1;
    T     = prefix | (unsigned)__shfl((unsigned)lane, src);
    needK = __shfl(needK - run, src);
    tieC  = __shfl(b0, src);
  }

  if (tieC != needK) {
    unsigned R = 0u;
#pragma unroll
    for (int i = 0; i < 8; ++i) {
      unsigned myEq = 0u;
#pragma unroll
      for (int c = 0; c < 4; ++c) myEq += (k[i * 4 + c] == T);
      unsigned ps = myEq;
#pragma unroll
      for (int off = 1; off < 64; off <<= 1) {
        const unsigned v = __shfl_up(ps, off);
        if (lane >= off) ps += v;
      }
      unsigned before = R + ps - myEq;
#pragma unroll
      for (int c = 0; c < 4; ++c) {
        if (k[i * 4 + c] == T) {
          if (before >= needK) k[i * 4 + c] = 0u;
          ++before;
        }
      }
      R += __shfl(ps, 63);
    }
  }

  float lz = 0.f;
#pragma unroll
  for (int i = 0; i < 32; ++i) {
    const unsigned kk = k[i];
    const float w = (kk >= T) ? __expf(key_to_float(kk) - m) : 0.f;
    k[i] = __float_as_uint(w);
    lz += w;
  }
#pragma unroll
  for (int off = 32; off > 0; off >>= 1) lz += __shfl_xor(lz, off);
  const float Zi = 1.0f / lz;

#pragma unroll
  for (int i = 0; i < 8; ++i) {
    float4 o;
    o.x = __uint_as_float(k[i * 4 + 0]) * Zi;
    o.y = __uint_as_float(k[i * 4 + 1]) * Zi;
    o.z = __uint_as_float(k[i * 4 + 2]) * Zi;
    o.w = __uint_as_float(k[i * 4 + 3]) * Zi;
    *(float4*)(rowu + i * 256 + lane * 4) = o;
  }
}

}  // namespace

extern "C" void kernel_launch(void* const* d_in, const int* in_sizes, int n_in,
                              void* d_out_v, int out_size, void* d_ws, size_t ws_size,
                              hipStream_t stream)
{
  const float* query = (const float*)d_in[0];
  const float* key   = (const float*)d_in[1];
  const float* value = (const float*)d_in[2];
  const float* Wq = (const float*)d_in[3];  const float* bq = (const float*)d_in[4];
  const float* Wk = (const float*)d_in[5];  const float* bk = (const float*)d_in[6];
  const float* Wv = (const float*)d_in[7];  const float* bv = (const float*)d_in[8];
  const float* Wo = (const float*)d_in[9];  const float* bo = (const float*)d_in[10];

  float* d_out = (float*)d_out_v;
  float* outp  = d_out;                              // [B,S,D] f32
  float* wts   = d_out + (size_t)Bb * Ss * Dd;       // [B,H,S,S] f32

  const size_t PROJ = (size_t)MROWS * Dd;            // 4M elements
  const size_t DD2  = (size_t)Dd * Dd;               // 1M elements

  ushort* ws    = (ushort*)d_ws;
  ushort* Qh    = ws;                                // 8 MB each
  ushort* Ql    = Qh + PROJ;
  ushort* Kh    = Ql + PROJ;
  ushort* Kl    = Kh + PROJ;                         // ends at 32 MB
  ushort* wreg  = Kl + PROJ;
  ushort* WqTh  = wreg;                              // 4 x 2 MB splits
  ushort* WqTl  = wreg + DD2;
  ushort* WkTh  = wreg + 2 * DD2;
  ushort* WkTl  = wreg + 3 * DD2;
  ushort* WvT   = wreg + 4 * DD2;                    // 2 MB
  ushort* WoT   = wreg + 5 * DD2;                    // 2 MB
  ushort* Vt    = wreg + 6 * DD2;                    // bf16 V^T [16][128][2048] 8 MB
  float*  pvp   = (float*)Qh;                        // pv partials alias Qh..Kl (32 MB)

  // pre-split raw inputs live in the (not-yet-written) wts region of d_out
  ushort* qsh = (ushort*)wts;
  ushort* qsl = qsh + PROJ;
  ushort* ksh = qsh + 2 * PROJ;
  ushort* ksl = qsh + 3 * PROJ;
  ushort* vsb = qsh + 4 * PROJ;

  const dim3 blk(256);

  // weight prep
  transpose_split<<<dim3(32, 32), blk, 0, stream>>>(Wq, WqTh, WqTl);
  transpose_split<<<dim3(32, 32), blk, 0, stream>>>(Wk, WkTh, WkTl);
  transpose_bf16<<<dim3(32, 32), blk, 0, stream>>>(Wv, WvT);
  transpose_bf16<<<dim3(32, 32), blk, 0, stream>>>(Wo, WoT);

  // pre-split inputs (once, elementwise)
  split_inputs<<<dim3((int)(PROJ / 2048), 3), blk, 0, stream>>>(
      query, key, value, qsh, qsl, ksh, ksl, vsb);

  // Q/K/V projections, batched, 128x128 tile (scores-shaped), m fastest
  mfma_proj<<<dim3(MROWS / 128, Dd / 128, 3), blk, 0, stream>>>(
      qsh, qsl, ksh, ksl, vsb, WqTh, WqTl, WkTh, WkTl, WvT,
      bq, bk, bv, Qh, Ql, Kh, Kl, Vt);

  // scores -> u32 keys in wts region (SCALE folded)
  mfma_scores<<<dim3(Ss / 128, Ss / 128, BH), blk, 0, stream>>>(
      Qh, Ql, Kh, Kl, (unsigned*)wts);

  // exact top-512 + softmax, in place (wave-per-row)
  topk_softmax<<<dim3(BH * Ss / 4), blk, 0, stream>>>(wts);

  // PV split-K=2 -> f32 partials (aliasing dead Qh..Kl)
  pv_split<<<dim3(2, Ss / 128, BH), blk, 0, stream>>>(wts, Vt, pvp);

  // output projection with inline partial-reduce, x = M-block
  mfma_oproj<<<dim3(MROWS / 128, Dd / 128), blk, 0, stream>>>(
      pvp, pvp + (size_t)MROWS * Dd, WoT, bo, outp);
}

// Round 15
// 380.680 us; speedup vs baseline: 1.6997x; 1.0300x over previous
//
#include <hip/hip_runtime.h>
#include <hip/hip_bf16.h>
#include <math.h>

namespace {

constexpr int Bb   = 2;
constexpr int Ss   = 2048;
constexpr int Dd   = 1024;
constexpr int Hh   = 8;
constexpr int DKk  = 128;
constexpr int KTOP = 512;
constexpr int BH    = Bb * Hh;   // 16
constexpr int MROWS = Bb * Ss;   // 4096
constexpr float SCALE = 0.08838834764831845f;  // 1/sqrt(128)

typedef __attribute__((ext_vector_type(8))) short short8t;  // 8 bf16 = 16 B
typedef __attribute__((ext_vector_type(4))) short short4t;  // 4 bf16 = 8 B
typedef __attribute__((ext_vector_type(4))) float f32x4;

__device__ inline ushort f2bf(float x) {  // f32 -> bf16 RNE
  const unsigned u = __float_as_uint(x);
  return (ushort)((u + 0x7FFFu + ((u >> 16) & 1u)) >> 16);
}
__device__ inline float bf2f(ushort h) {
  return __uint_as_float(((unsigned)h) << 16);
}
struct HL { short h, l; };
__device__ inline HL split1(float x) {
  HL r;
  const ushort hu = f2bf(x);
  r.h = (short)hu;
  r.l = (short)f2bf(x - bf2f(hu));
  return r;
}

__device__ inline unsigned key_of(float v) {
  const unsigned u = __float_as_uint(v);
  return (u & 0x80000000u) ? ~u : (u | 0x80000000u);
}
__device__ inline float key_to_float(unsigned k) {
  const unsigned u = (k & 0x80000000u) ? (k & 0x7FFFFFFFu) : ~k;
  return __uint_as_float(u);
}

// async global->LDS, 16 B per lane; LDS dest = uniform base + lane*16
__device__ inline void gload16(const void* g, void* l) {
  __builtin_amdgcn_global_load_lds(
      (const __attribute__((address_space(1))) unsigned int*)g,
      (__attribute__((address_space(3))) unsigned int*)l, 16, 0, 0);
}

// ---------------------------------------------------------------------------
// Pre-split raw inputs ONCE: z=0 query->hi/lo, z=1 key->hi/lo, z=2 value->bf16
// ---------------------------------------------------------------------------
__global__ __launch_bounds__(256) void split_inputs(
    const float* __restrict__ query, const float* __restrict__ keyi,
    const float* __restrict__ value,
    ushort* __restrict__ qsh, ushort* __restrict__ qsl,
    ushort* __restrict__ ksh, ushort* __restrict__ ksl,
    ushort* __restrict__ vsb)
{
  const int z = blockIdx.y;
  const size_t i = ((size_t)blockIdx.x * 256 + threadIdx.x) * 8;
  const float* src = (z == 0) ? query : (z == 1) ? keyi : value;
  const float4 v0 = *(const float4*)(src + i);
  const float4 v1 = *(const float4*)(src + i + 4);
  if (z < 2) {
    ushort* oh = (z == 0) ? qsh : ksh;
    ushort* ol = (z == 0) ? qsl : ksl;
    short8t h, lo;
    HL r;
    r = split1(v0.x); h[0] = r.h; lo[0] = r.l;
    r = split1(v0.y); h[1] = r.h; lo[1] = r.l;
    r = split1(v0.z); h[2] = r.h; lo[2] = r.l;
    r = split1(v0.w); h[3] = r.h; lo[3] = r.l;
    r = split1(v1.x); h[4] = r.h; lo[4] = r.l;
    r = split1(v1.y); h[5] = r.h; lo[5] = r.l;
    r = split1(v1.z); h[6] = r.h; lo[6] = r.l;
    r = split1(v1.w); h[7] = r.h; lo[7] = r.l;
    *(short8t*)(oh + i) = h;
    *(short8t*)(ol + i) = lo;
  } else {
    short8t h;
    h[0] = (short)f2bf(v0.x); h[1] = (short)f2bf(v0.y);
    h[2] = (short)f2bf(v0.z); h[3] = (short)f2bf(v0.w);
    h[4] = (short)f2bf(v1.x); h[5] = (short)f2bf(v1.y);
    h[6] = (short)f2bf(v1.z); h[7] = (short)f2bf(v1.w);
    *(short8t*)(vsb + i) = h;
  }
}

// ---------------------------------------------------------------------------
// Batched Q/K/V projection, v5: 128x128 / BK=32 / 4 waves, async
// global_load_lds staging with source-side swizzle (LDS stays lane-linear).
// z: 0=Q, 1=K (3-term, out hi/lo [bh][s][dk]); 2=V (1-term, out Vt).
// ---------------------------------------------------------------------------
__global__ __launch_bounds__(256) void mfma_proj(
    const ushort* __restrict__ qsh, const ushort* __restrict__ qsl,
    const ushort* __restrict__ ksh, const ushort* __restrict__ ksl,
    const ushort* __restrict__ vsb,
    const ushort* __restrict__ WqTh, const ushort* __restrict__ WqTl,
    const ushort* __restrict__ WkTh, const ushort* __restrict__ WkTl,
    const ushort* __restrict__ WvT,
    const float* __restrict__ bq, const float* __restrict__ bk,
    const float* __restrict__ bv,
    ushort* __restrict__ Qh, ushort* __restrict__ Ql,
    ushort* __restrict__ Kh, ushort* __restrict__ Kl,
    ushort* __restrict__ Vt)
{
  __shared__ ushort Ah[128 * 32];
  __shared__ ushort Al[128 * 32];
  __shared__ ushort Bh[128 * 32];
  __shared__ ushort Bl[128 * 32];
  const int t  = threadIdx.x;
  const int z  = blockIdx.z;
  const int m0 = blockIdx.x * 128;  // m fastest -> per-XCD A-panel locality
  const int n0 = blockIdx.y * 128;
  const int l  = t & 63, wv = t >> 6;
  const int wr = wv >> 1, wc = wv & 1;
  const int lrow = l & 15, lhi = l >> 4;

  const ushort* Ah_g = (z == 0) ? qsh : (z == 1) ? ksh : vsb;
  const ushort* Al_g = (z == 0) ? qsl : (z == 1) ? ksl : nullptr;
  const ushort* Bth  = (z == 0) ? WqTh : (z == 1) ? WkTh : WvT;
  const ushort* Btl  = (z == 0) ? WqTl : (z == 1) ? WkTl : nullptr;
  const float*  bias = (z == 0) ? bq   : (z == 1) ? bk   : bv;
  const bool    splitTerms = (z < 2);

  f32x4 acc[4][4] = {};

  for (int kt = 0; kt < Dd; kt += 32) {
#pragma unroll
    for (int p = 0; p < 2; ++p) {
      const int baseRow = p * 64 + wv * 16;          // wave-uniform
      const int row  = baseRow + (l >> 2);
      const int gl   = (l & 3) ^ (row & 3);          // pre-swizzled source granule
      const size_t ao = (size_t)(m0 + row) * Dd + kt + gl * 8;
      const size_t bo = (size_t)(n0 + row) * Dd + kt + gl * 8;
      gload16(Ah_g + ao, &Ah[baseRow * 32]);
      gload16(Bth + bo, &Bh[baseRow * 32]);
      if (splitTerms) {
        gload16(Al_g + ao, &Al[baseRow * 32]);
        gload16(Btl + bo, &Bl[baseRow * 32]);
      }
    }
    __syncthreads();

    short8t ah[4], al[4], bh[4], bl[4];
#pragma unroll
    for (int i = 0; i < 4; ++i) {
      const int row = wr * 64 + i * 16 + lrow;
      const int idx = row * 32 + ((lhi ^ (row & 3)) << 3);
      ah[i] = *(const short8t*)&Ah[idx];
      if (splitTerms) al[i] = *(const short8t*)&Al[idx];
    }
#pragma unroll
    for (int j = 0; j < 4; ++j) {
      const int row = wc * 64 + j * 16 + lrow;
      const int idx = row * 32 + ((lhi ^ (row & 3)) << 3);
      bh[j] = *(const short8t*)&Bh[idx];
      if (splitTerms) bl[j] = *(const short8t*)&Bl[idx];
    }
#pragma unroll
    for (int i = 0; i < 4; ++i)
#pragma unroll
      for (int j = 0; j < 4; ++j) {
        acc[i][j] = __builtin_amdgcn_mfma_f32_16x16x32_bf16(ah[i], bh[j], acc[i][j], 0, 0, 0);
        if (splitTerms) {
          acc[i][j] = __builtin_amdgcn_mfma_f32_16x16x32_bf16(ah[i], bl[j], acc[i][j], 0, 0, 0);
          acc[i][j] = __builtin_amdgcn_mfma_f32_16x16x32_bf16(al[i], bh[j], acc[i][j], 0, 0, 0);
        }
      }
    __syncthreads();
  }

#pragma unroll
  for (int i = 0; i < 4; ++i) {
#pragma unroll
    for (int j = 0; j < 4; ++j) {
      const int nn = n0 + wc * 64 + j * 16 + lrow;
#pragma unroll
      for (int r = 0; r < 4; ++r) {
        const int mm = m0 + wr * 64 + i * 16 + lhi * 4 + r;
        const float v = acc[i][j][r] + bias[nn];
        const int bb = mm >> 11, s = mm & (Ss - 1);
        const int hh = nn >> 7,  dk = nn & (DKk - 1);
        if (z < 2) {
          const size_t o = (((size_t)(bb * Hh + hh)) * Ss + s) * DKk + dk;
          const HL rr = split1(v);
          if (z == 0) { Qh[o] = (ushort)rr.h; Ql[o] = (ushort)rr.l; }
          else        { Kh[o] = (ushort)rr.h; Kl[o] = (ushort)rr.l; }
        } else {
          Vt[((size_t)((bb * Hh + hh) * DKk + dk)) * Ss + s] = f2bf(v);
        }
      }
    }
  }
}

// ---------------------------------------------------------------------------
// Scores from pre-split Q,K, async-staged; epilogue writes u32 keys (SCALE in)
// ---------------------------------------------------------------------------
__global__ __launch_bounds__(256) void mfma_scores(
    const ushort* __restrict__ Qh, const ushort* __restrict__ Ql,
    const ushort* __restrict__ Kh, const ushort* __restrict__ Kl,
    unsigned* __restrict__ wtsOut)
{
  __shared__ ushort Ah[128 * 32];
  __shared__ ushort Al[128 * 32];
  __shared__ ushort Bh[128 * 32];
  __shared__ ushort Bl[128 * 32];
  const int t  = threadIdx.x;
  const int z  = blockIdx.z;
  const int n0 = blockIdx.x * 128;   // j
  const int m0 = blockIdx.y * 128;   // q
  const int l  = t & 63, wv = t >> 6;
  const int wr = wv >> 1, wc = wv & 1;
  const int lrow = l & 15, lhi = l >> 4;
  const size_t boff = (size_t)z * Ss * DKk;

  f32x4 acc[4][4] = {};

  for (int kt = 0; kt < DKk; kt += 32) {
#pragma unroll
    for (int p = 0; p < 2; ++p) {
      const int baseRow = p * 64 + wv * 16;
      const int row  = baseRow + (l >> 2);
      const int gl   = (l & 3) ^ (row & 3);
      const size_t ao = boff + (size_t)(m0 + row) * DKk + kt + gl * 8;
      const size_t bo = boff + (size_t)(n0 + row) * DKk + kt + gl * 8;
      gload16(Qh + ao, &Ah[baseRow * 32]);
      gload16(Ql + ao, &Al[baseRow * 32]);
      gload16(Kh + bo, &Bh[baseRow * 32]);
      gload16(Kl + bo, &Bl[baseRow * 32]);
    }
    __syncthreads();

    short8t ah[4], al[4], bh[4], bl[4];
#pragma unroll
    for (int i = 0; i < 4; ++i) {
      const int row = wr * 64 + i * 16 + lrow;
      const int idx = row * 32 + ((lhi ^ (row & 3)) << 3);
      ah[i] = *(const short8t*)&Ah[idx];
      al[i] = *(const short8t*)&Al[idx];
    }
#pragma unroll
    for (int j = 0; j < 4; ++j) {
      const int row = wc * 64 + j * 16 + lrow;
      const int idx = row * 32 + ((lhi ^ (row & 3)) << 3);
      bh[j] = *(const short8t*)&Bh[idx];
      bl[j] = *(const short8t*)&Bl[idx];
    }
#pragma unroll
    for (int i = 0; i < 4; ++i)
#pragma unroll
      for (int j = 0; j < 4; ++j) {
        acc[i][j] = __builtin_amdgcn_mfma_f32_16x16x32_bf16(ah[i], bh[j], acc[i][j], 0, 0, 0);
        acc[i][j] = __builtin_amdgcn_mfma_f32_16x16x32_bf16(ah[i], bl[j], acc[i][j], 0, 0, 0);
        acc[i][j] = __builtin_amdgcn_mfma_f32_16x16x32_bf16(al[i], bh[j], acc[i][j], 0, 0, 0);
      }
    __syncthreads();
  }

#pragma unroll
  for (int i = 0; i < 4; ++i)
#pragma unroll
    for (int j = 0; j < 4; ++j) {
      const int nn = n0 + wc * 64 + j * 16 + lrow;
#pragma unroll
      for (int r = 0; r < 4; ++r) {
        const int mm = m0 + wr * 64 + i * 16 + lhi * 4 + r;
        wtsOut[(size_t)z * Ss * Ss + (size_t)mm * Ss + nn] =
            key_of(acc[i][j][r] * SCALE);
      }
    }
}

// ---------------------------------------------------------------------------
// o_proj with inline pv-partial reduce; async B staging
// ---------------------------------------------------------------------------
__global__ __launch_bounds__(256) void mfma_oproj(
    const float* __restrict__ pv0, const float* __restrict__ pv1,
    const ushort* __restrict__ Bt,
    const float* __restrict__ bias, float* __restrict__ Cout)
{
  __shared__ ushort As[128 * 64];
  __shared__ ushort Bs[128 * 64];
  const int t  = threadIdx.x;
  const int m0 = blockIdx.x * 128;
  const int n0 = blockIdx.y * 128;
  const int l  = t & 63, wv = t >> 6;
  const int wr = wv >> 1, wc = wv & 1;
  const int lrow = l & 15, lhi = l >> 4;

  f32x4 acc[4][4] = {};

  for (int kt = 0; kt < Dd; kt += 64) {
#pragma unroll
    for (int p = 0; p < 4; ++p) {
      // B: async with source-side swizzle
      const int baseRow = p * 32 + wv * 8;
      const int brow = baseRow + (l >> 3);
      const int bgl  = (l & 7) ^ (brow & 7);
      gload16(Bt + (size_t)(n0 + brow) * Dd + kt + bgl * 8, &Bs[baseRow * 64]);
      // A: manual (reduce + convert)
      const int li = p * 256 + t, row = li >> 3, g = li & 7;
      const int sw = row * 64 + ((g ^ (row & 7)) << 3);
      const size_t ao = (size_t)(m0 + row) * Dd + kt + g * 8;
      const float4 a0 = *(const float4*)(pv0 + ao);
      const float4 a1 = *(const float4*)(pv0 + ao + 4);
      const float4 c0 = *(const float4*)(pv1 + ao);
      const float4 c1 = *(const float4*)(pv1 + ao + 4);
      short8t sa;
      sa[0] = (short)f2bf(a0.x + c0.x); sa[1] = (short)f2bf(a0.y + c0.y);
      sa[2] = (short)f2bf(a0.z + c0.z); sa[3] = (short)f2bf(a0.w + c0.w);
      sa[4] = (short)f2bf(a1.x + c1.x); sa[5] = (short)f2bf(a1.y + c1.y);
      sa[6] = (short)f2bf(a1.z + c1.z); sa[7] = (short)f2bf(a1.w + c1.w);
      *(short8t*)&As[sw] = sa;
    }
    __syncthreads();

#pragma unroll
    for (int kk = 0; kk < 2; ++kk) {
      short8t a[4], b[4];
      const int g = kk * 4 + lhi;
#pragma unroll
      for (int i = 0; i < 4; ++i) {
        const int row = wr * 64 + i * 16 + lrow;
        a[i] = *(const short8t*)&As[row * 64 + ((g ^ (row & 7)) << 3)];
      }
#pragma unroll
      for (int j = 0; j < 4; ++j) {
        const int row = wc * 64 + j * 16 + lrow;
        b[j] = *(const short8t*)&Bs[row * 64 + ((g ^ (row & 7)) << 3)];
      }
#pragma unroll
      for (int i = 0; i < 4; ++i)
#pragma unroll
        for (int j = 0; j < 4; ++j)
          acc[i][j] = __builtin_amdgcn_mfma_f32_16x16x32_bf16(a[i], b[j], acc[i][j], 0, 0, 0);
    }
    __syncthreads();
  }

#pragma unroll
  for (int i = 0; i < 4; ++i)
#pragma unroll
    for (int j = 0; j < 4; ++j) {
      const int nn = n0 + wc * 64 + j * 16 + lrow;
#pragma unroll
      for (int r = 0; r < 4; ++r) {
        const int mm = m0 + wr * 64 + i * 16 + lhi * 4 + r;
        Cout[(size_t)mm * Dd + nn] = acc[i][j][r] + bias[nn];
      }
    }
}

// ---------------------------------------------------------------------------
// PV with split-K=2: async B staging; A manual (f32->bf16 convert)
// ---------------------------------------------------------------------------
__global__ __launch_bounds__(256) void pv_split(
    const float* __restrict__ Wts, const ushort* __restrict__ VtAll,
    float* __restrict__ pvp)
{
  __shared__ ushort As[128 * 64];
  __shared__ ushort Bs[128 * 64];
  const int t  = threadIdx.x;
  const int ks = blockIdx.x;
  const int m0 = blockIdx.y * 128;
  const int z  = blockIdx.z;
  const int l  = t & 63, wv = t >> 6;
  const int wr = wv >> 1, wc = wv & 1;
  const int lrow = l & 15, lhi = l >> 4;

  const float*  Af = Wts + (size_t)z * Ss * Ss;
  const ushort* Bt = VtAll + (size_t)z * DKk * Ss;

  f32x4 acc[4][4] = {};

  for (int kt = ks * 1024; kt < ks * 1024 + 1024; kt += 64) {
#pragma unroll
    for (int p = 0; p < 4; ++p) {
      // B: async with source-side swizzle (Vt rows = dk, cols = s)
      const int baseRow = p * 32 + wv * 8;
      const int brow = baseRow + (l >> 3);
      const int bgl  = (l & 7) ^ (brow & 7);
      gload16(Bt + (size_t)brow * Ss + kt + bgl * 8, &Bs[baseRow * 64]);
      // A: manual convert
      const int li = p * 256 + t, row = li >> 3, g = li & 7;
      const int sw = row * 64 + ((g ^ (row & 7)) << 3);
      const float* src = Af + (size_t)(m0 + row) * Ss + kt + g * 8;
      const float4 v0 = *(const float4*)src;
      const float4 v1 = *(const float4*)(src + 4);
      short8t sa;
      sa[0] = (short)f2bf(v0.x); sa[1] = (short)f2bf(v0.y);
      sa[2] = (short)f2bf(v0.z); sa[3] = (short)f2bf(v0.w);
      sa[4] = (short)f2bf(v1.x); sa[5] = (short)f2bf(v1.y);
      sa[6] = (short)f2bf(v1.z); sa[7] = (short)f2bf(v1.w);
      *(short8t*)&As[sw] = sa;
    }
    __syncthreads();

#pragma unroll
    for (int kk = 0; kk < 2; ++kk) {
      short8t a[4], b[4];
      const int g = kk * 4 + lhi;
#pragma unroll
      for (int i = 0; i < 4; ++i) {
        const int row = wr * 64 + i * 16 + lrow;
        a[i] = *(const short8t*)&As[row * 64 + ((g ^ (row & 7)) << 3)];
      }
#pragma unroll
      for (int j = 0; j < 4; ++j) {
        const int row = wc * 64 + j * 16 + lrow;
        b[j] = *(const short8t*)&Bs[row * 64 + ((g ^ (row & 7)) << 3)];
      }
#pragma unroll
      for (int i = 0; i < 4; ++i)
#pragma unroll
        for (int j = 0; j < 4; ++j)
          acc[i][j] = __builtin_amdgcn_mfma_f32_16x16x32_bf16(a[i], b[j], acc[i][j], 0, 0, 0);
    }
    __syncthreads();
  }

  const int bb = z >> 3, hh = z & 7;
  float* outp = pvp + (size_t)ks * MROWS * Dd;
#pragma unroll
  for (int i = 0; i < 4; ++i)
#pragma unroll
    for (int j = 0; j < 4; ++j) {
      const int nn = wc * 64 + j * 16 + lrow;
#pragma unroll
      for (int r = 0; r < 4; ++r) {
        const int mm = m0 + wr * 64 + i * 16 + lhi * 4 + r;
        outp[((size_t)(bb * Ss + mm)) * Dd + hh * DKk + nn] = acc[i][j][r];
      }
    }
}

// ---------------------------------------------------------------------------
// W[1024][1024] f32 -> Wt bf16 (transposed)
// ---------------------------------------------------------------------------
__global__ __launch_bounds__(256) void transpose_bf16(
    const float* __restrict__ W, ushort* __restrict__ Wt)
{
  __shared__ float tile[32][33];
  const int t  = threadIdx.x;
  const int c0 = blockIdx.x * 32, r0 = blockIdx.y * 32;
  const int lr = t >> 3, lc4 = (t & 7) * 4;
  const float4 v = *(const float4*)(W + (size_t)(r0 + lr) * Dd + c0 + lc4);
  tile[lr][lc4 + 0] = v.x; tile[lr][lc4 + 1] = v.y;
  tile[lr][lc4 + 2] = v.z; tile[lr][lc4 + 3] = v.w;
  __syncthreads();
  const int oc = t >> 3, or4 = (t & 7) * 4;
  short4t o;
  o[0] = (short)f2bf(tile[or4 + 0][oc]);
  o[1] = (short)f2bf(tile[or4 + 1][oc]);
  o[2] = (short)f2bf(tile[or4 + 2][oc]);
  o[3] = (short)f2bf(tile[or4 + 3][oc]);
  *(short4t*)(Wt + (size_t)(c0 + oc) * Dd + r0 + or4) = o;
}

// ---------------------------------------------------------------------------
// W[1024][1024] f32 -> transposed hi/lo bf16 split
// ---------------------------------------------------------------------------
__global__ __launch_bounds__(256) void transpose_split(
    const float* __restrict__ W, ushort* __restrict__ Th, ushort* __restrict__ Tl)
{
  __shared__ float tile[32][33];
  const int t  = threadIdx.x;
  const int c0 = blockIdx.x * 32, r0 = blockIdx.y * 32;
  const int lr = t >> 3, lc4 = (t & 7) * 4;
  const float4 v = *(const float4*)(W + (size_t)(r0 + lr) * Dd + c0 + lc4);
  tile[lr][lc4 + 0] = v.x; tile[lr][lc4 + 1] = v.y;
  tile[lr][lc4 + 2] = v.z; tile[lr][lc4 + 3] = v.w;
  __syncthreads();
  const int oc = t >> 3, or4 = (t & 7) * 4;
  short4t oh, ol;
  HL r;
  r = split1(tile[or4 + 0][oc]); oh[0] = r.h; ol[0] = r.l;
  r = split1(tile[or4 + 1][oc]); oh[1] = r.h; ol[1] = r.l;
  r = split1(tile[or4 + 2][oc]); oh[2] = r.h; ol[2] = r.l;
  r = split1(tile[or4 + 3][oc]); oh[3] = r.h; ol[3] = r.l;
  *(short4t*)(Th + (size_t)(c0 + oc) * Dd + r0 + or4) = oh;
  *(short4t*)(Tl + (size_t)(c0 + oc) * Dd + r0 + or4) = ol;
}

// ---------------------------------------------------------------------------
// Per-row exact top-512 + softmax, v6: wave-per-row, zero __syncthreads.
// ---------------------------------------------------------------------------
__global__ __launch_bounds__(256) void topk_softmax(float* __restrict__ wts)
{
  __shared__ unsigned histAll[4][1088];

  const int lane = threadIdx.x & 63;
  const int wv   = threadIdx.x >> 6;
  const int row  = blockIdx.x * 4 + wv;
  float* rowp = wts + (size_t)row * Ss;
  unsigned* rowu = (unsigned*)rowp;
  unsigned* h = histAll[wv];

  unsigned k[32];
  unsigned lmax = 0u;
#pragma unroll
  for (int i = 0; i < 8; ++i) {
    const uint4 v = *(const uint4*)(rowu + i * 256 + lane * 4);
    k[i * 4 + 0] = v.x; k[i * 4 + 1] = v.y;
    k[i * 4 + 2] = v.z; k[i * 4 + 3] = v.w;
    lmax = max(max(lmax, max(v.x, v.y)), max(v.z, v.w));
  }
#pragma unroll
  for (int off = 32; off > 0; off >>= 1) lmax = max(lmax, __shfl_xor(lmax, off));
  const float m = key_to_float(lmax);

  unsigned needK = KTOP, tieC = 0u, prefix = 0u;

  // pass 1: bits [31:22], 1024 bins
  {
#pragma unroll
    for (int i = 0; i < 17; ++i) h[lane + i * 64] = 0u;
#pragma unroll
    for (int i = 0; i < 32; ++i) {
      const unsigned b = k[i] >> 22;
      atomicAdd(&h[b + (b >> 4)], 1u);
    }
    unsigned b[16], lsum = 0u;
#pragma unroll
    for (int i = 0; i < 16; ++i) { b[i] = h[lane * 17 + i]; lsum += b[i]; }
    unsigned s = lsum;
#pragma unroll
    for (int off = 1; off < 64; off <<= 1) {
      const unsigned v = __shfl_down(s, off);
      if (lane + off < 64) s += v;
    }
    unsigned run = s - lsum;
    unsigned fb = 0u, fn = 0u, ft = 0u;
    bool found = false;
#pragma unroll
    for (int i = 15; i >= 0; --i) {
      const unsigned c = b[i];
      if (!found && c > 0u && run < needK && run + c >= needK) {
        found = true; fb = (unsigned)(lane * 16 + i); fn = needK - run; ft = c;
      }
      run += c;
    }
    const unsigned long long msk = __ballot(found);
    const int src = (int)__ffsll(msk) - 1;
    prefix = __shfl(fb, src) << 22;
    needK  = __shfl(fn, src);
    tieC   = __shfl(ft, src);
  }

  // passes 2,3: 8-bit refinements (bits [21:14], [13:6])
#pragma unroll
  for (int pass = 0; pass < 2; ++pass) {
    const int sh = (pass == 0) ? 14 : 6;
    const int ph = sh + 8;
#pragma unroll
    for (int i = 0; i < 5; ++i) h[lane + i * 64] = 0u;
    const unsigned pcmp = prefix >> ph;
#pragma unroll
    for (int i = 0; i < 32; ++i) {
      if ((k[i] >> ph) == pcmp) {
        const unsigned b = (k[i] >> sh) & 255u;
        atomicAdd(&h[b + (b >> 4)], 1u);
      }
    }
    unsigned b4[4], lsum = 0u;
#pragma unroll
    for (int i = 0; i < 4; ++i) {
      const unsigned x = (unsigned)(lane * 4 + i);
      b4[i] = h[x + (x >> 4)];
      lsum += b4[i];
    }
    unsigned s = lsum;
#pragma unroll
    for (int off = 1; off < 64; off <<= 1) {
      const unsigned v = __shfl_down(s, off);
      if (lane + off < 64) s += v;
    }
    unsigned run = s - lsum;
    unsigned fb = 0u, fn = 0u, ft = 0u;
    bool found = false;
#pragma unroll
    for (int i = 3; i >= 0; --i) {
      const unsigned c = b4[i];
      if (!found && c > 0u && run < needK && run + c >= needK) {
        found = true; fb = (unsigned)(lane * 4 + i); fn = needK - run; ft = c;
      }
      run += c;
    }
    const unsigned long long msk = __ballot(found);
    const int src = (int)__ffsll(msk) - 1;
    prefix |= __shfl(fb, src) << sh;
    needK   = __shfl(fn, src);
    tieC    = __shfl(ft, src);
  }

  // pass 4: bits [5:0]
  unsigned T;
  {
    h[lane] = 0u;
    if (lane < 4) h[64 + lane] = 0u;
    const unsigned pcmp = prefix >> 6;
#pragma unroll
    for (int i = 0; i < 32; ++i) {
      if ((k[i] >> 6) == pcmp) {
        const unsigned b = k[i] & 63u;
        atomicAdd(&h[b + (b >> 4)], 1u);
      }
    }
    const unsigned b0 = h[lane + (lane >> 4)];
    unsigned s = b0;
#pragma unroll
    for (int off = 1; off < 64; off <<= 1) {
      const unsigned v = __shfl_down(s, off);
      if (lane + off < 64) s += v;
    }
    const unsigned run = s - b0;
    const bool found = (b0 > 0u && run < needK && run + b0 >= needK);
    const unsigned long long msk = __ballot(found);
    const int src = (int)__ffsll(msk) - 1;
    T     = prefix | (unsigned)__shfl((unsigned)lane, src);
    needK = __shfl(needK - run, src);
    tieC  = __shfl(b0, src);
  }

  if (tieC != needK) {
    unsigned R = 0u;
#pragma unroll
    for (int i = 0; i < 8; ++i) {
      unsigned myEq = 0u;
#pragma unroll
      for (int c = 0; c < 4; ++c) myEq += (k[i * 4 + c] == T);
      unsigned ps = myEq;
#pragma unroll
      for (int off = 1; off < 64; off <<= 1) {
        const unsigned v = __shfl_up(ps, off);
        if (lane >= off) ps += v;
      }
      unsigned before = R + ps - myEq;
#pragma unroll
      for (int c = 0; c < 4; ++c) {
        if (k[i * 4 + c] == T) {
          if (before >= needK) k[i * 4 + c] = 0u;
          ++before;
        }
      }
      R += __shfl(ps, 63);
    }
  }

  float lz = 0.f;
#pragma unroll
  for (int i = 0; i < 32; ++i) {
    const unsigned kk = k[i];
    const float w = (kk >= T) ? __expf(key_to_float(kk) - m) : 0.f;
    k[i] = __float_as_uint(w);
    lz += w;
  }
#pragma unroll
  for (int off = 32; off > 0; off >>= 1) lz += __shfl_xor(lz, off);
  const float Zi = 1.0f / lz;

#pragma unroll
  for (int i = 0; i < 8; ++i) {
    float4 o;
    o.x = __uint_as_float(k[i * 4 + 0]) * Zi;
    o.y = __uint_as_float(k[i * 4 + 1]) * Zi;
    o.z = __uint_as_float(k[i * 4 + 2]) * Zi;
    o.w = __uint_as_float(k[i * 4 + 3]) * Zi;
    *(float4*)(rowu + i * 256 + lane * 4) = o;
  }
}

}  // namespace

extern "C" void kernel_launch(void* const* d_in, const int* in_sizes, int n_in,
                              void* d_out_v, int out_size, void* d_ws, size_t ws_size,
                              hipStream_t stream)
{
  const float* query = (const float*)d_in[0];
  const float* key   = (const float*)d_in[1];
  const float* value = (const float*)d_in[2];
  const float* Wq = (const float*)d_in[3];  const float* bq = (const float*)d_in[4];
  const float* Wk = (const float*)d_in[5];  const float* bk = (const float*)d_in[6];
  const float* Wv = (const float*)d_in[7];  const float* bv = (const float*)d_in[8];
  const float* Wo = (const float*)d_in[9];  const float* bo = (const float*)d_in[10];

  float* d_out = (float*)d_out_v;
  float* outp  = d_out;                              // [B,S,D] f32
  float* wts   = d_out + (size_t)Bb * Ss * Dd;       // [B,H,S,S] f32

  const size_t PROJ = (size_t)MROWS * Dd;            // 4M elements
  const size_t DD2  = (size_t)Dd * Dd;               // 1M elements

  ushort* ws    = (ushort*)d_ws;
  ushort* Qh    = ws;                                // 8 MB each
  ushort* Ql    = Qh + PROJ;
  ushort* Kh    = Ql + PROJ;
  ushort* Kl    = Kh + PROJ;                         // ends at 32 MB
  ushort* wreg  = Kl + PROJ;
  ushort* WqTh  = wreg;                              // 4 x 2 MB splits
  ushort* WqTl  = wreg + DD2;
  ushort* WkTh  = wreg + 2 * DD2;
  ushort* WkTl  = wreg + 3 * DD2;
  ushort* WvT   = wreg + 4 * DD2;                    // 2 MB
  ushort* WoT   = wreg + 5 * DD2;                    // 2 MB
  ushort* Vt    = wreg + 6 * DD2;                    // bf16 V^T [16][128][2048] 8 MB
  float*  pvp   = (float*)Qh;                        // pv partials alias Qh..Kl (32 MB)

  // pre-split raw inputs live in the (not-yet-written) wts region of d_out
  ushort* qsh = (ushort*)wts;
  ushort* qsl = qsh + PROJ;
  ushort* ksh = qsh + 2 * PROJ;
  ushort* ksl = qsh + 3 * PROJ;
  ushort* vsb = qsh + 4 * PROJ;

  const dim3 blk(256);

  // weight prep
  transpose_split<<<dim3(32, 32), blk, 0, stream>>>(Wq, WqTh, WqTl);
  transpose_split<<<dim3(32, 32), blk, 0, stream>>>(Wk, WkTh, WkTl);
  transpose_bf16<<<dim3(32, 32), blk, 0, stream>>>(Wv, WvT);
  transpose_bf16<<<dim3(32, 32), blk, 0, stream>>>(Wo, WoT);

  // pre-split inputs (once, elementwise)
  split_inputs<<<dim3((int)(PROJ / 2048), 3), blk, 0, stream>>>(
      query, key, value, qsh, qsl, ksh, ksl, vsb);

  // Q/K/V projections, batched, 128x128 tile, async staging
  mfma_proj<<<dim3(MROWS / 128, Dd / 128, 3), blk, 0, stream>>>(
      qsh, qsl, ksh, ksl, vsb, WqTh, WqTl, WkTh, WkTl, WvT,
      bq, bk, bv, Qh, Ql, Kh, Kl, Vt);

  // scores -> u32 keys in wts region (SCALE folded)
  mfma_scores<<<dim3(Ss / 128, Ss / 128, BH), blk, 0, stream>>>(
      Qh, Ql, Kh, Kl, (unsigned*)wts);

  // exact top-512 + softmax, in place (wave-per-row)
  topk_softmax<<<dim3(BH * Ss / 4), blk, 0, stream>>>(wts);

  // PV split-K=2 -> f32 partials (aliasing dead Qh..Kl)
  pv_split<<<dim3(2, Ss / 128, BH), blk, 0, stream>>>(wts, Vt, pvp);

  // output projection with inline partial-reduce
  mfma_oproj<<<dim3(MROWS / 128, Dd / 128), blk, 0, stream>>>(
      pvp, pvp + (size_t)MROWS * Dd, WoT, bo, outp);
}